// Round 7
// baseline (2614.017 us; speedup 1.0000x reference)
//
#include <hip/hip_runtime.h>
#include <hip/hip_bf16.h>

// ---------------- constants ----------------
#define NTOK   6000
#define INDIM  1536
#define DIM    1024
#define NPL    6144
#define PAD    59
#define NH     6085
#define HEADS  8
#define DHEAD  128
#define LMK    512
#define LSUB   12
#define HW     78
#define QSCALE 0.08838834764831845f

// ---------------- ws layout (float-slot offsets) ----------------
#define OFF_H     0LL          // 6144*1024 f32
#define OFF_LNXO  6291456LL    // LNXb bf16
#define OFF_QKVB  12582912LL   // 6144*3072 bf16; EO bf16 + PPEG planes alias
#define OFF_PBV   22020096LL   // 8h*512*8c*128 f32 = 4194304
#define OFF_PM    26214400LL   // 32768
#define OFF_PL    26247168LL   // 32768
#define OFF_OB    26279936LL   // 6144*1024 bf16 = 3145728 slots
#define OFF_VT    34603008LL   // 8*128*6144 bf16
#define OFF_QL    37748736LL
#define OFF_KL    38010880LL
#define OFF_A2F   38273024LL   // 8*512*512 f32
#define OFF_BVTB  40370176LL   // 8*128*512 bf16
#define OFF_XB    42467328LL   // bf16 8*512*512 each below
#define OFF_XZB   43515904LL
#define OFF_XZT7  44564480LL
#define OFF_PT15  45613056LL
#define OFF_QT13  46661632LL
#define OFF_ZB0   47710208LL
#define OFF_ZT0   48758784LL
#define OFF_ZB1   49807360LL
#define OFF_ZT1   50855936LL
#define OFF_ZBT   52428800LL   // 8*128*512 bf16
#define OFF_QWB   52690944LL   // 3072*1024 bf16
#define OFF_OWB   54263808LL   // 1024*1024 bf16
#define OFF_COLS  54788096LL
#define OFF_SCAL  54796288LL
#define OFF_BARS  54797312LL   // 8 heads * 32 uints
// transient aliases (dead before overlapping buffers are written)
#define OFF_DATAB 31457280LL   // 6000*1536 bf16 (pre-stage only)
#define OFF_EWB   36065280LL   // 3072*1536 bf16 (pre-stage only)

typedef __attribute__((ext_vector_type(8))) short s16x8;
typedef __attribute__((ext_vector_type(4))) float f32x4;

// ---------------- bf16 helpers ----------------
__device__ __forceinline__ ushort f2b(float f) {
    union { float f; unsigned u; } v; v.f = f;
    return (ushort)((v.u + 0x7FFF + ((v.u >> 16) & 1)) >> 16);
}
__device__ __forceinline__ float b2f(ushort h) {
    union { unsigned u; float f; } v; v.u = ((unsigned)h) << 16; return v.f;
}

// async global->LDS, 16 bytes per lane; lds ptr must be wave-uniform
__device__ __forceinline__ void gld16(const void* g, void* l) {
    __builtin_amdgcn_global_load_lds((const __attribute__((address_space(1))) void*)g,
                                     (__attribute__((address_space(3))) void*)l, 16, 0, 0);
}

// ---------------- reductions (blockDim.x == 256) ----------------
__device__ __forceinline__ float blk_sum(float v) {
    __shared__ float sb[4];
    #pragma unroll
    for (int o = 32; o > 0; o >>= 1) v += __shfl_down(v, o);
    int lane = threadIdx.x & 63, w = threadIdx.x >> 6;
    __syncthreads();
    if (lane == 0) sb[w] = v;
    __syncthreads();
    return sb[0] + sb[1] + sb[2] + sb[3];
}
__device__ __forceinline__ float blk_max(float v) {
    __shared__ float sb[4];
    #pragma unroll
    for (int o = 32; o > 0; o >>= 1) v = fmaxf(v, __shfl_down(v, o));
    int lane = threadIdx.x & 63, w = threadIdx.x >> 6;
    __syncthreads();
    if (lane == 0) sb[w] = v;
    __syncthreads();
    return fmaxf(fmaxf(sb[0], sb[1]), fmaxf(sb[2], sb[3]));
}

// ================= MFMA GEMM (bf16 x bf16), C = alpha * A @ B^T =================
// EPI: 0 f32 | 1 bf16 qkv-scale | 2 bf16 | 3 f32 += v+bias
template<int EPI>
__global__ __launch_bounds__(256)
void mg(const ushort* __restrict__ A, int lda, long long sA,
        const ushort* __restrict__ B, int ldb, long long sB,
        void* __restrict__ Cp, int ldc, long long sC,
        int M, int K, const float* __restrict__ bias, float alpha)
{
    __shared__ ushort As[4096];
    __shared__ ushort Bs[4096];
    const int t = threadIdx.x;
    const int z = blockIdx.z;
    const ushort* Ab = A + (long long)z * sA;
    const ushort* Bb = B + (long long)z * sB;
    const int row0 = blockIdx.y * 128, col0 = blockIdx.x * 128;
    const int w = t >> 6, lane = t & 63;
    const int l4 = lane >> 2, ls = (lane & 3) * 8;
    const int q0 = w, q1 = 4 + w;
    int ar0 = row0 + q0 * 16 + l4; if (ar0 >= M) ar0 = M - 1;
    int ar1 = row0 + q1 * 16 + l4; if (ar1 >= M) ar1 = M - 1;
    const int br0 = col0 + q0 * 16 + l4;
    const int br1 = col0 + q1 * 16 + l4;
    const ushort* ap0 = Ab + (long long)ar0 * lda + ls;
    const ushort* ap1 = Ab + (long long)ar1 * lda + ls;
    const ushort* bp0 = Bb + (long long)br0 * ldb + ls;
    const ushort* bp1 = Bb + (long long)br1 * ldb + ls;
    ushort* asl0 = &As[q0 * 512];
    ushort* asl1 = &As[q1 * 512];
    ushort* bsl0 = &Bs[q0 * 512];
    ushort* bsl1 = &Bs[q1 * 512];

    const int wr = (w >> 1) * 64, wc = (w & 1) * 64;
    const int fr = lane & 15, fo = (lane >> 4) * 8;

    f32x4 acc[4][4];
    #pragma unroll
    for (int a = 0; a < 4; a++)
        #pragma unroll
        for (int b = 0; b < 4; b++)
            acc[a][b] = (f32x4){0.f, 0.f, 0.f, 0.f};

    for (int kt = 0; kt < K; kt += 32) {
        gld16(ap0 + kt, asl0);
        gld16(ap1 + kt, asl1);
        gld16(bp0 + kt, bsl0);
        gld16(bp1 + kt, bsl1);
        __syncthreads();
        s16x8 af[4], bf[4];
        #pragma unroll
        for (int a = 0; a < 4; a++) af[a] = *(const s16x8*)&As[(wr + a * 16 + fr) * 32 + fo];
        #pragma unroll
        for (int b = 0; b < 4; b++) bf[b] = *(const s16x8*)&Bs[(wc + b * 16 + fr) * 32 + fo];
        #pragma unroll
        for (int a = 0; a < 4; a++)
            #pragma unroll
            for (int b = 0; b < 4; b++)
                acc[a][b] = __builtin_amdgcn_mfma_f32_16x16x32_bf16(af[a], bf[b], acc[a][b], 0, 0, 0);
        __syncthreads();
    }

    const int er0 = row0 + wr + ((lane >> 4) << 2);
    const int ec0 = col0 + wc + fr;
    #pragma unroll
    for (int a = 0; a < 4; a++) {
        #pragma unroll
        for (int j = 0; j < 4; j++) {
            int r = er0 + a * 16 + j;
            if (r >= M) continue;
            #pragma unroll
            for (int b = 0; b < 4; b++) {
                int c = ec0 + b * 16;
                float v = alpha * acc[a][b][j];
                long long ci = z * sC + (long long)r * ldc + c;
                if constexpr (EPI == 0) ((float*)Cp)[ci] = v;
                else if constexpr (EPI == 1) ((ushort*)Cp)[ci] = f2b(c < 1024 ? v * QSCALE : v);
                else if constexpr (EPI == 2) ((ushort*)Cp)[ci] = f2b(v);
                else ((float*)Cp)[ci] += v + bias[c];
            }
        }
    }
}

// ================= persistent Newton-Schulz =================
// per-head grid barrier: 16 blocks/head, monotonic counter
__device__ __forceinline__ void hbar(unsigned* bar, unsigned tgt)
{
    __syncthreads();
    if (threadIdx.x == 0) {
        __threadfence();
        atomicAdd(bar, 1u);
        while (atomicAdd(bar, 0u) < tgt) __builtin_amdgcn_s_sleep(2);
        __threadfence();
    }
    __syncthreads();
}

// one 128x128 tile of C = alpha * A @ B^T (all 512x512, ld=512)
// C (row-major bf16) optional; T[c][r] = tdelta*(r==c) + tsign*v optional
__device__ __forceinline__ void g512(const ushort* __restrict__ A, const ushort* __restrict__ B,
                                     ushort* C, ushort* T, float alpha, float tdelta, float tsign,
                                     ushort* As, ushort* Bs, int row0, int col0)
{
    const int t = threadIdx.x;
    const int w = t >> 6, lane = t & 63;
    const int l4 = lane >> 2, ls = (lane & 3) * 8;
    const int q0 = w, q1 = 4 + w;
    const ushort* ap0 = A + (long long)(row0 + q0 * 16 + l4) * 512 + ls;
    const ushort* ap1 = A + (long long)(row0 + q1 * 16 + l4) * 512 + ls;
    const ushort* bp0 = B + (long long)(col0 + q0 * 16 + l4) * 512 + ls;
    const ushort* bp1 = B + (long long)(col0 + q1 * 16 + l4) * 512 + ls;
    ushort* asl0 = &As[q0 * 512];
    ushort* asl1 = &As[q1 * 512];
    ushort* bsl0 = &Bs[q0 * 512];
    ushort* bsl1 = &Bs[q1 * 512];
    const int wr = (w >> 1) * 64, wc = (w & 1) * 64;
    const int fr = lane & 15, fo = (lane >> 4) * 8;

    f32x4 acc[4][4];
    #pragma unroll
    for (int a = 0; a < 4; a++)
        #pragma unroll
        for (int b = 0; b < 4; b++)
            acc[a][b] = (f32x4){0.f, 0.f, 0.f, 0.f};

    for (int kt = 0; kt < 512; kt += 32) {
        gld16(ap0 + kt, asl0);
        gld16(ap1 + kt, asl1);
        gld16(bp0 + kt, bsl0);
        gld16(bp1 + kt, bsl1);
        __syncthreads();
        s16x8 af[4], bf[4];
        #pragma unroll
        for (int a = 0; a < 4; a++) af[a] = *(const s16x8*)&As[(wr + a * 16 + fr) * 32 + fo];
        #pragma unroll
        for (int b = 0; b < 4; b++) bf[b] = *(const s16x8*)&Bs[(wc + b * 16 + fr) * 32 + fo];
        #pragma unroll
        for (int a = 0; a < 4; a++)
            #pragma unroll
            for (int b = 0; b < 4; b++)
                acc[a][b] = __builtin_amdgcn_mfma_f32_16x16x32_bf16(af[a], bf[b], acc[a][b], 0, 0, 0);
        __syncthreads();
    }

    const int er0 = row0 + wr + ((lane >> 4) << 2);
    const int ec0 = col0 + wc + fr;
    #pragma unroll
    for (int a = 0; a < 4; a++)
        #pragma unroll
        for (int j = 0; j < 4; j++) {
            int r = er0 + a * 16 + j;
            #pragma unroll
            for (int b = 0; b < 4; b++) {
                int c = ec0 + b * 16;
                float v = alpha * acc[a][b][j];
                if (C) C[(long long)r * 512 + c] = f2b(v);
                if (T) T[(long long)c * 512 + r] = f2b((r == c ? tdelta : 0.f) + tsign * v);
            }
        }
}

__global__ __launch_bounds__(256)
void newton6(const ushort* __restrict__ Xb, ushort* __restrict__ XZB, ushort* __restrict__ XZT7,
             ushort* __restrict__ PT15, ushort* __restrict__ QT13,
             ushort* ZB0, ushort* ZT0, ushort* ZB1, ushort* ZT1, unsigned* bars)
{
    __shared__ ushort As[4096];
    __shared__ ushort Bs[4096];
    const int h = blockIdx.z;
    const long long hb = (long long)h * 262144;
    const int row0 = blockIdx.y * 128, col0 = blockIdx.x * 128;
    unsigned* bar = bars + h * 32;
    ushort* zb[2] = {ZB0 + hb, ZB1 + hb};
    ushort* zt[2] = {ZT0 + hb, ZT1 + hb};
    const ushort* X = Xb + hb;
    ushort* Y   = XZB + hb;
    ushort* T7  = XZT7 + hb;
    ushort* T15 = PT15 + hb;
    ushort* T13 = QT13 + hb;
    unsigned tgt = 0;
    int cur = 0;
    for (int it = 0; it < 6; it++) {
        g512(X, zt[cur], Y, T7, 1.f, 7.f, -1.f, As, Bs, row0, col0);
        tgt += 16; hbar(bar, tgt);
        g512(Y, T7, nullptr, T15, 1.f, 15.f, -1.f, As, Bs, row0, col0);
        tgt += 16; hbar(bar, tgt);
        g512(Y, T15, nullptr, T13, 1.f, 13.f, -1.f, As, Bs, row0, col0);
        tgt += 16; hbar(bar, tgt);
        g512(zb[cur], T13, zb[1 - cur], (it < 5) ? zt[1 - cur] : nullptr, 0.25f, 0.f, 1.f, As, Bs, row0, col0);
        tgt += 16; hbar(bar, tgt);
        cur ^= 1;
    }
}

// ================= fused flash attention =================
// MODE 0: final bf16 output to Obp (+ fused depthwise-33 res conv of Vres); MODE 1: partials.
template<int MODE>
__global__ __launch_bounds__(256)
void flash(const ushort* __restrict__ Qp, int ldq, long long sQh,
           const ushort* __restrict__ Kp, int ldk, long long sKh,
           const ushort* __restrict__ Vp, int ldv, long long sVh,
           float* __restrict__ Op, float* __restrict__ Pm, float* __restrict__ Pl,
           ushort* __restrict__ Obp, const ushort* __restrict__ Vres, const float* __restrict__ rw,
           int nkv, int kvspan)
{
    __shared__ ushort Qs[16384];   // 4 subtiles [128][32]
    __shared__ ushort Zs[8192];    // 2 subtiles [128][32] (Vt chunk)
    __shared__ ushort KPs[8192];   // 4 subtiles [64][32] (K chunk); aliased by P [128][64] swizzled
    __shared__ float rws[33];
    ushort* Ps = KPs;
    const int t = threadIdx.x;
    const int h = blockIdx.z;
    const int q0 = blockIdx.x * 128;
    const int kvbase = blockIdx.y * kvspan;
    const ushort* Qb = Qp + (long long)h * sQh;
    const ushort* Kb = Kp + (long long)h * sKh;
    const ushort* Vb = Vp + (long long)h * sVh;
    const int w = t >> 6, lane = t & 63;
    const int sr = lane >> 2, sc2 = (lane & 3) * 8;
    const int fr = lane & 15, fo = (lane >> 4) * 8;
    const int jr = (lane >> 4) * 4;

    if (MODE == 0 && t < 33) rws[t] = rw[h * 33 + t];

    #pragma unroll
    for (int s = 0; s < 4; s++)
        #pragma unroll
        for (int r0 = 0; r0 < 128; r0 += 64)
            gld16(Qb + (long long)(q0 + r0 + w * 16 + sr) * ldq + s * 32 + sc2,
                  &Qs[s * 4096 + (r0 + w * 16) * 32]);

    f32x4 oa[2][8];
    float mold[2][4], lrun[2][4];
    #pragma unroll
    for (int fi = 0; fi < 2; fi++) {
        #pragma unroll
        for (int fj = 0; fj < 8; fj++) oa[fi][fj] = (f32x4){0.f,0.f,0.f,0.f};
        #pragma unroll
        for (int j = 0; j < 4; j++) { mold[fi][j] = -1e30f; lrun[fi][j] = 0.f; }
    }

    for (int c = 0; c < nkv; c++) {
        int kvp = kvbase + c * 64;
        #pragma unroll
        for (int s = 0; s < 4; s++)
            gld16(Kb + (long long)(kvp + w * 16 + sr) * ldk + s * 32 + sc2,
                  &KPs[s * 2048 + (w * 16) * 32]);
        #pragma unroll
        for (int s = 0; s < 2; s++)
            #pragma unroll
            for (int r0 = 0; r0 < 128; r0 += 64)
                gld16(Vb + (long long)(r0 + w * 16 + sr) * ldv + kvp + s * 32 + sc2,
                      &Zs[s * 4096 + (r0 + w * 16) * 32]);
        __syncthreads();

        f32x4 acc[2][4];
        #pragma unroll
        for (int fi = 0; fi < 2; fi++)
            #pragma unroll
            for (int fj = 0; fj < 4; fj++) acc[fi][fj] = (f32x4){0.f,0.f,0.f,0.f};
        #pragma unroll
        for (int ks = 0; ks < 4; ks++) {
            s16x8 qa[2], kb[4];
            #pragma unroll
            for (int fi = 0; fi < 2; fi++)
                qa[fi] = *(const s16x8*)&Qs[ks * 4096 + (w * 32 + fi * 16 + fr) * 32 + fo];
            #pragma unroll
            for (int fj = 0; fj < 4; fj++)
                kb[fj] = *(const s16x8*)&KPs[ks * 2048 + (fj * 16 + fr) * 32 + fo];
            #pragma unroll
            for (int fi = 0; fi < 2; fi++)
                #pragma unroll
                for (int fj = 0; fj < 4; fj++)
                    acc[fi][fj] = __builtin_amdgcn_mfma_f32_16x16x32_bf16(qa[fi], kb[fj], acc[fi][fj], 0, 0, 0);
        }

        float rs[2][4];
        #pragma unroll
        for (int fi = 0; fi < 2; fi++) {
            #pragma unroll
            for (int j = 0; j < 4; j++) {
                float mx = acc[fi][0][j];
                #pragma unroll
                for (int fj = 1; fj < 4; fj++) mx = fmaxf(mx, acc[fi][fj][j]);
                mx = fmaxf(mx, __shfl_xor(mx, 1));
                mx = fmaxf(mx, __shfl_xor(mx, 2));
                mx = fmaxf(mx, __shfl_xor(mx, 4));
                mx = fmaxf(mx, __shfl_xor(mx, 8));
                float mn = fmaxf(mold[fi][j], mx);
                float scl = __expf(mold[fi][j] - mn);
                mold[fi][j] = mn;
                lrun[fi][j] *= scl;
                #pragma unroll
                for (int fj = 0; fj < 8; fj++) oa[fi][fj][j] *= scl;
                float r = 0.f;
                #pragma unroll
                for (int fj = 0; fj < 4; fj++) {
                    float p = __expf(acc[fi][fj][j] - mn);
                    acc[fi][fj][j] = p;
                    r += p;
                }
                r += __shfl_xor(r, 1);
                r += __shfl_xor(r, 2);
                r += __shfl_xor(r, 4);
                r += __shfl_xor(r, 8);
                rs[fi][j] = r;
            }
        }
        __syncthreads();
        #pragma unroll
        for (int fi = 0; fi < 2; fi++)
            #pragma unroll
            for (int j = 0; j < 4; j++) {
                int row = w * 32 + fi * 16 + jr + j;
                lrun[fi][j] += rs[fi][j];
                #pragma unroll
                for (int fj = 0; fj < 4; fj++) {
                    int idx = (row * 64 + fj * 16 + fr) ^ ((row & 7) << 3);
                    Ps[idx] = f2b(acc[fi][fj][j]);
                }
            }
        __syncthreads();

        #pragma unroll
        for (int ks2 = 0; ks2 < 2; ks2++) {
            s16x8 pa[2], zb[8];
            #pragma unroll
            for (int fi = 0; fi < 2; fi++) {
                int row = w * 32 + fi * 16 + fr;
                int idx = (row * 64 + ks2 * 32 + fo) ^ ((row & 7) << 3);
                pa[fi] = *(const s16x8*)&Ps[idx];
            }
            #pragma unroll
            for (int fj = 0; fj < 8; fj++)
                zb[fj] = *(const s16x8*)&Zs[ks2 * 4096 + (fj * 16 + fr) * 32 + fo];
            #pragma unroll
            for (int fi = 0; fi < 2; fi++)
                #pragma unroll
                for (int fj = 0; fj < 8; fj++)
                    oa[fi][fj] = __builtin_amdgcn_mfma_f32_16x16x32_bf16(pa[fi], zb[fj], oa[fi][fj], 0, 0, 0);
        }
        __syncthreads();
    }

    // epilogue
    #pragma unroll
    for (int fi = 0; fi < 2; fi++)
        #pragma unroll
        for (int j = 0; j < 4; j++) {
            int row = w * 32 + fi * 16 + jr + j;
            if constexpr (MODE == 0) {
                float inv = 1.f / lrun[fi][j];
                int grow = q0 + row;
                float vv[8];
                #pragma unroll
                for (int fj = 0; fj < 8; fj++) vv[fj] = oa[fi][fj][j] * inv;
                // fused depthwise-33 res conv on Vres
                for (int tt = 0; tt < 33; tt++) {
                    int r = grow + tt - 16;
                    if ((unsigned)r < (unsigned)NPL) {
                        const ushort* p = Vres + (long long)r * 3072 + 2048 + h * 128;
                        float wv = rws[tt];
                        #pragma unroll
                        for (int fj = 0; fj < 8; fj++) vv[fj] += wv * b2f(p[fj * 16 + fr]);
                    }
                }
                #pragma unroll
                for (int fj = 0; fj < 8; fj++)
                    Obp[(long long)grow * DIM + h * 128 + fj * 16 + fr] = f2b(vv[fj]);
            } else {
                long long rb = (((long long)h * 512 + q0 + row) * 8 + blockIdx.y) * 128;
                #pragma unroll
                for (int fj = 0; fj < 8; fj++)
                    Op[rb + fj * 16 + fr] = oa[fi][fj][j];
                if (fr == 0) {
                    long long si = ((long long)h * 512 + q0 + row) * 8 + blockIdx.y;
                    Pm[si] = mold[fi][j];
                    Pl[si] = lrun[fi][j];
                }
            }
        }
}

// combine kv-split partials -> bvT bf16 [h][d][l]
__global__ __launch_bounds__(256)
void bv_combine(const float* __restrict__ PBV, const float* __restrict__ Pm,
                const float* __restrict__ Pl, ushort* __restrict__ BVTb)
{
    __shared__ float T[32][129];
    __shared__ float wc8[32][8], invL[32];
    int t = threadIdx.x;
    int h = blockIdx.y, l0 = blockIdx.x * 32;
    if (t < 32) {
        long long base = ((long long)h * 512 + l0 + t) * 8;
        float m = -1e30f;
        float mv[8], lv[8];
        #pragma unroll
        for (int c = 0; c < 8; c++) { mv[c] = Pm[base + c]; lv[c] = Pl[base + c]; m = fmaxf(m, mv[c]); }
        float L = 0.f;
        #pragma unroll
        for (int c = 0; c < 8; c++) { float wv = __expf(mv[c] - m); wc8[t][c] = wv; L += wv * lv[c]; }
        invL[t] = 1.f / L;
    }
    __syncthreads();
    int l = t >> 3, dg = t & 7;
    long long rbase = ((long long)h * 512 + l0 + l) * 8 * 128;
    #pragma unroll
    for (int dd = 0; dd < 16; dd++) {
        int d = dg * 16 + dd;
        float s = 0.f;
        #pragma unroll
        for (int c = 0; c < 8; c++) s += wc8[l][c] * PBV[rbase + c * 128 + d];
        T[l][d] = s * invL[l];
    }
    __syncthreads();
    int d = t >> 1, half = t & 1;
    #pragma unroll
    for (int lc = 0; lc < 16; lc++) {
        int l2 = half * 16 + lc;
        BVTb[(long long)h * 65536 + (long long)d * 512 + l0 + l2] = f2b(T[l2][d]);
    }
}

// ---------------- f32 -> bf16 convert ----------------
__global__ __launch_bounds__(256)
void cvt_bf16(const float* __restrict__ x, ushort* __restrict__ y, long long n)
{
    long long i = ((long long)blockIdx.x * 256 + threadIdx.x) * 8;
    if (i >= n) return;
    float4 a = *(const float4*)(x + i), b = *(const float4*)(x + i + 4);
    ushort4 u0 = {f2b(a.x), f2b(a.y), f2b(a.z), f2b(a.w)};
    ushort4 u1 = {f2b(b.x), f2b(b.y), f2b(b.z), f2b(b.w)};
    *(ushort4*)(y + i) = u0; *(ushort4*)(y + i + 4) = u1;
}

// ---------------- softmax fp32 rows (W = NIT*256) ----------------
template<int NIT>
__global__ __launch_bounds__(256)
void softmax_rows(float* __restrict__ X, int W)
{
    long long row = blockIdx.x;
    float* x = X + row * W;
    float r[NIT];
    float m = -1e30f;
    #pragma unroll
    for (int i = 0; i < NIT; i++) { r[i] = x[threadIdx.x + i * 256]; m = fmaxf(m, r[i]); }
    m = blk_max(m);
    float s = 0.f;
    #pragma unroll
    for (int i = 0; i < NIT; i++) { r[i] = __expf(r[i] - m); s += r[i]; }
    s = blk_sum(s);
    float inv = 1.f / s;
    #pragma unroll
    for (int i = 0; i < NIT; i++) x[threadIdx.x + i * 256] = r[i] * inv;
}

// ---------------- LN + front-pad -> bf16 ----------------
__global__ __launch_bounds__(256)
void ln_pad(const float* __restrict__ H, const float* __restrict__ g,
            const float* __restrict__ b, ushort* __restrict__ X)
{
    int row = blockIdx.x, t = threadIdx.x;
    ushort* o = X + (long long)row * DIM;
    if (row < PAD) {
        #pragma unroll
        for (int i = 0; i < 4; i++) o[t + i * 256] = 0;
        return;
    }
    const float* x = H + (long long)(row - PAD) * DIM;
    float r[4]; float s = 0.f;
    #pragma unroll
    for (int i = 0; i < 4; i++) { r[i] = x[t + i * 256]; s += r[i]; }
    float mu = blk_sum(s) * (1.f / DIM);
    float v = 0.f;
    #pragma unroll
    for (int i = 0; i < 4; i++) { float d = r[i] - mu; v += d * d; }
    float var = blk_sum(v) * (1.f / DIM);
    float rs = rsqrtf(var + 1e-5f);
    #pragma unroll
    for (int i = 0; i < 4; i++) { int c = t + i * 256; o[c] = f2b((r[i] - mu) * rs * g[c] + b[c]); }
}

// ---------------- landmarks ----------------
__global__ __launch_bounds__(128)
void landmarks(const ushort* __restrict__ QKVb, ushort* __restrict__ QL, ushort* __restrict__ KL)
{
    int L = blockIdx.x, h = blockIdx.y, d = threadIdx.x;
    float sq = 0.f, sk = 0.f;
    #pragma unroll
    for (int j = 0; j < LSUB; j++) {
        const ushort* p = QKVb + (long long)(L * LSUB + j) * 3072 + h * DHEAD + d;
        sq += b2f(p[0]);
        sk += b2f(p[1024]);
    }
    QL[(long long)(h * LMK + L) * DHEAD + d] = f2b(sq * (1.f / LSUB));
    KL[(long long)(h * LMK + L) * DHEAD + d] = f2b(sk * (1.f / LSUB));
}

// ---------------- V transpose -> bf16 VT[h][d][i] ----------------
__global__ void vtrans(const ushort* __restrict__ Q, ushort* __restrict__ VT)
{
    __shared__ ushort tile[32][33];
    int h = blockIdx.z, i0 = blockIdx.x * 32, d0 = blockIdx.y * 32;
    int tx = threadIdx.x, ty = threadIdx.y;
    for (int yy = ty; yy < 32; yy += 8)
        tile[yy][tx] = Q[(long long)(i0 + yy) * 3072 + 2048 + h * 128 + d0 + tx];
    __syncthreads();
    for (int yy = ty; yy < 32; yy += 8)
        VT[((long long)h * 128 + d0 + yy) * 6144 + i0 + tx] = tile[tx][yy];
}

// ---------------- a2 column sums ----------------
__global__ __launch_bounds__(256)
void a2_sums2(const float* __restrict__ A2, float* __restrict__ cols)
{
    int h = blockIdx.x, slice = blockIdx.y, t = threadIdx.x;
    const float* a = A2 + (long long)h * LMK * LMK + (long long)slice * 64 * LMK;
    float s0 = 0.f, s1 = 0.f;
    #pragma unroll 4
    for (int i = 0; i < 64; i++) {
        s0 += a[(long long)i * LMK + t];
        s1 += a[(long long)i * LMK + t + 256];
    }
    atomicAdd(&cols[h * LMK + t], s0);
    atomicAdd(&cols[h * LMK + t + 256], s1);
}
__global__ __launch_bounds__(256)
void a2_scal2(const float* __restrict__ cols, float* __restrict__ scal)
{
    float mc = -1e30f;
    for (int i = threadIdx.x; i < HEADS * LMK; i += 256) mc = fmaxf(mc, cols[i]);
    mc = blk_max(mc);
    if (threadIdx.x == 0) scal[0] = 1.f / mc;
}

// ---------------- z0/X prep ----------------
__global__ void z0_t(const float* __restrict__ A2, ushort* __restrict__ Xb,
                     ushort* __restrict__ Z0b, ushort* __restrict__ Z0T,
                     const float* __restrict__ scal)
{
    __shared__ float tile[32][33];
    int h = blockIdx.z;
    const float* a = A2 + (long long)h * LMK * LMK;
    float s = scal[0];
    int x0 = blockIdx.x * 32, y0 = blockIdx.y * 32;
    int tx = threadIdx.x, ty = threadIdx.y;
    long long hb = (long long)h * LMK * LMK;
    for (int yy = ty; yy < 32; yy += 8) {
        float v = a[(long long)(y0 + yy) * LMK + x0 + tx];
        tile[yy][tx] = v;
        Xb [hb + (long long)(y0 + yy) * LMK + x0 + tx] = f2b(v);
        Z0T[hb + (long long)(y0 + yy) * LMK + x0 + tx] = f2b(s * v);
    }
    __syncthreads();
    for (int yy = ty; yy < 32; yy += 8)
        Z0b[hb + (long long)(x0 + yy) * LMK + y0 + tx] = f2b(s * tile[tx][yy]);
}

// ---------------- MoE ----------------
__global__ __launch_bounds__(256)
void moe_combine(const float* __restrict__ X, const float* __restrict__ wg,
                 const ushort* __restrict__ EO, const float* __restrict__ eb,
                 float* __restrict__ H)
{
    int i = blockIdx.x, t = threadIdx.x;
    const float* x = X + (long long)i * INDIM;
    float g0 = 0.f, g1 = 0.f, g2 = 0.f;
    for (int f = t; f < INDIM; f += 256) {
        float xv = x[f];
        const float* w = wg + f * 3;
        g0 += xv * w[0]; g1 += xv * w[1]; g2 += xv * w[2];
    }
    g0 = blk_sum(g0); g1 = blk_sum(g1); g2 = blk_sum(g2);
    float m = fmaxf(g0, fmaxf(g1, g2));
    float e0 = __expf(g0 - m), e1 = __expf(g1 - m), e2 = __expf(g2 - m);
    float inv = 1.f / (e0 + e1 + e2);
    e0 *= inv; e1 *= inv; e2 *= inv;
    const ushort* eo = EO + (long long)i * 3072;
    for (int o = t; o < DIM; o += 256) {
        float v0 = fmaxf(b2f(eo[o])        + eb[o],        0.f);
        float v1 = fmaxf(b2f(eo[1024 + o]) + eb[1024 + o], 0.f);
        float v2 = fmaxf(b2f(eo[2048 + o]) + eb[2048 + o], 0.f);
        float r = e0 * v0 + e1 * v1 + e2 * v2;
        H[(long long)(1 + i) * DIM + o] = r;
        if (i < 84) H[(long long)(6001 + i) * DIM + o] = r;
    }
}

__global__ void cls_copy(const float* __restrict__ c, float* __restrict__ H)
{
    for (int i = threadIdx.x; i < DIM; i += 256) H[i] = c[i];
}

// ---------------- PPEG ----------------
__global__ void h2f(const float* __restrict__ H, float* __restrict__ F)
{
    __shared__ float tile[32][33];
    int p0 = blockIdx.x * 32, c0 = blockIdx.y * 32;
    int tx = threadIdx.x, ty = threadIdx.y;
    for (int yy = ty; yy < 32; yy += 8) {
        int p = p0 + yy;
        if (p < HW * HW) tile[yy][tx] = H[(long long)(1 + p) * DIM + c0 + tx];
    }
    __syncthreads();
    for (int yy = ty; yy < 32; yy += 8) {
        int p = p0 + tx, c = c0 + yy;
        if (p < HW * HW) F[(long long)c * (HW * HW) + p] = tile[tx][yy];
    }
}
__global__ void f2h(const float* __restrict__ F2, float* __restrict__ H)
{
    __shared__ float tile[32][33];
    int c0 = blockIdx.x * 32, p0 = blockIdx.y * 32;
    int tx = threadIdx.x, ty = threadIdx.y;
    for (int yy = ty; yy < 32; yy += 8) {
        int p = p0 + tx;
        if (p < HW * HW) tile[yy][tx] = F2[(long long)(c0 + yy) * (HW * HW) + p];
    }
    __syncthreads();
    for (int yy = ty; yy < 32; yy += 8) {
        int p = p0 + yy;
        if (p < HW * HW) H[(long long)(1 + p) * DIM + c0 + tx] = tile[tx][yy];
    }
}
__global__ __launch_bounds__(256)
void ppeg_conv2(const float* __restrict__ F,
                const float* __restrict__ w7, const float* __restrict__ b7,
                const float* __restrict__ w5, const float* __restrict__ b5,
                const float* __restrict__ w3, const float* __restrict__ b3,
                float* __restrict__ F2)
{
    int c = blockIdx.x, t = threadIdx.x;
    __shared__ float plane[HW * HW];
    __shared__ float wm[49];
    for (int p = t; p < HW * HW; p += 256) plane[p] = F[(long long)c * (HW * HW) + p];
    if (t < 49) {
        int ky = t / 7 - 3, kx = t % 7 - 3;
        float w = w7[(long long)c * 49 + t];
        if (ky >= -2 && ky <= 2 && kx >= -2 && kx <= 2) w += w5[(long long)c * 25 + (ky + 2) * 5 + (kx + 2)];
        if (ky >= -1 && ky <= 1 && kx >= -1 && kx <= 1) w += w3[(long long)c * 9 + (ky + 1) * 3 + (kx + 1)];
        if (t == 24) w += 1.0f;
        wm[t] = w;
    }
    __syncthreads();
    float bsum = b7[c] + b5[c] + b3[c];
    for (int p = t; p < HW * HW; p += 256) {
        int y = p / HW, x = p - y * HW;
        float acc = bsum;
        if (y >= 3 && y < HW - 3 && x >= 3 && x < HW - 3) {
            const float* base = &plane[p];
            #pragma unroll
            for (int ky = -3; ky <= 3; ky++)
                #pragma unroll
                for (int kx = -3; kx <= 3; kx++)
                    acc += wm[(ky + 3) * 7 + kx + 3] * base[ky * HW + kx];
        } else {
            for (int ky = -3; ky <= 3; ky++) {
                int yy = y + ky; if ((unsigned)yy >= (unsigned)HW) continue;
                for (int kx = -3; kx <= 3; kx++) {
                    int xx = x + kx; if ((unsigned)xx >= (unsigned)HW) continue;
                    acc += wm[(ky + 3) * 7 + kx + 3] * plane[yy * HW + xx];
                }
            }
        }
        F2[(long long)c * (HW * HW) + p] = acc;
    }
}

// ---------------- final head ----------------
__global__ __launch_bounds__(256)
void head_k(const float* __restrict__ H, const float* __restrict__ g, const float* __restrict__ b,
            const float* __restrict__ fw, const float* __restrict__ fb, float* __restrict__ out)
{
    int t = threadIdx.x;
    float r[4]; float s = 0.f;
    #pragma unroll
    for (int i = 0; i < 4; i++) { r[i] = H[t + i * 256]; s += r[i]; }
    float mu = blk_sum(s) * (1.f / DIM);
    float v = 0.f;
    #pragma unroll
    for (int i = 0; i < 4; i++) { float d = r[i] - mu; v += d * d; }
    float var = blk_sum(v) * (1.f / DIM);
    float rs = rsqrtf(var + 1e-5f);
    float d0 = 0.f, d1 = 0.f;
    #pragma unroll
    for (int i = 0; i < 4; i++) {
        int c = t + i * 256;
        float hv = (r[i] - mu) * rs * g[c] + b[c];
        d0 += hv * fw[c];
        d1 += hv * fw[DIM + c];
    }
    d0 = blk_sum(d0); d1 = blk_sum(d1);
    if (t == 0) {
        float l0 = d0 + fb[0], l1 = d1 + fb[1];
        float m = fmaxf(l0, l1);
        float e0 = __expf(l0 - m), e1 = __expf(l1 - m);
        float inv = 1.f / (e0 + e1);
        out[0] = l0; out[1] = l1;
        out[2] = e0 * inv; out[3] = e1 * inv;
        out[4] = (l1 > l0) ? 1.0f : 0.0f;
    }
}

// ---------------- host ----------------
extern "C" void kernel_launch(void* const* d_in, const int* in_sizes, int n_in,
                              void* d_out, int out_size, void* d_ws, size_t ws_size,
                              hipStream_t stream)
{
    const float* data     = (const float*)d_in[0];
    const float* w_gate   = (const float*)d_in[1];
    const float* expert_w = (const float*)d_in[2];
    const float* expert_b = (const float*)d_in[3];
    const float* cls_tok  = (const float*)d_in[4];
    const float* ln_g[2]  = {(const float*)d_in[5],  (const float*)d_in[11]};
    const float* ln_b[2]  = {(const float*)d_in[6],  (const float*)d_in[12]};
    const float* qkv_w[2] = {(const float*)d_in[7],  (const float*)d_in[13]};
    const float* out_w[2] = {(const float*)d_in[8],  (const float*)d_in[14]};
    const float* out_b[2] = {(const float*)d_in[9],  (const float*)d_in[15]};
    const float* res_w[2] = {(const float*)d_in[10], (const float*)d_in[16]};
    const float* pw7 = (const float*)d_in[17]; const float* pb7 = (const float*)d_in[18];
    const float* pw5 = (const float*)d_in[19]; const float* pb5 = (const float*)d_in[20];
    const float* pw3 = (const float*)d_in[21]; const float* pb3 = (const float*)d_in[22];
    const float* nf_g = (const float*)d_in[23]; const float* nf_b = (const float*)d_in[24];
    const float* fc2w = (const float*)d_in[25]; const float* fc2b = (const float*)d_in[26];

    float*  ws    = (float*)d_ws;
    float*  H     = ws + OFF_H;
    ushort* LNXb  = (ushort*)(ws + OFF_LNXO);
    ushort* QKVb  = (ushort*)(ws + OFF_QKVB);
    ushort* EOb   = (ushort*)(ws + OFF_QKVB);
    float*  PBV   = ws + OFF_PBV;
    float*  PM    = ws + OFF_PM;
    float*  PL    = ws + OFF_PL;
    ushort* Ob    = (ushort*)(ws + OFF_OB);
    ushort* VT    = (ushort*)(ws + OFF_VT);
    ushort* QL    = (ushort*)(ws + OFF_QL);
    ushort* KL    = (ushort*)(ws + OFF_KL);
    float*  A2F   = ws + OFF_A2F;
    ushort* BVTb  = (ushort*)(ws + OFF_BVTB);
    ushort* Xb    = (ushort*)(ws + OFF_XB);
    ushort* XZB   = (ushort*)(ws + OFF_XZB);
    ushort* XZT7  = (ushort*)(ws + OFF_XZT7);
    ushort* PT15  = (ushort*)(ws + OFF_PT15);
    ushort* QT13  = (ushort*)(ws + OFF_QT13);
    ushort* ZB[2] = {(ushort*)(ws + OFF_ZB0), (ushort*)(ws + OFF_ZB1)};
    ushort* ZT[2] = {(ushort*)(ws + OFF_ZT0), (ushort*)(ws + OFF_ZT1)};
    ushort* ZBT   = (ushort*)(ws + OFF_ZBT);
    ushort* QWB   = (ushort*)(ws + OFF_QWB);
    ushort* OWB   = (ushort*)(ws + OFF_OWB);
    ushort* DATAB = (ushort*)(ws + OFF_DATAB);
    ushort* EWB   = (ushort*)(ws + OFF_EWB);
    float*  COLS  = ws + OFF_COLS;
    float*  SCAL  = ws + OFF_SCAL;
    unsigned* BARS = (unsigned*)(ws + OFF_BARS);

    const long long HSB = (long long)LMK * DHEAD;   // 65536
    const long long A2S = (long long)LMK * LMK;     // 262144

    // ---- MoE ----
    cvt_bf16<<<4500, 256, 0, stream>>>(data, DATAB, (long long)NTOK * INDIM);
    cvt_bf16<<<2304, 256, 0, stream>>>(expert_w, EWB, 3072LL * INDIM);
    mg<2><<<dim3(24,47,1),256,0,stream>>>(DATAB,INDIM,0, EWB,INDIM,0, EOb,3072,0,
        NTOK,INDIM, nullptr, 1.f);
    moe_combine<<<NTOK,256,0,stream>>>(data, w_gate, EOb, expert_b, H);
    cls_copy<<<1,256,0,stream>>>(cls_tok, H);

    for (int stage = 0; stage < 2; stage++) {
        cvt_bf16<<<1536, 256, 0, stream>>>(qkv_w[stage], QWB, 3072LL * DIM);
        cvt_bf16<<<512, 256, 0, stream>>>(out_w[stage], OWB, (long long)DIM * DIM);
        ln_pad<<<NPL,256,0,stream>>>(H, ln_g[stage], ln_b[stage], LNXb);
        mg<1><<<dim3(24,48,1),256,0,stream>>>(LNXb,DIM,0, QWB,DIM,0, QKVb,3072,0,
            NPL,DIM, nullptr, 1.f);
        landmarks<<<dim3(LMK,HEADS),128,0,stream>>>(QKVb, QL, KL);
        vtrans<<<dim3(192,4,8),dim3(32,8),0,stream>>>(QKVb, VT);
        // a2 = softmax(ql @ kl^T) f32
        mg<0><<<dim3(4,4,8),256,0,stream>>>(QL,DHEAD,HSB, KL,DHEAD,HSB, A2F,LMK,A2S,
            LMK,DHEAD, nullptr, 1.f);
        softmax_rows<2><<<HEADS*LMK,256,0,stream>>>(A2F, LMK);
        hipMemsetAsync(COLS, 0, HEADS * LMK * sizeof(float), stream);
        a2_sums2<<<dim3(HEADS,8),256,0,stream>>>(A2F, COLS);
        a2_scal2<<<1,256,0,stream>>>(COLS, SCAL);
        z0_t<<<dim3(16,16,8),dim3(32,8),0,stream>>>(A2F, Xb, ZB[0], ZT[0], SCAL);
        // Newton-Schulz: single persistent kernel, per-head grid barriers
        hipMemsetAsync(BARS, 0, HEADS * 32 * sizeof(unsigned), stream);
        newton6<<<dim3(4,4,8),256,0,stream>>>(Xb, XZB, XZT7, PT15, QT13,
            ZB[0], ZT[0], ZB[1], ZT[1], BARS);
        ushort* Z6 = ZB[0];
        // flash a3: partial bv over 8 kv-chunks of 768
        flash<1><<<dim3(4,8,8),256,0,stream>>>(QL,DHEAD,HSB, QKVb+1024,3072,128,
            VT,NPL,(long long)DHEAD*NPL, PBV, PM, PL, nullptr, nullptr, nullptr, 12, 768);
        bv_combine<<<dim3(16,8),256,0,stream>>>(PBV, PM, PL, BVTb);
        // ZBT[d][l'] = sum_l bvT[d][l] z6[l'][l]
        mg<2><<<dim3(4,1,8),256,0,stream>>>(BVTb,LMK,HSB, Z6,LMK,A2S, ZBT,LMK,HSB,
            DHEAD,LMK, nullptr, 1.f);
        // flash a1: Ob = softmax(q @ kl^T) @ zb + resconv(V)  (fused, bf16 out)
        flash<0><<<dim3(48,1,8),256,0,stream>>>(QKVb,3072,128, KL,DHEAD,HSB,
            ZBT,LMK,HSB, nullptr, nullptr, nullptr, Ob, QKVb, res_w[stage], 8, 0);
        // H += Ob @ out_w^T + out_b
        mg<3><<<dim3(8,48,1),256,0,stream>>>(Ob + (long long)PAD*DIM,DIM,0, OWB,DIM,0, H,DIM,0,
            NH,DIM, out_b[stage], 1.f);
        if (stage == 0) {
            float* F  = ws + OFF_QKVB;
            float* F2 = F + 6230016LL;
            h2f<<<dim3(191,32),dim3(32,8),0,stream>>>(H, F);
            ppeg_conv2<<<DIM,256,0,stream>>>(F, pw7, pb7, pw5, pb5, pw3, pb3, F2);
            f2h<<<dim3(32,191),dim3(32,8),0,stream>>>(F2, H);
        }
    }

    head_k<<<1,256,0,stream>>>(H, nf_g, nf_b, fc2w, fc2b, (float*)d_out);
}

// Round 8
// 2032.808 us; speedup vs baseline: 1.2859x; 1.2859x over previous
//
#include <hip/hip_runtime.h>
#include <hip/hip_bf16.h>

// ---------------- constants ----------------
#define NTOK   6000
#define INDIM  1536
#define DIM    1024
#define NPL    6144
#define PAD    59
#define NH     6085
#define HEADS  8
#define DHEAD  128
#define LMK    512
#define LSUB   12
#define HW     78
#define QSCALE 0.08838834764831845f

// ---------------- ws layout (float-slot offsets) ----------------
#define OFF_H     0LL          // 6144*1024 f32
#define OFF_LNXO  6291456LL    // LNXb bf16
#define OFF_QKVB  12582912LL   // 6144*3072 bf16; EO bf16 + PPEG planes alias
#define OFF_PBV   22020096LL   // 8h*512*8c*128 f32 = 4194304
#define OFF_PM    26214400LL   // 32768
#define OFF_PL    26247168LL   // 32768
#define OFF_OB    26279936LL   // 6144*1024 bf16 = 3145728 slots
#define OFF_VT    34603008LL   // 8*128*6144 bf16
#define OFF_QL    37748736LL
#define OFF_KL    38010880LL
#define OFF_A2F   38273024LL   // 8*512*512 f32
#define OFF_BVTB  40370176LL   // 8*128*512 bf16
#define OFF_XB    42467328LL   // bf16 8*512*512 each below
#define OFF_XZB   43515904LL
#define OFF_XZT7  44564480LL
#define OFF_PT15  45613056LL
#define OFF_QT13  46661632LL
#define OFF_ZB0   47710208LL
#define OFF_ZT0   48758784LL
#define OFF_ZB1   49807360LL
#define OFF_ZT1   50855936LL
#define OFF_ZBT   52428800LL   // 8*128*512 bf16
#define OFF_QWB   52690944LL   // 3072*1024 bf16
#define OFF_OWB   54263808LL   // 1024*1024 bf16
#define OFF_COLS  54788096LL
#define OFF_SCAL  54796288LL
// transient aliases (dead before overlapping buffers are written)
#define OFF_DATAB 31457280LL   // 6000*1536 bf16 (pre-stage only)
#define OFF_EWB   36065280LL   // 3072*1536 bf16 (pre-stage only)

typedef __attribute__((ext_vector_type(8))) short s16x8;
typedef __attribute__((ext_vector_type(4))) float f32x4;

// ---------------- bf16 helpers ----------------
__device__ __forceinline__ ushort f2b(float f) {
    union { float f; unsigned u; } v; v.f = f;
    return (ushort)((v.u + 0x7FFF + ((v.u >> 16) & 1)) >> 16);
}
__device__ __forceinline__ float b2f(ushort h) {
    union { unsigned u; float f; } v; v.u = ((unsigned)h) << 16; return v.f;
}

// async global->LDS, 16 bytes per lane; lds ptr must be wave-uniform
__device__ __forceinline__ void gld16(const void* g, void* l) {
    __builtin_amdgcn_global_load_lds((const __attribute__((address_space(1))) void*)g,
                                     (__attribute__((address_space(3))) void*)l, 16, 0, 0);
}

// ---------------- reductions (blockDim.x == 256) ----------------
__device__ __forceinline__ float blk_sum(float v) {
    __shared__ float sb[4];
    #pragma unroll
    for (int o = 32; o > 0; o >>= 1) v += __shfl_down(v, o);
    int lane = threadIdx.x & 63, w = threadIdx.x >> 6;
    __syncthreads();
    if (lane == 0) sb[w] = v;
    __syncthreads();
    return sb[0] + sb[1] + sb[2] + sb[3];
}
__device__ __forceinline__ float blk_max(float v) {
    __shared__ float sb[4];
    #pragma unroll
    for (int o = 32; o > 0; o >>= 1) v = fmaxf(v, __shfl_down(v, o));
    int lane = threadIdx.x & 63, w = threadIdx.x >> 6;
    __syncthreads();
    if (lane == 0) sb[w] = v;
    __syncthreads();
    return fmaxf(fmaxf(sb[0], sb[1]), fmaxf(sb[2], sb[3]));
}

// ================= MFMA GEMM (bf16 x bf16), C = alpha * A @ B^T =================
// EPI: 0 f32 | 1 bf16 qkv-scale | 2 bf16 | 3 f32 += v+bias
//      4 bf16 C + bf16 T[c][r]=tdelta*(r==c)+tsign*v | 5 T only
template<int EPI>
__global__ __launch_bounds__(256)
void mg(const ushort* __restrict__ A, int lda, long long sA,
        const ushort* __restrict__ B, int ldb, long long sB,
        void* __restrict__ Cp, int ldc, long long sC,
        void* __restrict__ Tp, int ldt, long long sT,
        int M, int K, const float* __restrict__ bias,
        float alpha, float tdelta, float tsign)
{
    __shared__ ushort As[4096];
    __shared__ ushort Bs[4096];
    const int t = threadIdx.x;
    const int z = blockIdx.z;
    const ushort* Ab = A + (long long)z * sA;
    const ushort* Bb = B + (long long)z * sB;
    const int row0 = blockIdx.y * 128, col0 = blockIdx.x * 128;
    const int w = t >> 6, lane = t & 63;
    const int l4 = lane >> 2, ls = (lane & 3) * 8;
    const int q0 = w, q1 = 4 + w;
    int ar0 = row0 + q0 * 16 + l4; if (ar0 >= M) ar0 = M - 1;
    int ar1 = row0 + q1 * 16 + l4; if (ar1 >= M) ar1 = M - 1;
    const int br0 = col0 + q0 * 16 + l4;
    const int br1 = col0 + q1 * 16 + l4;
    const ushort* ap0 = Ab + (long long)ar0 * lda + ls;
    const ushort* ap1 = Ab + (long long)ar1 * lda + ls;
    const ushort* bp0 = Bb + (long long)br0 * ldb + ls;
    const ushort* bp1 = Bb + (long long)br1 * ldb + ls;
    ushort* asl0 = &As[q0 * 512];
    ushort* asl1 = &As[q1 * 512];
    ushort* bsl0 = &Bs[q0 * 512];
    ushort* bsl1 = &Bs[q1 * 512];

    const int wr = (w >> 1) * 64, wc = (w & 1) * 64;
    const int fr = lane & 15, fo = (lane >> 4) * 8;

    f32x4 acc[4][4];
    #pragma unroll
    for (int a = 0; a < 4; a++)
        #pragma unroll
        for (int b = 0; b < 4; b++)
            acc[a][b] = (f32x4){0.f, 0.f, 0.f, 0.f};

    for (int kt = 0; kt < K; kt += 32) {
        gld16(ap0 + kt, asl0);
        gld16(ap1 + kt, asl1);
        gld16(bp0 + kt, bsl0);
        gld16(bp1 + kt, bsl1);
        __syncthreads();
        s16x8 af[4], bf[4];
        #pragma unroll
        for (int a = 0; a < 4; a++) af[a] = *(const s16x8*)&As[(wr + a * 16 + fr) * 32 + fo];
        #pragma unroll
        for (int b = 0; b < 4; b++) bf[b] = *(const s16x8*)&Bs[(wc + b * 16 + fr) * 32 + fo];
        #pragma unroll
        for (int a = 0; a < 4; a++)
            #pragma unroll
            for (int b = 0; b < 4; b++)
                acc[a][b] = __builtin_amdgcn_mfma_f32_16x16x32_bf16(af[a], bf[b], acc[a][b], 0, 0, 0);
        __syncthreads();
    }

    const int er0 = row0 + wr + ((lane >> 4) << 2);
    const int ec0 = col0 + wc + fr;
    #pragma unroll
    for (int a = 0; a < 4; a++) {
        #pragma unroll
        for (int j = 0; j < 4; j++) {
            int r = er0 + a * 16 + j;
            if (r >= M) continue;
            #pragma unroll
            for (int b = 0; b < 4; b++) {
                int c = ec0 + b * 16;
                float v = alpha * acc[a][b][j];
                long long ci = z * sC + (long long)r * ldc + c;
                if constexpr (EPI == 0) ((float*)Cp)[ci] = v;
                else if constexpr (EPI == 1) ((ushort*)Cp)[ci] = f2b(c < 1024 ? v * QSCALE : v);
                else if constexpr (EPI == 2) ((ushort*)Cp)[ci] = f2b(v);
                else if constexpr (EPI == 3) ((float*)Cp)[ci] += v + bias[c];
                else {
                    ushort tv = f2b((r == c ? tdelta : 0.f) + tsign * v);
                    long long ti = z * sT + (long long)c * ldt + r;
                    if constexpr (EPI == 4) { ((ushort*)Cp)[ci] = f2b(v); ((ushort*)Tp)[ti] = tv; }
                    else { ((ushort*)Tp)[ti] = tv; }  // 5
                }
            }
        }
    }
}

// ================= fused flash attention =================
// MODE 0: final bf16 output to Obp (+ fused depthwise-33 res conv of Vres); MODE 1: partials.
template<int MODE>
__global__ __launch_bounds__(256)
void flash(const ushort* __restrict__ Qp, int ldq, long long sQh,
           const ushort* __restrict__ Kp, int ldk, long long sKh,
           const ushort* __restrict__ Vp, int ldv, long long sVh,
           float* __restrict__ Op, float* __restrict__ Pm, float* __restrict__ Pl,
           ushort* __restrict__ Obp, const ushort* __restrict__ Vres, const float* __restrict__ rw,
           int nkv, int kvspan)
{
    __shared__ ushort Qs[16384];   // 4 subtiles [128][32]
    __shared__ ushort Zs[8192];    // 2 subtiles [128][32] (Vt chunk)
    __shared__ ushort KPs[8192];   // 4 subtiles [64][32] (K chunk); aliased by P [128][64] swizzled
    __shared__ float rws[33];
    ushort* Ps = KPs;
    const int t = threadIdx.x;
    const int h = blockIdx.z;
    const int q0 = blockIdx.x * 128;
    const int kvbase = blockIdx.y * kvspan;
    const ushort* Qb = Qp + (long long)h * sQh;
    const ushort* Kb = Kp + (long long)h * sKh;
    const ushort* Vb = Vp + (long long)h * sVh;
    const int w = t >> 6, lane = t & 63;
    const int sr = lane >> 2, sc2 = (lane & 3) * 8;
    const int fr = lane & 15, fo = (lane >> 4) * 8;
    const int jr = (lane >> 4) * 4;

    if (MODE == 0 && t < 33) rws[t] = rw[h * 33 + t];

    #pragma unroll
    for (int s = 0; s < 4; s++)
        #pragma unroll
        for (int r0 = 0; r0 < 128; r0 += 64)
            gld16(Qb + (long long)(q0 + r0 + w * 16 + sr) * ldq + s * 32 + sc2,
                  &Qs[s * 4096 + (r0 + w * 16) * 32]);

    f32x4 oa[2][8];
    float mold[2][4], lrun[2][4];
    #pragma unroll
    for (int fi = 0; fi < 2; fi++) {
        #pragma unroll
        for (int fj = 0; fj < 8; fj++) oa[fi][fj] = (f32x4){0.f,0.f,0.f,0.f};
        #pragma unroll
        for (int j = 0; j < 4; j++) { mold[fi][j] = -1e30f; lrun[fi][j] = 0.f; }
    }

    for (int c = 0; c < nkv; c++) {
        int kvp = kvbase + c * 64;
        #pragma unroll
        for (int s = 0; s < 4; s++)
            gld16(Kb + (long long)(kvp + w * 16 + sr) * ldk + s * 32 + sc2,
                  &KPs[s * 2048 + (w * 16) * 32]);
        #pragma unroll
        for (int s = 0; s < 2; s++)
            #pragma unroll
            for (int r0 = 0; r0 < 128; r0 += 64)
                gld16(Vb + (long long)(r0 + w * 16 + sr) * ldv + kvp + s * 32 + sc2,
                      &Zs[s * 4096 + (r0 + w * 16) * 32]);
        __syncthreads();

        f32x4 acc[2][4];
        #pragma unroll
        for (int fi = 0; fi < 2; fi++)
            #pragma unroll
            for (int fj = 0; fj < 4; fj++) acc[fi][fj] = (f32x4){0.f,0.f,0.f,0.f};
        #pragma unroll
        for (int ks = 0; ks < 4; ks++) {
            s16x8 qa[2], kb[4];
            #pragma unroll
            for (int fi = 0; fi < 2; fi++)
                qa[fi] = *(const s16x8*)&Qs[ks * 4096 + (w * 32 + fi * 16 + fr) * 32 + fo];
            #pragma unroll
            for (int fj = 0; fj < 4; fj++)
                kb[fj] = *(const s16x8*)&KPs[ks * 2048 + (fj * 16 + fr) * 32 + fo];
            #pragma unroll
            for (int fi = 0; fi < 2; fi++)
                #pragma unroll
                for (int fj = 0; fj < 4; fj++)
                    acc[fi][fj] = __builtin_amdgcn_mfma_f32_16x16x32_bf16(qa[fi], kb[fj], acc[fi][fj], 0, 0, 0);
        }

        float rs[2][4];
        #pragma unroll
        for (int fi = 0; fi < 2; fi++) {
            #pragma unroll
            for (int j = 0; j < 4; j++) {
                float mx = acc[fi][0][j];
                #pragma unroll
                for (int fj = 1; fj < 4; fj++) mx = fmaxf(mx, acc[fi][fj][j]);
                mx = fmaxf(mx, __shfl_xor(mx, 1));
                mx = fmaxf(mx, __shfl_xor(mx, 2));
                mx = fmaxf(mx, __shfl_xor(mx, 4));
                mx = fmaxf(mx, __shfl_xor(mx, 8));
                float mn = fmaxf(mold[fi][j], mx);
                float scl = __expf(mold[fi][j] - mn);
                mold[fi][j] = mn;
                lrun[fi][j] *= scl;
                #pragma unroll
                for (int fj = 0; fj < 8; fj++) oa[fi][fj][j] *= scl;
                float r = 0.f;
                #pragma unroll
                for (int fj = 0; fj < 4; fj++) {
                    float p = __expf(acc[fi][fj][j] - mn);
                    acc[fi][fj][j] = p;
                    r += p;
                }
                r += __shfl_xor(r, 1);
                r += __shfl_xor(r, 2);
                r += __shfl_xor(r, 4);
                r += __shfl_xor(r, 8);
                rs[fi][j] = r;
            }
        }
        __syncthreads();
        #pragma unroll
        for (int fi = 0; fi < 2; fi++)
            #pragma unroll
            for (int j = 0; j < 4; j++) {
                int row = w * 32 + fi * 16 + jr + j;
                lrun[fi][j] += rs[fi][j];
                #pragma unroll
                for (int fj = 0; fj < 4; fj++) {
                    int idx = (row * 64 + fj * 16 + fr) ^ ((row & 7) << 3);
                    Ps[idx] = f2b(acc[fi][fj][j]);
                }
            }
        __syncthreads();

        #pragma unroll
        for (int ks2 = 0; ks2 < 2; ks2++) {
            s16x8 pa[2], zb[8];
            #pragma unroll
            for (int fi = 0; fi < 2; fi++) {
                int row = w * 32 + fi * 16 + fr;
                int idx = (row * 64 + ks2 * 32 + fo) ^ ((row & 7) << 3);
                pa[fi] = *(const s16x8*)&Ps[idx];
            }
            #pragma unroll
            for (int fj = 0; fj < 8; fj++)
                zb[fj] = *(const s16x8*)&Zs[ks2 * 4096 + (fj * 16 + fr) * 32 + fo];
            #pragma unroll
            for (int fi = 0; fi < 2; fi++)
                #pragma unroll
                for (int fj = 0; fj < 8; fj++)
                    oa[fi][fj] = __builtin_amdgcn_mfma_f32_16x16x32_bf16(pa[fi], zb[fj], oa[fi][fj], 0, 0, 0);
        }
        __syncthreads();
    }

    // epilogue
    #pragma unroll
    for (int fi = 0; fi < 2; fi++)
        #pragma unroll
        for (int j = 0; j < 4; j++) {
            int row = w * 32 + fi * 16 + jr + j;
            if constexpr (MODE == 0) {
                float inv = 1.f / lrun[fi][j];
                int grow = q0 + row;
                float vv[8];
                #pragma unroll
                for (int fj = 0; fj < 8; fj++) vv[fj] = oa[fi][fj][j] * inv;
                // fused depthwise-33 res conv on Vres
                for (int tt = 0; tt < 33; tt++) {
                    int r = grow + tt - 16;
                    if ((unsigned)r < (unsigned)NPL) {
                        const ushort* p = Vres + (long long)r * 3072 + 2048 + h * 128;
                        float wv = rws[tt];
                        #pragma unroll
                        for (int fj = 0; fj < 8; fj++) vv[fj] += wv * b2f(p[fj * 16 + fr]);
                    }
                }
                #pragma unroll
                for (int fj = 0; fj < 8; fj++)
                    Obp[(long long)grow * DIM + h * 128 + fj * 16 + fr] = f2b(vv[fj]);
            } else {
                long long rb = (((long long)h * 512 + q0 + row) * 8 + blockIdx.y) * 128;
                #pragma unroll
                for (int fj = 0; fj < 8; fj++)
                    Op[rb + fj * 16 + fr] = oa[fi][fj][j];
                if (fr == 0) {
                    long long si = ((long long)h * 512 + q0 + row) * 8 + blockIdx.y;
                    Pm[si] = mold[fi][j];
                    Pl[si] = lrun[fi][j];
                }
            }
        }
}

// combine kv-split partials -> bvT bf16 [h][d][l]
__global__ __launch_bounds__(256)
void bv_combine(const float* __restrict__ PBV, const float* __restrict__ Pm,
                const float* __restrict__ Pl, ushort* __restrict__ BVTb)
{
    __shared__ float T[32][129];
    __shared__ float wc8[32][8], invL[32];
    int t = threadIdx.x;
    int h = blockIdx.y, l0 = blockIdx.x * 32;
    if (t < 32) {
        long long base = ((long long)h * 512 + l0 + t) * 8;
        float m = -1e30f;
        float mv[8], lv[8];
        #pragma unroll
        for (int c = 0; c < 8; c++) { mv[c] = Pm[base + c]; lv[c] = Pl[base + c]; m = fmaxf(m, mv[c]); }
        float L = 0.f;
        #pragma unroll
        for (int c = 0; c < 8; c++) { float wv = __expf(mv[c] - m); wc8[t][c] = wv; L += wv * lv[c]; }
        invL[t] = 1.f / L;
    }
    __syncthreads();
    int l = t >> 3, dg = t & 7;
    long long rbase = ((long long)h * 512 + l0 + l) * 8 * 128;
    #pragma unroll
    for (int dd = 0; dd < 16; dd++) {
        int d = dg * 16 + dd;
        float s = 0.f;
        #pragma unroll
        for (int c = 0; c < 8; c++) s += wc8[l][c] * PBV[rbase + c * 128 + d];
        T[l][d] = s * invL[l];
    }
    __syncthreads();
    int d = t >> 1, half = t & 1;
    #pragma unroll
    for (int lc = 0; lc < 16; lc++) {
        int l2 = half * 16 + lc;
        BVTb[(long long)h * 65536 + (long long)d * 512 + l0 + l2] = f2b(T[l2][d]);
    }
}

// ---------------- f32 -> bf16 convert ----------------
__global__ __launch_bounds__(256)
void cvt_bf16(const float* __restrict__ x, ushort* __restrict__ y, long long n)
{
    long long i = ((long long)blockIdx.x * 256 + threadIdx.x) * 8;
    if (i >= n) return;
    float4 a = *(const float4*)(x + i), b = *(const float4*)(x + i + 4);
    ushort4 u0 = {f2b(a.x), f2b(a.y), f2b(a.z), f2b(a.w)};
    ushort4 u1 = {f2b(b.x), f2b(b.y), f2b(b.z), f2b(b.w)};
    *(ushort4*)(y + i) = u0; *(ushort4*)(y + i + 4) = u1;
}

// ---------------- softmax fp32 rows (W = NIT*256) ----------------
template<int NIT>
__global__ __launch_bounds__(256)
void softmax_rows(float* __restrict__ X, int W)
{
    long long row = blockIdx.x;
    float* x = X + row * W;
    float r[NIT];
    float m = -1e30f;
    #pragma unroll
    for (int i = 0; i < NIT; i++) { r[i] = x[threadIdx.x + i * 256]; m = fmaxf(m, r[i]); }
    m = blk_max(m);
    float s = 0.f;
    #pragma unroll
    for (int i = 0; i < NIT; i++) { r[i] = __expf(r[i] - m); s += r[i]; }
    s = blk_sum(s);
    float inv = 1.f / s;
    #pragma unroll
    for (int i = 0; i < NIT; i++) x[threadIdx.x + i * 256] = r[i] * inv;
}

// ---------------- LN + front-pad -> bf16 ----------------
__global__ __launch_bounds__(256)
void ln_pad(const float* __restrict__ H, const float* __restrict__ g,
            const float* __restrict__ b, ushort* __restrict__ X)
{
    int row = blockIdx.x, t = threadIdx.x;
    ushort* o = X + (long long)row * DIM;
    if (row < PAD) {
        #pragma unroll
        for (int i = 0; i < 4; i++) o[t + i * 256] = 0;
        return;
    }
    const float* x = H + (long long)(row - PAD) * DIM;
    float r[4]; float s = 0.f;
    #pragma unroll
    for (int i = 0; i < 4; i++) { r[i] = x[t + i * 256]; s += r[i]; }
    float mu = blk_sum(s) * (1.f / DIM);
    float v = 0.f;
    #pragma unroll
    for (int i = 0; i < 4; i++) { float d = r[i] - mu; v += d * d; }
    float var = blk_sum(v) * (1.f / DIM);
    float rs = rsqrtf(var + 1e-5f);
    #pragma unroll
    for (int i = 0; i < 4; i++) { int c = t + i * 256; o[c] = f2b((r[i] - mu) * rs * g[c] + b[c]); }
}

// ---------------- landmarks ----------------
__global__ __launch_bounds__(128)
void landmarks(const ushort* __restrict__ QKVb, ushort* __restrict__ QL, ushort* __restrict__ KL)
{
    int L = blockIdx.x, h = blockIdx.y, d = threadIdx.x;
    float sq = 0.f, sk = 0.f;
    #pragma unroll
    for (int j = 0; j < LSUB; j++) {
        const ushort* p = QKVb + (long long)(L * LSUB + j) * 3072 + h * DHEAD + d;
        sq += b2f(p[0]);
        sk += b2f(p[1024]);
    }
    QL[(long long)(h * LMK + L) * DHEAD + d] = f2b(sq * (1.f / LSUB));
    KL[(long long)(h * LMK + L) * DHEAD + d] = f2b(sk * (1.f / LSUB));
}

// ---------------- V transpose -> bf16 VT[h][d][i] ----------------
__global__ void vtrans(const ushort* __restrict__ Q, ushort* __restrict__ VT)
{
    __shared__ ushort tile[32][33];
    int h = blockIdx.z, i0 = blockIdx.x * 32, d0 = blockIdx.y * 32;
    int tx = threadIdx.x, ty = threadIdx.y;
    for (int yy = ty; yy < 32; yy += 8)
        tile[yy][tx] = Q[(long long)(i0 + yy) * 3072 + 2048 + h * 128 + d0 + tx];
    __syncthreads();
    for (int yy = ty; yy < 32; yy += 8)
        VT[((long long)h * 128 + d0 + yy) * 6144 + i0 + tx] = tile[tx][yy];
}

// ---------------- a2 column sums ----------------
__global__ __launch_bounds__(256)
void a2_sums2(const float* __restrict__ A2, float* __restrict__ cols)
{
    int h = blockIdx.x, slice = blockIdx.y, t = threadIdx.x;
    const float* a = A2 + (long long)h * LMK * LMK + (long long)slice * 64 * LMK;
    float s0 = 0.f, s1 = 0.f;
    #pragma unroll 4
    for (int i = 0; i < 64; i++) {
        s0 += a[(long long)i * LMK + t];
        s1 += a[(long long)i * LMK + t + 256];
    }
    atomicAdd(&cols[h * LMK + t], s0);
    atomicAdd(&cols[h * LMK + t + 256], s1);
}
__global__ __launch_bounds__(256)
void a2_scal2(const float* __restrict__ cols, float* __restrict__ scal)
{
    float mc = -1e30f;
    for (int i = threadIdx.x; i < HEADS * LMK; i += 256) mc = fmaxf(mc, cols[i]);
    mc = blk_max(mc);
    if (threadIdx.x == 0) scal[0] = 1.f / mc;
}

// ---------------- z0/X prep ----------------
__global__ void z0_t(const float* __restrict__ A2, ushort* __restrict__ Xb,
                     ushort* __restrict__ Z0b, ushort* __restrict__ Z0T,
                     const float* __restrict__ scal)
{
    __shared__ float tile[32][33];
    int h = blockIdx.z;
    const float* a = A2 + (long long)h * LMK * LMK;
    float s = scal[0];
    int x0 = blockIdx.x * 32, y0 = blockIdx.y * 32;
    int tx = threadIdx.x, ty = threadIdx.y;
    long long hb = (long long)h * LMK * LMK;
    for (int yy = ty; yy < 32; yy += 8) {
        float v = a[(long long)(y0 + yy) * LMK + x0 + tx];
        tile[yy][tx] = v;
        Xb [hb + (long long)(y0 + yy) * LMK + x0 + tx] = f2b(v);
        Z0T[hb + (long long)(y0 + yy) * LMK + x0 + tx] = f2b(s * v);
    }
    __syncthreads();
    for (int yy = ty; yy < 32; yy += 8)
        Z0b[hb + (long long)(x0 + yy) * LMK + y0 + tx] = f2b(s * tile[tx][yy]);
}

// ---------------- MoE ----------------
__global__ __launch_bounds__(256)
void moe_combine(const float* __restrict__ X, const float* __restrict__ wg,
                 const ushort* __restrict__ EO, const float* __restrict__ eb,
                 float* __restrict__ H)
{
    int i = blockIdx.x, t = threadIdx.x;
    const float* x = X + (long long)i * INDIM;
    float g0 = 0.f, g1 = 0.f, g2 = 0.f;
    for (int f = t; f < INDIM; f += 256) {
        float xv = x[f];
        const float* w = wg + f * 3;
        g0 += xv * w[0]; g1 += xv * w[1]; g2 += xv * w[2];
    }
    g0 = blk_sum(g0); g1 = blk_sum(g1); g2 = blk_sum(g2);
    float m = fmaxf(g0, fmaxf(g1, g2));
    float e0 = __expf(g0 - m), e1 = __expf(g1 - m), e2 = __expf(g2 - m);
    float inv = 1.f / (e0 + e1 + e2);
    e0 *= inv; e1 *= inv; e2 *= inv;
    const ushort* eo = EO + (long long)i * 3072;
    for (int o = t; o < DIM; o += 256) {
        float v0 = fmaxf(b2f(eo[o])        + eb[o],        0.f);
        float v1 = fmaxf(b2f(eo[1024 + o]) + eb[1024 + o], 0.f);
        float v2 = fmaxf(b2f(eo[2048 + o]) + eb[2048 + o], 0.f);
        float r = e0 * v0 + e1 * v1 + e2 * v2;
        H[(long long)(1 + i) * DIM + o] = r;
        if (i < 84) H[(long long)(6001 + i) * DIM + o] = r;
    }
}

__global__ void cls_copy(const float* __restrict__ c, float* __restrict__ H)
{
    for (int i = threadIdx.x; i < DIM; i += 256) H[i] = c[i];
}

// ---------------- PPEG ----------------
__global__ void h2f(const float* __restrict__ H, float* __restrict__ F)
{
    __shared__ float tile[32][33];
    int p0 = blockIdx.x * 32, c0 = blockIdx.y * 32;
    int tx = threadIdx.x, ty = threadIdx.y;
    for (int yy = ty; yy < 32; yy += 8) {
        int p = p0 + yy;
        if (p < HW * HW) tile[yy][tx] = H[(long long)(1 + p) * DIM + c0 + tx];
    }
    __syncthreads();
    for (int yy = ty; yy < 32; yy += 8) {
        int p = p0 + tx, c = c0 + yy;
        if (p < HW * HW) F[(long long)c * (HW * HW) + p] = tile[tx][yy];
    }
}
__global__ void f2h(const float* __restrict__ F2, float* __restrict__ H)
{
    __shared__ float tile[32][33];
    int c0 = blockIdx.x * 32, p0 = blockIdx.y * 32;
    int tx = threadIdx.x, ty = threadIdx.y;
    for (int yy = ty; yy < 32; yy += 8) {
        int p = p0 + tx;
        if (p < HW * HW) tile[yy][tx] = F2[(long long)(c0 + yy) * (HW * HW) + p];
    }
    __syncthreads();
    for (int yy = ty; yy < 32; yy += 8) {
        int p = p0 + yy;
        if (p < HW * HW) H[(long long)(1 + p) * DIM + c0 + tx] = tile[tx][yy];
    }
}
__global__ __launch_bounds__(256)
void ppeg_conv2(const float* __restrict__ F,
                const float* __restrict__ w7, const float* __restrict__ b7,
                const float* __restrict__ w5, const float* __restrict__ b5,
                const float* __restrict__ w3, const float* __restrict__ b3,
                float* __restrict__ F2)
{
    int c = blockIdx.x, t = threadIdx.x;
    __shared__ float plane[HW * HW];
    __shared__ float wm[49];
    for (int p = t; p < HW * HW; p += 256) plane[p] = F[(long long)c * (HW * HW) + p];
    if (t < 49) {
        int ky = t / 7 - 3, kx = t % 7 - 3;
        float w = w7[(long long)c * 49 + t];
        if (ky >= -2 && ky <= 2 && kx >= -2 && kx <= 2) w += w5[(long long)c * 25 + (ky + 2) * 5 + (kx + 2)];
        if (ky >= -1 && ky <= 1 && kx >= -1 && kx <= 1) w += w3[(long long)c * 9 + (ky + 1) * 3 + (kx + 1)];
        if (t == 24) w += 1.0f;
        wm[t] = w;
    }
    __syncthreads();
    float bsum = b7[c] + b5[c] + b3[c];
    for (int p = t; p < HW * HW; p += 256) {
        int y = p / HW, x = p - y * HW;
        float acc = bsum;
        if (y >= 3 && y < HW - 3 && x >= 3 && x < HW - 3) {
            const float* base = &plane[p];
            #pragma unroll
            for (int ky = -3; ky <= 3; ky++)
                #pragma unroll
                for (int kx = -3; kx <= 3; kx++)
                    acc += wm[(ky + 3) * 7 + kx + 3] * base[ky * HW + kx];
        } else {
            for (int ky = -3; ky <= 3; ky++) {
                int yy = y + ky; if ((unsigned)yy >= (unsigned)HW) continue;
                for (int kx = -3; kx <= 3; kx++) {
                    int xx = x + kx; if ((unsigned)xx >= (unsigned)HW) continue;
                    acc += wm[(ky + 3) * 7 + kx + 3] * plane[yy * HW + xx];
                }
            }
        }
        F2[(long long)c * (HW * HW) + p] = acc;
    }
}

// ---------------- final head ----------------
__global__ __launch_bounds__(256)
void head_k(const float* __restrict__ H, const float* __restrict__ g, const float* __restrict__ b,
            const float* __restrict__ fw, const float* __restrict__ fb, float* __restrict__ out)
{
    int t = threadIdx.x;
    float r[4]; float s = 0.f;
    #pragma unroll
    for (int i = 0; i < 4; i++) { r[i] = H[t + i * 256]; s += r[i]; }
    float mu = blk_sum(s) * (1.f / DIM);
    float v = 0.f;
    #pragma unroll
    for (int i = 0; i < 4; i++) { float d = r[i] - mu; v += d * d; }
    float var = blk_sum(v) * (1.f / DIM);
    float rs = rsqrtf(var + 1e-5f);
    float d0 = 0.f, d1 = 0.f;
    #pragma unroll
    for (int i = 0; i < 4; i++) {
        int c = t + i * 256;
        float hv = (r[i] - mu) * rs * g[c] + b[c];
        d0 += hv * fw[c];
        d1 += hv * fw[DIM + c];
    }
    d0 = blk_sum(d0); d1 = blk_sum(d1);
    if (t == 0) {
        float l0 = d0 + fb[0], l1 = d1 + fb[1];
        float m = fmaxf(l0, l1);
        float e0 = __expf(l0 - m), e1 = __expf(l1 - m);
        float inv = 1.f / (e0 + e1);
        out[0] = l0; out[1] = l1;
        out[2] = e0 * inv; out[3] = e1 * inv;
        out[4] = (l1 > l0) ? 1.0f : 0.0f;
    }
}

// ---------------- host ----------------
extern "C" void kernel_launch(void* const* d_in, const int* in_sizes, int n_in,
                              void* d_out, int out_size, void* d_ws, size_t ws_size,
                              hipStream_t stream)
{
    const float* data     = (const float*)d_in[0];
    const float* w_gate   = (const float*)d_in[1];
    const float* expert_w = (const float*)d_in[2];
    const float* expert_b = (const float*)d_in[3];
    const float* cls_tok  = (const float*)d_in[4];
    const float* ln_g[2]  = {(const float*)d_in[5],  (const float*)d_in[11]};
    const float* ln_b[2]  = {(const float*)d_in[6],  (const float*)d_in[12]};
    const float* qkv_w[2] = {(const float*)d_in[7],  (const float*)d_in[13]};
    const float* out_w[2] = {(const float*)d_in[8],  (const float*)d_in[14]};
    const float* out_b[2] = {(const float*)d_in[9],  (const float*)d_in[15]};
    const float* res_w[2] = {(const float*)d_in[10], (const float*)d_in[16]};
    const float* pw7 = (const float*)d_in[17]; const float* pb7 = (const float*)d_in[18];
    const float* pw5 = (const float*)d_in[19]; const float* pb5 = (const float*)d_in[20];
    const float* pw3 = (const float*)d_in[21]; const float* pb3 = (const float*)d_in[22];
    const float* nf_g = (const float*)d_in[23]; const float* nf_b = (const float*)d_in[24];
    const float* fc2w = (const float*)d_in[25]; const float* fc2b = (const float*)d_in[26];

    float*  ws    = (float*)d_ws;
    float*  H     = ws + OFF_H;
    ushort* LNXb  = (ushort*)(ws + OFF_LNXO);
    ushort* QKVb  = (ushort*)(ws + OFF_QKVB);
    ushort* EOb   = (ushort*)(ws + OFF_QKVB);
    float*  PBV   = ws + OFF_PBV;
    float*  PM    = ws + OFF_PM;
    float*  PL    = ws + OFF_PL;
    ushort* Ob    = (ushort*)(ws + OFF_OB);
    ushort* VT    = (ushort*)(ws + OFF_VT);
    ushort* QL    = (ushort*)(ws + OFF_QL);
    ushort* KL    = (ushort*)(ws + OFF_KL);
    float*  A2F   = ws + OFF_A2F;
    ushort* BVTb  = (ushort*)(ws + OFF_BVTB);
    ushort* Xb    = (ushort*)(ws + OFF_XB);
    ushort* XZB   = (ushort*)(ws + OFF_XZB);
    ushort* XZT7  = (ushort*)(ws + OFF_XZT7);
    ushort* PT15  = (ushort*)(ws + OFF_PT15);
    ushort* QT13  = (ushort*)(ws + OFF_QT13);
    ushort* ZB[2] = {(ushort*)(ws + OFF_ZB0), (ushort*)(ws + OFF_ZB1)};
    ushort* ZT[2] = {(ushort*)(ws + OFF_ZT0), (ushort*)(ws + OFF_ZT1)};
    ushort* ZBT   = (ushort*)(ws + OFF_ZBT);
    ushort* QWB   = (ushort*)(ws + OFF_QWB);
    ushort* OWB   = (ushort*)(ws + OFF_OWB);
    ushort* DATAB = (ushort*)(ws + OFF_DATAB);
    ushort* EWB   = (ushort*)(ws + OFF_EWB);
    float*  COLS  = ws + OFF_COLS;
    float*  SCAL  = ws + OFF_SCAL;

    const long long HSB = (long long)LMK * DHEAD;   // 65536
    const long long A2S = (long long)LMK * LMK;     // 262144

    // ---- MoE ----
    cvt_bf16<<<4500, 256, 0, stream>>>(data, DATAB, (long long)NTOK * INDIM);
    cvt_bf16<<<2304, 256, 0, stream>>>(expert_w, EWB, 3072LL * INDIM);
    mg<2><<<dim3(24,47,1),256,0,stream>>>(DATAB,INDIM,0, EWB,INDIM,0, EOb,3072,0,
        nullptr,0,0, NTOK,INDIM, nullptr, 1.f,0.f,0.f);
    moe_combine<<<NTOK,256,0,stream>>>(data, w_gate, EOb, expert_b, H);
    cls_copy<<<1,256,0,stream>>>(cls_tok, H);

    for (int stage = 0; stage < 2; stage++) {
        cvt_bf16<<<1536, 256, 0, stream>>>(qkv_w[stage], QWB, 3072LL * DIM);
        cvt_bf16<<<512, 256, 0, stream>>>(out_w[stage], OWB, (long long)DIM * DIM);
        ln_pad<<<NPL,256,0,stream>>>(H, ln_g[stage], ln_b[stage], LNXb);
        mg<1><<<dim3(24,48,1),256,0,stream>>>(LNXb,DIM,0, QWB,DIM,0, QKVb,3072,0,
            nullptr,0,0, NPL,DIM, nullptr, 1.f,0.f,0.f);
        landmarks<<<dim3(LMK,HEADS),128,0,stream>>>(QKVb, QL, KL);
        vtrans<<<dim3(192,4,8),dim3(32,8),0,stream>>>(QKVb, VT);
        // a2 = softmax(ql @ kl^T) f32
        mg<0><<<dim3(4,4,8),256,0,stream>>>(QL,DHEAD,HSB, KL,DHEAD,HSB, A2F,LMK,A2S,
            nullptr,0,0, LMK,DHEAD, nullptr, 1.f,0.f,0.f);
        softmax_rows<2><<<HEADS*LMK,256,0,stream>>>(A2F, LMK);
        hipMemsetAsync(COLS, 0, HEADS * LMK * sizeof(float), stream);
        a2_sums2<<<dim3(HEADS,8),256,0,stream>>>(A2F, COLS);
        a2_scal2<<<1,256,0,stream>>>(COLS, SCAL);
        z0_t<<<dim3(16,16,8),dim3(32,8),0,stream>>>(A2F, Xb, ZB[0], ZT[0], SCAL);
        // Newton-Schulz: 6 iterations, separate launches (L2-resident between dispatches)
        int cur = 0;
        for (int it = 0; it < 6; it++) {
            mg<4><<<dim3(4,4,8),256,0,stream>>>(Xb,LMK,A2S, ZT[cur],LMK,A2S, XZB,LMK,A2S,
                XZT7,LMK,A2S, LMK,LMK, nullptr, 1.f, 7.f, -1.f);
            mg<5><<<dim3(4,4,8),256,0,stream>>>(XZB,LMK,A2S, XZT7,LMK,A2S, nullptr,0,0,
                PT15,LMK,A2S, LMK,LMK, nullptr, 1.f, 15.f, -1.f);
            mg<5><<<dim3(4,4,8),256,0,stream>>>(XZB,LMK,A2S, PT15,LMK,A2S, nullptr,0,0,
                QT13,LMK,A2S, LMK,LMK, nullptr, 1.f, 13.f, -1.f);
            if (it < 5)
                mg<4><<<dim3(4,4,8),256,0,stream>>>(ZB[cur],LMK,A2S, QT13,LMK,A2S, ZB[1-cur],LMK,A2S,
                    ZT[1-cur],LMK,A2S, LMK,LMK, nullptr, 0.25f, 0.f, 1.f);
            else
                mg<2><<<dim3(4,4,8),256,0,stream>>>(ZB[cur],LMK,A2S, QT13,LMK,A2S, ZB[1-cur],LMK,A2S,
                    nullptr,0,0, LMK,LMK, nullptr, 0.25f, 0.f, 1.f);
            cur = 1 - cur;
        }
        ushort* Z6 = ZB[cur];
        // flash a3: partial bv over 8 kv-chunks of 768
        flash<1><<<dim3(4,8,8),256,0,stream>>>(QL,DHEAD,HSB, QKVb+1024,3072,128,
            VT,NPL,(long long)DHEAD*NPL, PBV, PM, PL, nullptr, nullptr, nullptr, 12, 768);
        bv_combine<<<dim3(16,8),256,0,stream>>>(PBV, PM, PL, BVTb);
        // ZBT[d][l'] = sum_l bvT[d][l] z6[l'][l]
        mg<2><<<dim3(4,1,8),256,0,stream>>>(BVTb,LMK,HSB, Z6,LMK,A2S, ZBT,LMK,HSB,
            nullptr,0,0, DHEAD,LMK, nullptr, 1.f,0.f,0.f);
        // flash a1: Ob = softmax(q @ kl^T) @ zb + resconv(V)  (fused, bf16 out)
        flash<0><<<dim3(48,1,8),256,0,stream>>>(QKVb,3072,128, KL,DHEAD,HSB,
            ZBT,LMK,HSB, nullptr, nullptr, nullptr, Ob, QKVb, res_w[stage], 8, 0);
        // H += Ob @ out_w^T + out_b
        mg<3><<<dim3(8,48,1),256,0,stream>>>(Ob + (long long)PAD*DIM,DIM,0, OWB,DIM,0, H,DIM,0,
            nullptr,0,0, NH,DIM, out_b[stage], 1.f,0.f,0.f);
        if (stage == 0) {
            float* F  = ws + OFF_QKVB;
            float* F2 = F + 6230016LL;
            h2f<<<dim3(191,32),dim3(32,8),0,stream>>>(H, F);
            ppeg_conv2<<<DIM,256,0,stream>>>(F, pw7, pb7, pw5, pb5, pw3, pb3, F2);
            f2h<<<dim3(32,191),dim3(32,8),0,stream>>>(F2, H);
        }
    }

    head_k<<<1,256,0,stream>>>(H, nf_g, nf_b, fc2w, fc2b, (float*)d_out);
}

// Round 9
// 1981.476 us; speedup vs baseline: 1.3192x; 1.0259x over previous
//
#include <hip/hip_runtime.h>
#include <hip/hip_bf16.h>

// ---------------- constants ----------------
#define NTOK   6000
#define INDIM  1536
#define DIM    1024
#define NPL    6144
#define PAD    59
#define NH     6085
#define HEADS  8
#define DHEAD  128
#define LMK    512
#define LSUB   12
#define HW     78
#define QSCALE 0.08838834764831845f
#define NSPLIT 16

// ---------------- ws layout (float-slot offsets) ----------------
#define OFF_H     0LL          // 6144*1024 f32
#define OFF_LNXO  6291456LL    // LNXb bf16 / O f32 alias
#define OFF_QKVB  12582912LL   // 6144*3072 bf16; EO bf16 + PPEG planes alias
#define OFF_PBV   22020096LL   // 8h*512*16c*128 f32 = 8388608
#define OFF_PM    30408704LL   // 65536
#define OFF_PL    30474240LL   // 65536
#define OFF_OB    30539776LL   // 6144*1024 bf16 = 3145728 slots (ends 33685504)
#define OFF_VT    34603008LL   // 8*128*6144 bf16
#define OFF_QL    37748736LL
#define OFF_KL    38010880LL
#define OFF_A2F   38273024LL   // 8*512*512 f32
#define OFF_BVTB  40370176LL   // 8*128*512 bf16
#define OFF_XB    42467328LL   // bf16 8*512*512 each below
#define OFF_XZB   43515904LL
#define OFF_XZT7  44564480LL
#define OFF_PT15  45613056LL
#define OFF_QT13  46661632LL
#define OFF_ZB0   47710208LL
#define OFF_ZT0   48758784LL
#define OFF_ZB1   49807360LL
#define OFF_ZT1   50855936LL
#define OFF_ZBT   52428800LL   // 8*128*512 bf16
#define OFF_QWB   52690944LL   // 3072*1024 bf16
#define OFF_OWB   54263808LL   // 1024*1024 bf16
#define OFF_COLS  54788096LL
#define OFF_SCAL  54796288LL
// transient aliases (dead before overlapping buffers are written)
#define OFF_DATAB 31457280LL   // 6000*1536 bf16 (pre-stage only; overlaps OB/VT span)
#define OFF_EWB   36065280LL   // 3072*1536 bf16 (pre-stage only)

typedef __attribute__((ext_vector_type(8))) short s16x8;
typedef __attribute__((ext_vector_type(4))) float f32x4;

// ---------------- bf16 helpers ----------------
__device__ __forceinline__ ushort f2b(float f) {
    union { float f; unsigned u; } v; v.f = f;
    return (ushort)((v.u + 0x7FFF + ((v.u >> 16) & 1)) >> 16);
}
__device__ __forceinline__ float b2f(ushort h) {
    union { unsigned u; float f; } v; v.u = ((unsigned)h) << 16; return v.f;
}

// async global->LDS, 16 bytes per lane; lds ptr must be wave-uniform
__device__ __forceinline__ void gld16(const void* g, void* l) {
    __builtin_amdgcn_global_load_lds((const __attribute__((address_space(1))) void*)g,
                                     (__attribute__((address_space(3))) void*)l, 16, 0, 0);
}

// ---------------- reductions (blockDim.x == 256) ----------------
__device__ __forceinline__ float blk_sum(float v) {
    __shared__ float sb[4];
    #pragma unroll
    for (int o = 32; o > 0; o >>= 1) v += __shfl_down(v, o);
    int lane = threadIdx.x & 63, w = threadIdx.x >> 6;
    __syncthreads();
    if (lane == 0) sb[w] = v;
    __syncthreads();
    return sb[0] + sb[1] + sb[2] + sb[3];
}
__device__ __forceinline__ float blk_max(float v) {
    __shared__ float sb[4];
    #pragma unroll
    for (int o = 32; o > 0; o >>= 1) v = fmaxf(v, __shfl_down(v, o));
    int lane = threadIdx.x & 63, w = threadIdx.x >> 6;
    __syncthreads();
    if (lane == 0) sb[w] = v;
    __syncthreads();
    return fmaxf(fmaxf(sb[0], sb[1]), fmaxf(sb[2], sb[3]));
}

// ================= MFMA GEMM (bf16 x bf16), C = alpha * A @ B^T =================
// EPI: 0 f32 | 1 bf16 qkv-scale | 2 bf16 | 3 f32 += v+bias
//      4 bf16 C + bf16 T[c][r]=tdelta*(r==c)+tsign*v | 5 T only
template<int EPI>
__global__ __launch_bounds__(256)
void mg(const ushort* __restrict__ A, int lda, long long sA,
        const ushort* __restrict__ B, int ldb, long long sB,
        void* __restrict__ Cp, int ldc, long long sC,
        void* __restrict__ Tp, int ldt, long long sT,
        int M, int K, const float* __restrict__ bias,
        float alpha, float tdelta, float tsign)
{
    __shared__ ushort As[4096];
    __shared__ ushort Bs[4096];
    const int t = threadIdx.x;
    const int z = blockIdx.z;
    const ushort* Ab = A + (long long)z * sA;
    const ushort* Bb = B + (long long)z * sB;
    const int row0 = blockIdx.y * 128, col0 = blockIdx.x * 128;
    const int w = t >> 6, lane = t & 63;
    const int l4 = lane >> 2, ls = (lane & 3) * 8;
    const int q0 = w, q1 = 4 + w;
    int ar0 = row0 + q0 * 16 + l4; if (ar0 >= M) ar0 = M - 1;
    int ar1 = row0 + q1 * 16 + l4; if (ar1 >= M) ar1 = M - 1;
    const int br0 = col0 + q0 * 16 + l4;
    const int br1 = col0 + q1 * 16 + l4;
    const ushort* ap0 = Ab + (long long)ar0 * lda + ls;
    const ushort* ap1 = Ab + (long long)ar1 * lda + ls;
    const ushort* bp0 = Bb + (long long)br0 * ldb + ls;
    const ushort* bp1 = Bb + (long long)br1 * ldb + ls;
    ushort* asl0 = &As[q0 * 512];
    ushort* asl1 = &As[q1 * 512];
    ushort* bsl0 = &Bs[q0 * 512];
    ushort* bsl1 = &Bs[q1 * 512];

    const int wr = (w >> 1) * 64, wc = (w & 1) * 64;
    const int fr = lane & 15, fo = (lane >> 4) * 8;

    f32x4 acc[4][4];
    #pragma unroll
    for (int a = 0; a < 4; a++)
        #pragma unroll
        for (int b = 0; b < 4; b++)
            acc[a][b] = (f32x4){0.f, 0.f, 0.f, 0.f};

    for (int kt = 0; kt < K; kt += 32) {
        gld16(ap0 + kt, asl0);
        gld16(ap1 + kt, asl1);
        gld16(bp0 + kt, bsl0);
        gld16(bp1 + kt, bsl1);
        __syncthreads();
        s16x8 af[4], bf[4];
        #pragma unroll
        for (int a = 0; a < 4; a++) af[a] = *(const s16x8*)&As[(wr + a * 16 + fr) * 32 + fo];
        #pragma unroll
        for (int b = 0; b < 4; b++) bf[b] = *(const s16x8*)&Bs[(wc + b * 16 + fr) * 32 + fo];
        #pragma unroll
        for (int a = 0; a < 4; a++)
            #pragma unroll
            for (int b = 0; b < 4; b++)
                acc[a][b] = __builtin_amdgcn_mfma_f32_16x16x32_bf16(af[a], bf[b], acc[a][b], 0, 0, 0);
        __syncthreads();
    }

    const int er0 = row0 + wr + ((lane >> 4) << 2);
    const int ec0 = col0 + wc + fr;
    #pragma unroll
    for (int a = 0; a < 4; a++) {
        #pragma unroll
        for (int j = 0; j < 4; j++) {
            int r = er0 + a * 16 + j;
            if (r >= M) continue;
            #pragma unroll
            for (int b = 0; b < 4; b++) {
                int c = ec0 + b * 16;
                float v = alpha * acc[a][b][j];
                long long ci = z * sC + (long long)r * ldc + c;
                if constexpr (EPI == 0) ((float*)Cp)[ci] = v;
                else if constexpr (EPI == 1) ((ushort*)Cp)[ci] = f2b(c < 1024 ? v * QSCALE : v);
                else if constexpr (EPI == 2) ((ushort*)Cp)[ci] = f2b(v);
                else if constexpr (EPI == 3) ((float*)Cp)[ci] += v + bias[c];
                else {
                    ushort tv = f2b((r == c ? tdelta : 0.f) + tsign * v);
                    long long ti = z * sT + (long long)c * ldt + r;
                    if constexpr (EPI == 4) { ((ushort*)Cp)[ci] = f2b(v); ((ushort*)Tp)[ti] = tv; }
                    else { ((ushort*)Tp)[ti] = tv; }  // 5
                }
            }
        }
    }
}

// ================= fused flash attention =================
// Q in registers; q tile = NFI*64 rows (wave owns NFI*16 rows); KV chunks of 64.
// MODE 0: final f32 output to Op (cols h*128..); MODE 1: partial (acc,m,l) per kv-split.
template<int MODE, int NFI>
__global__ __launch_bounds__(256)
void flash(const ushort* __restrict__ Qp, int ldq, long long sQh,
           const ushort* __restrict__ Kp, int ldk, long long sKh,
           const ushort* __restrict__ Vp, int ldv, long long sVh,
           float* __restrict__ Op, float* __restrict__ Pm, float* __restrict__ Pl,
           int nkv, int kvspan)
{
    __shared__ ushort Zs[8192];    // 2 subtiles [128][32] (Vt chunk)
    __shared__ ushort KPs[8192];   // 4 subtiles [64][32] (K chunk); aliased by P [NFI*64][64] swizzled
    ushort* Ps = KPs;
    const int t = threadIdx.x;
    const int h = blockIdx.z;
    const int q0 = blockIdx.x * (NFI * 64);
    const int kvbase = blockIdx.y * kvspan;
    const ushort* Qb = Qp + (long long)h * sQh;
    const ushort* Kb = Kp + (long long)h * sKh;
    const ushort* Vb = Vp + (long long)h * sVh;
    const int w = t >> 6, lane = t & 63;
    const int sr = lane >> 2, sc2 = (lane & 3) * 8;
    const int fr = lane & 15, fo = (lane >> 4) * 8;
    const int jr = (lane >> 4) * 4;
    const int wbase = w * (NFI * 16);

    // Q fragments directly to registers (reused across all kv chunks)
    s16x8 qr[NFI][4];
    #pragma unroll
    for (int fi = 0; fi < NFI; fi++)
        #pragma unroll
        for (int ks = 0; ks < 4; ks++)
            qr[fi][ks] = *(const s16x8*)&Qb[(long long)(q0 + wbase + fi * 16 + fr) * ldq + ks * 32 + fo];

    f32x4 oa[NFI][8];
    float mold[NFI][4], lrun[NFI][4];
    #pragma unroll
    for (int fi = 0; fi < NFI; fi++) {
        #pragma unroll
        for (int fj = 0; fj < 8; fj++) oa[fi][fj] = (f32x4){0.f,0.f,0.f,0.f};
        #pragma unroll
        for (int j = 0; j < 4; j++) { mold[fi][j] = -1e30f; lrun[fi][j] = 0.f; }
    }

    for (int c = 0; c < nkv; c++) {
        int kvp = kvbase + c * 64;
        #pragma unroll
        for (int s = 0; s < 4; s++)
            gld16(Kb + (long long)(kvp + w * 16 + sr) * ldk + s * 32 + sc2,
                  &KPs[s * 2048 + (w * 16) * 32]);
        #pragma unroll
        for (int s = 0; s < 2; s++)
            #pragma unroll
            for (int r0 = 0; r0 < 128; r0 += 64)
                gld16(Vb + (long long)(r0 + w * 16 + sr) * ldv + kvp + s * 32 + sc2,
                      &Zs[s * 4096 + (r0 + w * 16) * 32]);
        __syncthreads();

        f32x4 acc[NFI][4];
        #pragma unroll
        for (int fi = 0; fi < NFI; fi++)
            #pragma unroll
            for (int fj = 0; fj < 4; fj++) acc[fi][fj] = (f32x4){0.f,0.f,0.f,0.f};
        #pragma unroll
        for (int ks = 0; ks < 4; ks++) {
            s16x8 kb[4];
            #pragma unroll
            for (int fj = 0; fj < 4; fj++)
                kb[fj] = *(const s16x8*)&KPs[ks * 2048 + (fj * 16 + fr) * 32 + fo];
            #pragma unroll
            for (int fi = 0; fi < NFI; fi++)
                #pragma unroll
                for (int fj = 0; fj < 4; fj++)
                    acc[fi][fj] = __builtin_amdgcn_mfma_f32_16x16x32_bf16(qr[fi][ks], kb[fj], acc[fi][fj], 0, 0, 0);
        }

        float rs[NFI][4];
        #pragma unroll
        for (int fi = 0; fi < NFI; fi++) {
            #pragma unroll
            for (int j = 0; j < 4; j++) {
                float mx = acc[fi][0][j];
                #pragma unroll
                for (int fj = 1; fj < 4; fj++) mx = fmaxf(mx, acc[fi][fj][j]);
                mx = fmaxf(mx, __shfl_xor(mx, 1));
                mx = fmaxf(mx, __shfl_xor(mx, 2));
                mx = fmaxf(mx, __shfl_xor(mx, 4));
                mx = fmaxf(mx, __shfl_xor(mx, 8));
                float mn = fmaxf(mold[fi][j], mx);
                float scl = __expf(mold[fi][j] - mn);
                mold[fi][j] = mn;
                lrun[fi][j] *= scl;
                #pragma unroll
                for (int fj = 0; fj < 8; fj++) oa[fi][fj][j] *= scl;
                float r = 0.f;
                #pragma unroll
                for (int fj = 0; fj < 4; fj++) {
                    float p = __expf(acc[fi][fj][j] - mn);
                    acc[fi][fj][j] = p;
                    r += p;
                }
                r += __shfl_xor(r, 1);
                r += __shfl_xor(r, 2);
                r += __shfl_xor(r, 4);
                r += __shfl_xor(r, 8);
                rs[fi][j] = r;
            }
        }
        __syncthreads();   // all waves done reading KPs
        #pragma unroll
        for (int fi = 0; fi < NFI; fi++)
            #pragma unroll
            for (int j = 0; j < 4; j++) {
                int row = wbase + fi * 16 + jr + j;
                lrun[fi][j] += rs[fi][j];
                #pragma unroll
                for (int fj = 0; fj < 4; fj++) {
                    int idx = (row * 64 + fj * 16 + fr) ^ ((row & 7) << 3);
                    Ps[idx] = f2b(acc[fi][fj][j]);
                }
            }
        __syncthreads();   // P visible

        #pragma unroll
        for (int ks2 = 0; ks2 < 2; ks2++) {
            s16x8 pa[NFI], zb[8];
            #pragma unroll
            for (int fi = 0; fi < NFI; fi++) {
                int row = wbase + fi * 16 + fr;
                int idx = (row * 64 + ks2 * 32 + fo) ^ ((row & 7) << 3);
                pa[fi] = *(const s16x8*)&Ps[idx];
            }
            #pragma unroll
            for (int fj = 0; fj < 8; fj++)
                zb[fj] = *(const s16x8*)&Zs[ks2 * 4096 + (fj * 16 + fr) * 32 + fo];
            #pragma unroll
            for (int fi = 0; fi < NFI; fi++)
                #pragma unroll
                for (int fj = 0; fj < 8; fj++)
                    oa[fi][fj] = __builtin_amdgcn_mfma_f32_16x16x32_bf16(pa[fi], zb[fj], oa[fi][fj], 0, 0, 0);
        }
        __syncthreads();
    }

    // epilogue
    #pragma unroll
    for (int fi = 0; fi < NFI; fi++)
        #pragma unroll
        for (int j = 0; j < 4; j++) {
            int row = wbase + fi * 16 + jr + j;
            if constexpr (MODE == 0) {
                float inv = 1.f / lrun[fi][j];
                #pragma unroll
                for (int fj = 0; fj < 8; fj++)
                    Op[(long long)(q0 + row) * DIM + h * 128 + fj * 16 + fr] = oa[fi][fj][j] * inv;
            } else {
                long long rb = (((long long)h * 512 + q0 + row) * NSPLIT + blockIdx.y) * 128;
                #pragma unroll
                for (int fj = 0; fj < 8; fj++)
                    Op[rb + fj * 16 + fr] = oa[fi][fj][j];
                if (fr == 0) {
                    long long si = ((long long)h * 512 + q0 + row) * NSPLIT + blockIdx.y;
                    Pm[si] = mold[fi][j];
                    Pl[si] = lrun[fi][j];
                }
            }
        }
}

// combine kv-split partials -> bvT bf16 [h][d][l]
__global__ __launch_bounds__(256)
void bv_combine(const float* __restrict__ PBV, const float* __restrict__ Pm,
                const float* __restrict__ Pl, ushort* __restrict__ BVTb)
{
    __shared__ float T[32][129];
    __shared__ float wc8[32][NSPLIT], invL[32];
    int t = threadIdx.x;
    int h = blockIdx.y, l0 = blockIdx.x * 32;
    if (t < 32) {
        long long base = ((long long)h * 512 + l0 + t) * NSPLIT;
        float m = -1e30f;
        float mv[NSPLIT], lv[NSPLIT];
        #pragma unroll
        for (int c = 0; c < NSPLIT; c++) { mv[c] = Pm[base + c]; lv[c] = Pl[base + c]; m = fmaxf(m, mv[c]); }
        float L = 0.f;
        #pragma unroll
        for (int c = 0; c < NSPLIT; c++) { float wv = __expf(mv[c] - m); wc8[t][c] = wv; L += wv * lv[c]; }
        invL[t] = 1.f / L;
    }
    __syncthreads();
    int l = t >> 3, dg = t & 7;
    long long rbase = ((long long)h * 512 + l0 + l) * NSPLIT * 128;
    #pragma unroll
    for (int dd = 0; dd < 16; dd++) {
        int d = dg * 16 + dd;
        float s = 0.f;
        #pragma unroll
        for (int c = 0; c < NSPLIT; c++) s += wc8[l][c] * PBV[rbase + c * 128 + d];
        T[l][d] = s * invL[l];
    }
    __syncthreads();
    int d = t >> 1, half = t & 1;
    #pragma unroll
    for (int lc = 0; lc < 16; lc++) {
        int l2 = half * 16 + lc;
        BVTb[(long long)h * 65536 + (long long)d * 512 + l0 + l2] = f2b(T[l2][d]);
    }
}

// ---------------- f32 -> bf16 convert ----------------
__global__ __launch_bounds__(256)
void cvt_bf16(const float* __restrict__ x, ushort* __restrict__ y, long long n)
{
    long long i = ((long long)blockIdx.x * 256 + threadIdx.x) * 8;
    if (i >= n) return;
    float4 a = *(const float4*)(x + i), b = *(const float4*)(x + i + 4);
    ushort4 u0 = {f2b(a.x), f2b(a.y), f2b(a.z), f2b(a.w)};
    ushort4 u1 = {f2b(b.x), f2b(b.y), f2b(b.z), f2b(b.w)};
    *(ushort4*)(y + i) = u0; *(ushort4*)(y + i + 4) = u1;
}

// ---------------- softmax fp32 rows (W = NIT*256) ----------------
template<int NIT>
__global__ __launch_bounds__(256)
void softmax_rows(float* __restrict__ X, int W)
{
    long long row = blockIdx.x;
    float* x = X + row * W;
    float r[NIT];
    float m = -1e30f;
    #pragma unroll
    for (int i = 0; i < NIT; i++) { r[i] = x[threadIdx.x + i * 256]; m = fmaxf(m, r[i]); }
    m = blk_max(m);
    float s = 0.f;
    #pragma unroll
    for (int i = 0; i < NIT; i++) { r[i] = __expf(r[i] - m); s += r[i]; }
    s = blk_sum(s);
    float inv = 1.f / s;
    #pragma unroll
    for (int i = 0; i < NIT; i++) x[threadIdx.x + i * 256] = r[i] * inv;
}

// ---------------- LN + front-pad -> bf16 ----------------
__global__ __launch_bounds__(256)
void ln_pad(const float* __restrict__ H, const float* __restrict__ g,
            const float* __restrict__ b, ushort* __restrict__ X)
{
    int row = blockIdx.x, t = threadIdx.x;
    ushort* o = X + (long long)row * DIM;
    if (row < PAD) {
        #pragma unroll
        for (int i = 0; i < 4; i++) o[t + i * 256] = 0;
        return;
    }
    const float* x = H + (long long)(row - PAD) * DIM;
    float r[4]; float s = 0.f;
    #pragma unroll
    for (int i = 0; i < 4; i++) { r[i] = x[t + i * 256]; s += r[i]; }
    float mu = blk_sum(s) * (1.f / DIM);
    float v = 0.f;
    #pragma unroll
    for (int i = 0; i < 4; i++) { float d = r[i] - mu; v += d * d; }
    float var = blk_sum(v) * (1.f / DIM);
    float rs = rsqrtf(var + 1e-5f);
    #pragma unroll
    for (int i = 0; i < 4; i++) { int c = t + i * 256; o[c] = f2b((r[i] - mu) * rs * g[c] + b[c]); }
}

// ---------------- landmarks ----------------
__global__ __launch_bounds__(128)
void landmarks(const ushort* __restrict__ QKVb, ushort* __restrict__ QL, ushort* __restrict__ KL)
{
    int L = blockIdx.x, h = blockIdx.y, d = threadIdx.x;
    float sq = 0.f, sk = 0.f;
    #pragma unroll
    for (int j = 0; j < LSUB; j++) {
        const ushort* p = QKVb + (long long)(L * LSUB + j) * 3072 + h * DHEAD + d;
        sq += b2f(p[0]);
        sk += b2f(p[1024]);
    }
    QL[(long long)(h * LMK + L) * DHEAD + d] = f2b(sq * (1.f / LSUB));
    KL[(long long)(h * LMK + L) * DHEAD + d] = f2b(sk * (1.f / LSUB));
}

// ---------------- V transpose -> bf16 VT[h][d][i] ----------------
__global__ void vtrans(const ushort* __restrict__ Q, ushort* __restrict__ VT)
{
    __shared__ ushort tile[32][33];
    int h = blockIdx.z, i0 = blockIdx.x * 32, d0 = blockIdx.y * 32;
    int tx = threadIdx.x, ty = threadIdx.y;
    for (int yy = ty; yy < 32; yy += 8)
        tile[yy][tx] = Q[(long long)(i0 + yy) * 3072 + 2048 + h * 128 + d0 + tx];
    __syncthreads();
    for (int yy = ty; yy < 32; yy += 8)
        VT[((long long)h * 128 + d0 + yy) * 6144 + i0 + tx] = tile[tx][yy];
}

// ---------------- a2 column sums ----------------
__global__ __launch_bounds__(256)
void a2_sums2(const float* __restrict__ A2, float* __restrict__ cols)
{
    int h = blockIdx.x, slice = blockIdx.y, t = threadIdx.x;
    const float* a = A2 + (long long)h * LMK * LMK + (long long)slice * 64 * LMK;
    float s0 = 0.f, s1 = 0.f;
    #pragma unroll 4
    for (int i = 0; i < 64; i++) {
        s0 += a[(long long)i * LMK + t];
        s1 += a[(long long)i * LMK + t + 256];
    }
    atomicAdd(&cols[h * LMK + t], s0);
    atomicAdd(&cols[h * LMK + t + 256], s1);
}
__global__ __launch_bounds__(256)
void a2_scal2(const float* __restrict__ cols, float* __restrict__ scal)
{
    float mc = -1e30f;
    for (int i = threadIdx.x; i < HEADS * LMK; i += 256) mc = fmaxf(mc, cols[i]);
    mc = blk_max(mc);
    if (threadIdx.x == 0) scal[0] = 1.f / mc;
}

// ---------------- z0/X prep ----------------
__global__ void z0_t(const float* __restrict__ A2, ushort* __restrict__ Xb,
                     ushort* __restrict__ Z0b, ushort* __restrict__ Z0T,
                     const float* __restrict__ scal)
{
    __shared__ float tile[32][33];
    int h = blockIdx.z;
    const float* a = A2 + (long long)h * LMK * LMK;
    float s = scal[0];
    int x0 = blockIdx.x * 32, y0 = blockIdx.y * 32;
    int tx = threadIdx.x, ty = threadIdx.y;
    long long hb = (long long)h * LMK * LMK;
    for (int yy = ty; yy < 32; yy += 8) {
        float v = a[(long long)(y0 + yy) * LMK + x0 + tx];
        tile[yy][tx] = v;
        Xb [hb + (long long)(y0 + yy) * LMK + x0 + tx] = f2b(v);
        Z0T[hb + (long long)(y0 + yy) * LMK + x0 + tx] = f2b(s * v);
    }
    __syncthreads();
    for (int yy = ty; yy < 32; yy += 8)
        Z0b[hb + (long long)(x0 + yy) * LMK + y0 + tx] = f2b(s * tile[tx][yy]);
}

// ---------------- MoE ----------------
__global__ __launch_bounds__(256)
void moe_combine(const float* __restrict__ X, const float* __restrict__ wg,
                 const ushort* __restrict__ EO, const float* __restrict__ eb,
                 float* __restrict__ H)
{
    int i = blockIdx.x, t = threadIdx.x;
    const float* x = X + (long long)i * INDIM;
    float g0 = 0.f, g1 = 0.f, g2 = 0.f;
    for (int f = t; f < INDIM; f += 256) {
        float xv = x[f];
        const float* w = wg + f * 3;
        g0 += xv * w[0]; g1 += xv * w[1]; g2 += xv * w[2];
    }
    g0 = blk_sum(g0); g1 = blk_sum(g1); g2 = blk_sum(g2);
    float m = fmaxf(g0, fmaxf(g1, g2));
    float e0 = __expf(g0 - m), e1 = __expf(g1 - m), e2 = __expf(g2 - m);
    float inv = 1.f / (e0 + e1 + e2);
    e0 *= inv; e1 *= inv; e2 *= inv;
    const ushort* eo = EO + (long long)i * 3072;
    for (int o = t; o < DIM; o += 256) {
        float v0 = fmaxf(b2f(eo[o])        + eb[o],        0.f);
        float v1 = fmaxf(b2f(eo[1024 + o]) + eb[1024 + o], 0.f);
        float v2 = fmaxf(b2f(eo[2048 + o]) + eb[2048 + o], 0.f);
        float r = e0 * v0 + e1 * v1 + e2 * v2;
        H[(long long)(1 + i) * DIM + o] = r;
        if (i < 84) H[(long long)(6001 + i) * DIM + o] = r;
    }
}

__global__ void cls_copy(const float* __restrict__ c, float* __restrict__ H)
{
    for (int i = threadIdx.x; i < DIM; i += 256) H[i] = c[i];
}

// ---------------- res conv: Ob = bf16(O + depthwise33(V)) (coalesced) ----------------
__global__ __launch_bounds__(256)
void resconv(const ushort* __restrict__ QKVb, const float* __restrict__ rw,
             const float* __restrict__ O, ushort* __restrict__ Ob)
{
    long long idx = (long long)blockIdx.x * 256 + threadIdx.x;
    int c = (int)(idx & 1023);
    long long i = idx >> 10;
    int h = c >> 7;
    float acc = O[idx];
    #pragma unroll
    for (int t = 0; t < 33; t++) {
        long long r = i + t - 16;
        if (r >= 0 && r < NPL) acc += rw[h * 33 + t] * b2f(QKVb[r * 3072 + 2048 + c]);
    }
    Ob[idx] = f2b(acc);
}

// ---------------- PPEG ----------------
__global__ void h2f(const float* __restrict__ H, float* __restrict__ F)
{
    __shared__ float tile[32][33];
    int p0 = blockIdx.x * 32, c0 = blockIdx.y * 32;
    int tx = threadIdx.x, ty = threadIdx.y;
    for (int yy = ty; yy < 32; yy += 8) {
        int p = p0 + yy;
        if (p < HW * HW) tile[yy][tx] = H[(long long)(1 + p) * DIM + c0 + tx];
    }
    __syncthreads();
    for (int yy = ty; yy < 32; yy += 8) {
        int p = p0 + tx, c = c0 + yy;
        if (p < HW * HW) F[(long long)c * (HW * HW) + p] = tile[tx][yy];
    }
}
__global__ void f2h(const float* __restrict__ F2, float* __restrict__ H)
{
    __shared__ float tile[32][33];
    int c0 = blockIdx.x * 32, p0 = blockIdx.y * 32;
    int tx = threadIdx.x, ty = threadIdx.y;
    for (int yy = ty; yy < 32; yy += 8) {
        int p = p0 + tx;
        if (p < HW * HW) tile[yy][tx] = F2[(long long)(c0 + yy) * (HW * HW) + p];
    }
    __syncthreads();
    for (int yy = ty; yy < 32; yy += 8) {
        int p = p0 + yy;
        if (p < HW * HW) H[(long long)(1 + p) * DIM + c0 + tx] = tile[tx][yy];
    }
}
__global__ __launch_bounds__(256)
void ppeg_conv2(const float* __restrict__ F,
                const float* __restrict__ w7, const float* __restrict__ b7,
                const float* __restrict__ w5, const float* __restrict__ b5,
                const float* __restrict__ w3, const float* __restrict__ b3,
                float* __restrict__ F2)
{
    int c = blockIdx.x, t = threadIdx.x;
    __shared__ float plane[HW * HW];
    __shared__ float wm[49];
    for (int p = t; p < HW * HW; p += 256) plane[p] = F[(long long)c * (HW * HW) + p];
    if (t < 49) {
        int ky = t / 7 - 3, kx = t % 7 - 3;
        float w = w7[(long long)c * 49 + t];
        if (ky >= -2 && ky <= 2 && kx >= -2 && kx <= 2) w += w5[(long long)c * 25 + (ky + 2) * 5 + (kx + 2)];
        if (ky >= -1 && ky <= 1 && kx >= -1 && kx <= 1) w += w3[(long long)c * 9 + (ky + 1) * 3 + (kx + 1)];
        if (t == 24) w += 1.0f;
        wm[t] = w;
    }
    __syncthreads();
    float bsum = b7[c] + b5[c] + b3[c];
    for (int p = t; p < HW * HW; p += 256) {
        int y = p / HW, x = p - y * HW;
        float acc = bsum;
        if (y >= 3 && y < HW - 3 && x >= 3 && x < HW - 3) {
            const float* base = &plane[p];
            #pragma unroll
            for (int ky = -3; ky <= 3; ky++)
                #pragma unroll
                for (int kx = -3; kx <= 3; kx++)
                    acc += wm[(ky + 3) * 7 + kx + 3] * base[ky * HW + kx];
        } else {
            for (int ky = -3; ky <= 3; ky++) {
                int yy = y + ky; if ((unsigned)yy >= (unsigned)HW) continue;
                for (int kx = -3; kx <= 3; kx++) {
                    int xx = x + kx; if ((unsigned)xx >= (unsigned)HW) continue;
                    acc += wm[(ky + 3) * 7 + kx + 3] * plane[yy * HW + xx];
                }
            }
        }
        F2[(long long)c * (HW * HW) + p] = acc;
    }
}

// ---------------- final head ----------------
__global__ __launch_bounds__(256)
void head_k(const float* __restrict__ H, const float* __restrict__ g, const float* __restrict__ b,
            const float* __restrict__ fw, const float* __restrict__ fb, float* __restrict__ out)
{
    int t = threadIdx.x;
    float r[4]; float s = 0.f;
    #pragma unroll
    for (int i = 0; i < 4; i++) { r[i] = H[t + i * 256]; s += r[i]; }
    float mu = blk_sum(s) * (1.f / DIM);
    float v = 0.f;
    #pragma unroll
    for (int i = 0; i < 4; i++) { float d = r[i] - mu; v += d * d; }
    float var = blk_sum(v) * (1.f / DIM);
    float rs = rsqrtf(var + 1e-5f);
    float d0 = 0.f, d1 = 0.f;
    #pragma unroll
    for (int i = 0; i < 4; i++) {
        int c = t + i * 256;
        float hv = (r[i] - mu) * rs * g[c] + b[c];
        d0 += hv * fw[c];
        d1 += hv * fw[DIM + c];
    }
    d0 = blk_sum(d0); d1 = blk_sum(d1);
    if (t == 0) {
        float l0 = d0 + fb[0], l1 = d1 + fb[1];
        float m = fmaxf(l0, l1);
        float e0 = __expf(l0 - m), e1 = __expf(l1 - m);
        float inv = 1.f / (e0 + e1);
        out[0] = l0; out[1] = l1;
        out[2] = e0 * inv; out[3] = e1 * inv;
        out[4] = (l1 > l0) ? 1.0f : 0.0f;
    }
}

// ---------------- host ----------------
extern "C" void kernel_launch(void* const* d_in, const int* in_sizes, int n_in,
                              void* d_out, int out_size, void* d_ws, size_t ws_size,
                              hipStream_t stream)
{
    const float* data     = (const float*)d_in[0];
    const float* w_gate   = (const float*)d_in[1];
    const float* expert_w = (const float*)d_in[2];
    const float* expert_b = (const float*)d_in[3];
    const float* cls_tok  = (const float*)d_in[4];
    const float* ln_g[2]  = {(const float*)d_in[5],  (const float*)d_in[11]};
    const float* ln_b[2]  = {(const float*)d_in[6],  (const float*)d_in[12]};
    const float* qkv_w[2] = {(const float*)d_in[7],  (const float*)d_in[13]};
    const float* out_w[2] = {(const float*)d_in[8],  (const float*)d_in[14]};
    const float* out_b[2] = {(const float*)d_in[9],  (const float*)d_in[15]};
    const float* res_w[2] = {(const float*)d_in[10], (const float*)d_in[16]};
    const float* pw7 = (const float*)d_in[17]; const float* pb7 = (const float*)d_in[18];
    const float* pw5 = (const float*)d_in[19]; const float* pb5 = (const float*)d_in[20];
    const float* pw3 = (const float*)d_in[21]; const float* pb3 = (const float*)d_in[22];
    const float* nf_g = (const float*)d_in[23]; const float* nf_b = (const float*)d_in[24];
    const float* fc2w = (const float*)d_in[25]; const float* fc2b = (const float*)d_in[26];

    float*  ws    = (float*)d_ws;
    float*  H     = ws + OFF_H;
    ushort* LNXb  = (ushort*)(ws + OFF_LNXO);
    float*  O     = ws + OFF_LNXO;             // alias: O written after LNXb dead
    ushort* QKVb  = (ushort*)(ws + OFF_QKVB);
    ushort* EOb   = (ushort*)(ws + OFF_QKVB);
    float*  PBV   = ws + OFF_PBV;
    float*  PM    = ws + OFF_PM;
    float*  PL    = ws + OFF_PL;
    ushort* Ob    = (ushort*)(ws + OFF_OB);
    ushort* VT    = (ushort*)(ws + OFF_VT);
    ushort* QL    = (ushort*)(ws + OFF_QL);
    ushort* KL    = (ushort*)(ws + OFF_KL);
    float*  A2F   = ws + OFF_A2F;
    ushort* BVTb  = (ushort*)(ws + OFF_BVTB);
    ushort* Xb    = (ushort*)(ws + OFF_XB);
    ushort* XZB   = (ushort*)(ws + OFF_XZB);
    ushort* XZT7  = (ushort*)(ws + OFF_XZT7);
    ushort* PT15  = (ushort*)(ws + OFF_PT15);
    ushort* QT13  = (ushort*)(ws + OFF_QT13);
    ushort* ZB[2] = {(ushort*)(ws + OFF_ZB0), (ushort*)(ws + OFF_ZB1)};
    ushort* ZT[2] = {(ushort*)(ws + OFF_ZT0), (ushort*)(ws + OFF_ZT1)};
    ushort* ZBT   = (ushort*)(ws + OFF_ZBT);
    ushort* QWB   = (ushort*)(ws + OFF_QWB);
    ushort* OWB   = (ushort*)(ws + OFF_OWB);
    ushort* DATAB = (ushort*)(ws + OFF_DATAB);
    ushort* EWB   = (ushort*)(ws + OFF_EWB);
    float*  COLS  = ws + OFF_COLS;
    float*  SCAL  = ws + OFF_SCAL;

    const long long HSB = (long long)LMK * DHEAD;   // 65536
    const long long A2S = (long long)LMK * LMK;     // 262144

    // ---- MoE ----
    cvt_bf16<<<4500, 256, 0, stream>>>(data, DATAB, (long long)NTOK * INDIM);
    cvt_bf16<<<2304, 256, 0, stream>>>(expert_w, EWB, 3072LL * INDIM);
    mg<2><<<dim3(24,47,1),256,0,stream>>>(DATAB,INDIM,0, EWB,INDIM,0, EOb,3072,0,
        nullptr,0,0, NTOK,INDIM, nullptr, 1.f,0.f,0.f);
    moe_combine<<<NTOK,256,0,stream>>>(data, w_gate, EOb, expert_b, H);
    cls_copy<<<1,256,0,stream>>>(cls_tok, H);

    for (int stage = 0; stage < 2; stage++) {
        cvt_bf16<<<1536, 256, 0, stream>>>(qkv_w[stage], QWB, 3072LL * DIM);
        cvt_bf16<<<512, 256, 0, stream>>>(out_w[stage], OWB, (long long)DIM * DIM);
        ln_pad<<<NPL,256,0,stream>>>(H, ln_g[stage], ln_b[stage], LNXb);
        mg<1><<<dim3(24,48,1),256,0,stream>>>(LNXb,DIM,0, QWB,DIM,0, QKVb,3072,0,
            nullptr,0,0, NPL,DIM, nullptr, 1.f,0.f,0.f);
        landmarks<<<dim3(LMK,HEADS),128,0,stream>>>(QKVb, QL, KL);
        vtrans<<<dim3(192,4,8),dim3(32,8),0,stream>>>(QKVb, VT);
        // a2 = softmax(ql @ kl^T) f32
        mg<0><<<dim3(4,4,8),256,0,stream>>>(QL,DHEAD,HSB, KL,DHEAD,HSB, A2F,LMK,A2S,
            nullptr,0,0, LMK,DHEAD, nullptr, 1.f,0.f,0.f);
        softmax_rows<2><<<HEADS*LMK,256,0,stream>>>(A2F, LMK);
        hipMemsetAsync(COLS, 0, HEADS * LMK * sizeof(float), stream);
        a2_sums2<<<dim3(HEADS,8),256,0,stream>>>(A2F, COLS);
        a2_scal2<<<1,256,0,stream>>>(COLS, SCAL);
        z0_t<<<dim3(16,16,8),dim3(32,8),0,stream>>>(A2F, Xb, ZB[0], ZT[0], SCAL);
        // Newton-Schulz: 6 iterations, separate launches (L2-resident between dispatches)
        int cur = 0;
        for (int it = 0; it < 6; it++) {
            mg<4><<<dim3(4,4,8),256,0,stream>>>(Xb,LMK,A2S, ZT[cur],LMK,A2S, XZB,LMK,A2S,
                XZT7,LMK,A2S, LMK,LMK, nullptr, 1.f, 7.f, -1.f);
            mg<5><<<dim3(4,4,8),256,0,stream>>>(XZB,LMK,A2S, XZT7,LMK,A2S, nullptr,0,0,
                PT15,LMK,A2S, LMK,LMK, nullptr, 1.f, 15.f, -1.f);
            mg<5><<<dim3(4,4,8),256,0,stream>>>(XZB,LMK,A2S, PT15,LMK,A2S, nullptr,0,0,
                QT13,LMK,A2S, LMK,LMK, nullptr, 1.f, 13.f, -1.f);
            if (it < 5)
                mg<4><<<dim3(4,4,8),256,0,stream>>>(ZB[cur],LMK,A2S, QT13,LMK,A2S, ZB[1-cur],LMK,A2S,
                    ZT[1-cur],LMK,A2S, LMK,LMK, nullptr, 0.25f, 0.f, 1.f);
            else
                mg<2><<<dim3(4,4,8),256,0,stream>>>(ZB[cur],LMK,A2S, QT13,LMK,A2S, ZB[1-cur],LMK,A2S,
                    nullptr,0,0, LMK,LMK, nullptr, 0.25f, 0.f, 1.f);
            cur = 1 - cur;
        }
        ushort* Z6 = ZB[cur];
        // flash a3: partial bv over 16 kv-chunks of 384
        flash<1,2><<<dim3(4,NSPLIT,8),256,0,stream>>>(QL,DHEAD,HSB, QKVb+1024,3072,128,
            VT,NPL,(long long)DHEAD*NPL, PBV, PM, PL, 6, 384);
        bv_combine<<<dim3(16,8),256,0,stream>>>(PBV, PM, PL, BVTb);
        // ZBT[d][l'] = sum_l bvT[d][l] z6[l'][l]
        mg<2><<<dim3(4,1,8),256,0,stream>>>(BVTb,LMK,HSB, Z6,LMK,A2S, ZBT,LMK,HSB,
            nullptr,0,0, DHEAD,LMK, nullptr, 1.f,0.f,0.f);
        // flash a1: O = softmax(q @ kl^T) @ zb  (64-row q tiles, 768 blocks)
        flash<0,1><<<dim3(96,1,8),256,0,stream>>>(QKVb,3072,128, KL,DHEAD,HSB,
            ZBT,LMK,HSB, O, nullptr, nullptr, 8, 0);
        // Ob = bf16(O + res conv of v)
        resconv<<<(NPL*DIM)/256,256,0,stream>>>(QKVb, res_w[stage], O, Ob);
        // H += Ob @ out_w^T + out_b
        mg<3><<<dim3(8,48,1),256,0,stream>>>(Ob + (long long)PAD*DIM,DIM,0, OWB,DIM,0, H,DIM,0,
            nullptr,0,0, NH,DIM, out_b[stage], 1.f,0.f,0.f);
        if (stage == 0) {
            float* F  = ws + OFF_QKVB;
            float* F2 = F + 6230016LL;
            h2f<<<dim3(191,32),dim3(32,8),0,stream>>>(H, F);
            ppeg_conv2<<<DIM,256,0,stream>>>(F, pw7, pb7, pw5, pb5, pw3, pb3, F2);
            f2h<<<dim3(32,191),dim3(32,8),0,stream>>>(F2, H);
        }
    }

    head_k<<<1,256,0,stream>>>(H, nf_g, nf_b, fc2w, fc2b, (float*)d_out);
}

// Round 10
// 1661.423 us; speedup vs baseline: 1.5734x; 1.1926x over previous
//
#include <hip/hip_runtime.h>
#include <hip/hip_bf16.h>

// ---------------- constants ----------------
#define NTOK   6000
#define INDIM  1536
#define DIM    1024
#define NPL    6144
#define PAD    59
#define NH     6085
#define HEADS  8
#define DHEAD  128
#define LMK    512
#define LSUB   12
#define HW     78
#define QSCALE 0.08838834764831845f
#define NSPLIT 16

// ---------------- ws layout (float-slot offsets) ----------------
#define OFF_H     0LL          // 6144*1024 f32
#define OFF_LNXO  6291456LL    // LNXb bf16 / O f32 alias
#define OFF_QKVB  12582912LL   // 6144*3072 bf16; EO bf16 + PPEG planes alias
#define OFF_PBV   22020096LL   // 8h*512*16c*128 f32 = 8388608
#define OFF_PM    30408704LL   // 65536
#define OFF_PL    30474240LL   // 65536
#define OFF_OB    30539776LL   // 6144*1024 bf16 = 3145728 slots (ends 33685504)
#define OFF_VT    34603008LL   // 8*128*6144 bf16
#define OFF_QL    37748736LL
#define OFF_KL    38010880LL
#define OFF_A2F   38273024LL   // 8*512*512 f32
#define OFF_BVTB  40370176LL   // 8*128*512 bf16
#define OFF_XB    42467328LL   // bf16 8*512*512 each below
#define OFF_XZB   43515904LL
#define OFF_XZT7  44564480LL
#define OFF_PT15  45613056LL
#define OFF_QT13  46661632LL
#define OFF_ZB0   47710208LL
#define OFF_ZT0   48758784LL
#define OFF_ZB1   49807360LL
#define OFF_ZT1   50855936LL
#define OFF_ZBT   52428800LL   // 8*128*512 bf16
#define OFF_QWB   52690944LL   // 3072*1024 bf16
#define OFF_OWB   54263808LL   // 1024*1024 bf16
#define OFF_COLS  54788096LL
#define OFF_SCAL  54796288LL
// transient aliases (dead before overlapping buffers are written)
#define OFF_DATAB 31457280LL   // 6000*1536 bf16 (pre-stage only; overlaps OB/VT span)
#define OFF_EWB   36065280LL   // 3072*1536 bf16 (pre-stage only)

typedef __attribute__((ext_vector_type(8))) short s16x8;
typedef __attribute__((ext_vector_type(4))) float f32x4;

// ---------------- bf16 helpers ----------------
__device__ __forceinline__ ushort f2b(float f) {
    union { float f; unsigned u; } v; v.f = f;
    return (ushort)((v.u + 0x7FFF + ((v.u >> 16) & 1)) >> 16);
}
__device__ __forceinline__ float b2f(ushort h) {
    union { unsigned u; float f; } v; v.u = ((unsigned)h) << 16; return v.f;
}

// async global->LDS, 16 bytes per lane; lds ptr must be wave-uniform
__device__ __forceinline__ void gld16(const void* g, void* l) {
    __builtin_amdgcn_global_load_lds((const __attribute__((address_space(1))) void*)g,
                                     (__attribute__((address_space(3))) void*)l, 16, 0, 0);
}

// ---------------- reductions (blockDim.x == 256) ----------------
__device__ __forceinline__ float blk_sum(float v) {
    __shared__ float sb[4];
    #pragma unroll
    for (int o = 32; o > 0; o >>= 1) v += __shfl_down(v, o);
    int lane = threadIdx.x & 63, w = threadIdx.x >> 6;
    __syncthreads();
    if (lane == 0) sb[w] = v;
    __syncthreads();
    return sb[0] + sb[1] + sb[2] + sb[3];
}
__device__ __forceinline__ float blk_max(float v) {
    __shared__ float sb[4];
    #pragma unroll
    for (int o = 32; o > 0; o >>= 1) v = fmaxf(v, __shfl_down(v, o));
    int lane = threadIdx.x & 63, w = threadIdx.x >> 6;
    __syncthreads();
    if (lane == 0) sb[w] = v;
    __syncthreads();
    return fmaxf(fmaxf(sb[0], sb[1]), fmaxf(sb[2], sb[3]));
}

// ================= MFMA GEMM (bf16 x bf16), C = alpha * A @ B^T, 128x128 tile =================
// EPI: 0 f32 | 1 bf16 qkv-scale | 2 bf16 | 3 f32 += v+bias
//      4 bf16 C + bf16 T[c][r]=tdelta*(r==c)+tsign*v | 5 T only
template<int EPI>
__global__ __launch_bounds__(256)
void mg(const ushort* __restrict__ A, int lda, long long sA,
        const ushort* __restrict__ B, int ldb, long long sB,
        void* __restrict__ Cp, int ldc, long long sC,
        void* __restrict__ Tp, int ldt, long long sT,
        int M, int K, const float* __restrict__ bias,
        float alpha, float tdelta, float tsign)
{
    __shared__ ushort As[4096];
    __shared__ ushort Bs[4096];
    const int t = threadIdx.x;
    const int z = blockIdx.z;
    const ushort* Ab = A + (long long)z * sA;
    const ushort* Bb = B + (long long)z * sB;
    const int row0 = blockIdx.y * 128, col0 = blockIdx.x * 128;
    const int w = t >> 6, lane = t & 63;
    const int l4 = lane >> 2, ls = (lane & 3) * 8;
    const int q0 = w, q1 = 4 + w;
    int ar0 = row0 + q0 * 16 + l4; if (ar0 >= M) ar0 = M - 1;
    int ar1 = row0 + q1 * 16 + l4; if (ar1 >= M) ar1 = M - 1;
    const int br0 = col0 + q0 * 16 + l4;
    const int br1 = col0 + q1 * 16 + l4;
    const ushort* ap0 = Ab + (long long)ar0 * lda + ls;
    const ushort* ap1 = Ab + (long long)ar1 * lda + ls;
    const ushort* bp0 = Bb + (long long)br0 * ldb + ls;
    const ushort* bp1 = Bb + (long long)br1 * ldb + ls;
    ushort* asl0 = &As[q0 * 512];
    ushort* asl1 = &As[q1 * 512];
    ushort* bsl0 = &Bs[q0 * 512];
    ushort* bsl1 = &Bs[q1 * 512];

    const int wr = (w >> 1) * 64, wc = (w & 1) * 64;
    const int fr = lane & 15, fo = (lane >> 4) * 8;

    f32x4 acc[4][4];
    #pragma unroll
    for (int a = 0; a < 4; a++)
        #pragma unroll
        for (int b = 0; b < 4; b++)
            acc[a][b] = (f32x4){0.f, 0.f, 0.f, 0.f};

    for (int kt = 0; kt < K; kt += 32) {
        gld16(ap0 + kt, asl0);
        gld16(ap1 + kt, asl1);
        gld16(bp0 + kt, bsl0);
        gld16(bp1 + kt, bsl1);
        __syncthreads();
        s16x8 af[4], bf[4];
        #pragma unroll
        for (int a = 0; a < 4; a++) af[a] = *(const s16x8*)&As[(wr + a * 16 + fr) * 32 + fo];
        #pragma unroll
        for (int b = 0; b < 4; b++) bf[b] = *(const s16x8*)&Bs[(wc + b * 16 + fr) * 32 + fo];
        #pragma unroll
        for (int a = 0; a < 4; a++)
            #pragma unroll
            for (int b = 0; b < 4; b++)
                acc[a][b] = __builtin_amdgcn_mfma_f32_16x16x32_bf16(af[a], bf[b], acc[a][b], 0, 0, 0);
        __syncthreads();
    }

    const int er0 = row0 + wr + ((lane >> 4) << 2);
    const int ec0 = col0 + wc + fr;
    #pragma unroll
    for (int a = 0; a < 4; a++) {
        #pragma unroll
        for (int j = 0; j < 4; j++) {
            int r = er0 + a * 16 + j;
            if (r >= M) continue;
            #pragma unroll
            for (int b = 0; b < 4; b++) {
                int c = ec0 + b * 16;
                float v = alpha * acc[a][b][j];
                long long ci = z * sC + (long long)r * ldc + c;
                if constexpr (EPI == 0) ((float*)Cp)[ci] = v;
                else if constexpr (EPI == 1) ((ushort*)Cp)[ci] = f2b(c < 1024 ? v * QSCALE : v);
                else if constexpr (EPI == 2) ((ushort*)Cp)[ci] = f2b(v);
                else if constexpr (EPI == 3) ((float*)Cp)[ci] += v + bias[c];
                else {
                    ushort tv = f2b((r == c ? tdelta : 0.f) + tsign * v);
                    long long ti = z * sT + (long long)c * ldt + r;
                    if constexpr (EPI == 4) { ((ushort*)Cp)[ci] = f2b(v); ((ushort*)Tp)[ti] = tv; }
                    else { ((ushort*)Tp)[ti] = tv; }  // 5
                }
            }
        }
    }
}

// ================= MFMA GEMM 64x128 tile — for small batched GEMMs =================
// C = alpha * A @ B^T. Requires M%64==0, N%128==0, K%32==0. Grid (N/128, M/64, Z).
// 4 waves; wave w owns cols w*32..+31 across all 64 rows. 12 KB LDS -> high occupancy.
// EPI: 0 f32 | 2 bf16 | 4 bf16 C + bf16 T[c][r]=tdelta*(r==c)+tsign*v | 5 T only
template<int EPI>
__global__ __launch_bounds__(256)
void mg64(const ushort* __restrict__ A, int lda, long long sA,
          const ushort* __restrict__ B, int ldb, long long sB,
          void* __restrict__ Cp, int ldc, long long sC,
          void* __restrict__ Tp, int ldt, long long sT,
          int K, float alpha, float tdelta, float tsign)
{
    __shared__ ushort As[2048];   // [64][32]
    __shared__ ushort Bs[4096];   // [128][32]
    const int t = threadIdx.x;
    const int z = blockIdx.z;
    const ushort* Ab = A + (long long)z * sA;
    const ushort* Bb = B + (long long)z * sB;
    const int row0 = blockIdx.y * 64, col0 = blockIdx.x * 128;
    const int w = t >> 6, lane = t & 63;
    const int l4 = lane >> 2, ls = (lane & 3) * 8;
    // A: wave w stages rows w*16..+15 (one gld16)
    const ushort* ap = Ab + (long long)(row0 + w * 16 + l4) * lda + ls;
    ushort* asl = &As[w * 16 * 32];
    // B: wave w stages rows w*16..+15 and 64+w*16..+15
    const ushort* bp0 = Bb + (long long)(col0 + w * 16 + l4) * ldb + ls;
    const ushort* bp1 = Bb + (long long)(col0 + 64 + w * 16 + l4) * ldb + ls;
    ushort* bsl0 = &Bs[w * 16 * 32];
    ushort* bsl1 = &Bs[(64 + w * 16) * 32];

    const int fr = lane & 15, fo = (lane >> 4) * 8;

    f32x4 acc[4][2];
    #pragma unroll
    for (int a = 0; a < 4; a++)
        #pragma unroll
        for (int b = 0; b < 2; b++)
            acc[a][b] = (f32x4){0.f, 0.f, 0.f, 0.f};

    for (int kt = 0; kt < K; kt += 32) {
        gld16(ap + kt, asl);
        gld16(bp0 + kt, bsl0);
        gld16(bp1 + kt, bsl1);
        __syncthreads();
        s16x8 af[4], bf[2];
        #pragma unroll
        for (int a = 0; a < 4; a++) af[a] = *(const s16x8*)&As[(a * 16 + fr) * 32 + fo];
        #pragma unroll
        for (int b = 0; b < 2; b++) bf[b] = *(const s16x8*)&Bs[(w * 32 + b * 16 + fr) * 32 + fo];
        #pragma unroll
        for (int a = 0; a < 4; a++)
            #pragma unroll
            for (int b = 0; b < 2; b++)
                acc[a][b] = __builtin_amdgcn_mfma_f32_16x16x32_bf16(af[a], bf[b], acc[a][b], 0, 0, 0);
        __syncthreads();
    }

    const int er0 = row0 + ((lane >> 4) << 2);
    const int ec0 = col0 + w * 32 + fr;
    #pragma unroll
    for (int a = 0; a < 4; a++) {
        #pragma unroll
        for (int j = 0; j < 4; j++) {
            int r = er0 + a * 16 + j;
            #pragma unroll
            for (int b = 0; b < 2; b++) {
                int c = ec0 + b * 16;
                float v = alpha * acc[a][b][j];
                long long ci = z * sC + (long long)r * ldc + c;
                if constexpr (EPI == 0) ((float*)Cp)[ci] = v;
                else if constexpr (EPI == 2) ((ushort*)Cp)[ci] = f2b(v);
                else {
                    ushort tv = f2b((r == c ? tdelta : 0.f) + tsign * v);
                    long long ti = z * sT + (long long)c * ldt + r;
                    if constexpr (EPI == 4) { ((ushort*)Cp)[ci] = f2b(v); ((ushort*)Tp)[ti] = tv; }
                    else { ((ushort*)Tp)[ti] = tv; }  // 5
                }
            }
        }
    }
}

// ================= fused flash attention =================
// Q in registers; q tile = NFI*64 rows (wave owns NFI*16 rows); KV chunks of 64.
// MODE 0: final f32 output to Op (cols h*128..); MODE 1: partial (acc,m,l) per kv-split.
template<int MODE, int NFI>
__global__ __launch_bounds__(256)
void flash(const ushort* __restrict__ Qp, int ldq, long long sQh,
           const ushort* __restrict__ Kp, int ldk, long long sKh,
           const ushort* __restrict__ Vp, int ldv, long long sVh,
           float* __restrict__ Op, float* __restrict__ Pm, float* __restrict__ Pl,
           int nkv, int kvspan)
{
    __shared__ ushort Zs[8192];    // 2 subtiles [128][32] (Vt chunk)
    __shared__ ushort KPs[8192];   // 4 subtiles [64][32] (K chunk); aliased by P [NFI*64][64] swizzled
    ushort* Ps = KPs;
    const int t = threadIdx.x;
    const int h = blockIdx.z;
    const int q0 = blockIdx.x * (NFI * 64);
    const int kvbase = blockIdx.y * kvspan;
    const ushort* Qb = Qp + (long long)h * sQh;
    const ushort* Kb = Kp + (long long)h * sKh;
    const ushort* Vb = Vp + (long long)h * sVh;
    const int w = t >> 6, lane = t & 63;
    const int sr = lane >> 2, sc2 = (lane & 3) * 8;
    const int fr = lane & 15, fo = (lane >> 4) * 8;
    const int jr = (lane >> 4) * 4;
    const int wbase = w * (NFI * 16);

    // Q fragments directly to registers (reused across all kv chunks)
    s16x8 qr[NFI][4];
    #pragma unroll
    for (int fi = 0; fi < NFI; fi++)
        #pragma unroll
        for (int ks = 0; ks < 4; ks++)
            qr[fi][ks] = *(const s16x8*)&Qb[(long long)(q0 + wbase + fi * 16 + fr) * ldq + ks * 32 + fo];

    f32x4 oa[NFI][8];
    float mold[NFI][4], lrun[NFI][4];
    #pragma unroll
    for (int fi = 0; fi < NFI; fi++) {
        #pragma unroll
        for (int fj = 0; fj < 8; fj++) oa[fi][fj] = (f32x4){0.f,0.f,0.f,0.f};
        #pragma unroll
        for (int j = 0; j < 4; j++) { mold[fi][j] = -1e30f; lrun[fi][j] = 0.f; }
    }

    for (int c = 0; c < nkv; c++) {
        int kvp = kvbase + c * 64;
        #pragma unroll
        for (int s = 0; s < 4; s++)
            gld16(Kb + (long long)(kvp + w * 16 + sr) * ldk + s * 32 + sc2,
                  &KPs[s * 2048 + (w * 16) * 32]);
        #pragma unroll
        for (int s = 0; s < 2; s++)
            #pragma unroll
            for (int r0 = 0; r0 < 128; r0 += 64)
                gld16(Vb + (long long)(r0 + w * 16 + sr) * ldv + kvp + s * 32 + sc2,
                      &Zs[s * 4096 + (r0 + w * 16) * 32]);
        __syncthreads();

        f32x4 acc[NFI][4];
        #pragma unroll
        for (int fi = 0; fi < NFI; fi++)
            #pragma unroll
            for (int fj = 0; fj < 4; fj++) acc[fi][fj] = (f32x4){0.f,0.f,0.f,0.f};
        #pragma unroll
        for (int ks = 0; ks < 4; ks++) {
            s16x8 kb[4];
            #pragma unroll
            for (int fj = 0; fj < 4; fj++)
                kb[fj] = *(const s16x8*)&KPs[ks * 2048 + (fj * 16 + fr) * 32 + fo];
            #pragma unroll
            for (int fi = 0; fi < NFI; fi++)
                #pragma unroll
                for (int fj = 0; fj < 4; fj++)
                    acc[fi][fj] = __builtin_amdgcn_mfma_f32_16x16x32_bf16(qr[fi][ks], kb[fj], acc[fi][fj], 0, 0, 0);
        }

        float rs[NFI][4];
        #pragma unroll
        for (int fi = 0; fi < NFI; fi++) {
            #pragma unroll
            for (int j = 0; j < 4; j++) {
                float mx = acc[fi][0][j];
                #pragma unroll
                for (int fj = 1; fj < 4; fj++) mx = fmaxf(mx, acc[fi][fj][j]);
                mx = fmaxf(mx, __shfl_xor(mx, 1));
                mx = fmaxf(mx, __shfl_xor(mx, 2));
                mx = fmaxf(mx, __shfl_xor(mx, 4));
                mx = fmaxf(mx, __shfl_xor(mx, 8));
                float mn = fmaxf(mold[fi][j], mx);
                float scl = __expf(mold[fi][j] - mn);
                mold[fi][j] = mn;
                lrun[fi][j] *= scl;
                #pragma unroll
                for (int fj = 0; fj < 8; fj++) oa[fi][fj][j] *= scl;
                float r = 0.f;
                #pragma unroll
                for (int fj = 0; fj < 4; fj++) {
                    float p = __expf(acc[fi][fj][j] - mn);
                    acc[fi][fj][j] = p;
                    r += p;
                }
                r += __shfl_xor(r, 1);
                r += __shfl_xor(r, 2);
                r += __shfl_xor(r, 4);
                r += __shfl_xor(r, 8);
                rs[fi][j] = r;
            }
        }
        __syncthreads();   // all waves done reading KPs
        #pragma unroll
        for (int fi = 0; fi < NFI; fi++)
            #pragma unroll
            for (int j = 0; j < 4; j++) {
                int row = wbase + fi * 16 + jr + j;
                lrun[fi][j] += rs[fi][j];
                #pragma unroll
                for (int fj = 0; fj < 4; fj++) {
                    int idx = (row * 64 + fj * 16 + fr) ^ ((row & 7) << 3);
                    Ps[idx] = f2b(acc[fi][fj][j]);
                }
            }
        __syncthreads();   // P visible

        #pragma unroll
        for (int ks2 = 0; ks2 < 2; ks2++) {
            s16x8 pa[NFI], zb[8];
            #pragma unroll
            for (int fi = 0; fi < NFI; fi++) {
                int row = wbase + fi * 16 + fr;
                int idx = (row * 64 + ks2 * 32 + fo) ^ ((row & 7) << 3);
                pa[fi] = *(const s16x8*)&Ps[idx];
            }
            #pragma unroll
            for (int fj = 0; fj < 8; fj++)
                zb[fj] = *(const s16x8*)&Zs[ks2 * 4096 + (fj * 16 + fr) * 32 + fo];
            #pragma unroll
            for (int fi = 0; fi < NFI; fi++)
                #pragma unroll
                for (int fj = 0; fj < 8; fj++)
                    oa[fi][fj] = __builtin_amdgcn_mfma_f32_16x16x32_bf16(pa[fi], zb[fj], oa[fi][fj], 0, 0, 0);
        }
        __syncthreads();
    }

    // epilogue
    #pragma unroll
    for (int fi = 0; fi < NFI; fi++)
        #pragma unroll
        for (int j = 0; j < 4; j++) {
            int row = wbase + fi * 16 + jr + j;
            if constexpr (MODE == 0) {
                float inv = 1.f / lrun[fi][j];
                #pragma unroll
                for (int fj = 0; fj < 8; fj++)
                    Op[(long long)(q0 + row) * DIM + h * 128 + fj * 16 + fr] = oa[fi][fj][j] * inv;
            } else {
                long long rb = (((long long)h * 512 + q0 + row) * NSPLIT + blockIdx.y) * 128;
                #pragma unroll
                for (int fj = 0; fj < 8; fj++)
                    Op[rb + fj * 16 + fr] = oa[fi][fj][j];
                if (fr == 0) {
                    long long si = ((long long)h * 512 + q0 + row) * NSPLIT + blockIdx.y;
                    Pm[si] = mold[fi][j];
                    Pl[si] = lrun[fi][j];
                }
            }
        }
}

// combine kv-split partials -> bvT bf16 [h][d][l]
__global__ __launch_bounds__(256)
void bv_combine(const float* __restrict__ PBV, const float* __restrict__ Pm,
                const float* __restrict__ Pl, ushort* __restrict__ BVTb)
{
    __shared__ float T[32][129];
    __shared__ float wc8[32][NSPLIT], invL[32];
    int t = threadIdx.x;
    int h = blockIdx.y, l0 = blockIdx.x * 32;
    if (t < 32) {
        long long base = ((long long)h * 512 + l0 + t) * NSPLIT;
        float m = -1e30f;
        float mv[NSPLIT], lv[NSPLIT];
        #pragma unroll
        for (int c = 0; c < NSPLIT; c++) { mv[c] = Pm[base + c]; lv[c] = Pl[base + c]; m = fmaxf(m, mv[c]); }
        float L = 0.f;
        #pragma unroll
        for (int c = 0; c < NSPLIT; c++) { float wv = __expf(mv[c] - m); wc8[t][c] = wv; L += wv * lv[c]; }
        invL[t] = 1.f / L;
    }
    __syncthreads();
    int l = t >> 3, dg = t & 7;
    long long rbase = ((long long)h * 512 + l0 + l) * NSPLIT * 128;
    #pragma unroll
    for (int dd = 0; dd < 16; dd++) {
        int d = dg * 16 + dd;
        float s = 0.f;
        #pragma unroll
        for (int c = 0; c < NSPLIT; c++) s += wc8[l][c] * PBV[rbase + c * 128 + d];
        T[l][d] = s * invL[l];
    }
    __syncthreads();
    int d = t >> 1, half = t & 1;
    #pragma unroll
    for (int lc = 0; lc < 16; lc++) {
        int l2 = half * 16 + lc;
        BVTb[(long long)h * 65536 + (long long)d * 512 + l0 + l2] = f2b(T[l2][d]);
    }
}

// ---------------- f32 -> bf16 convert ----------------
__global__ __launch_bounds__(256)
void cvt_bf16(const float* __restrict__ x, ushort* __restrict__ y, long long n)
{
    long long i = ((long long)blockIdx.x * 256 + threadIdx.x) * 8;
    if (i >= n) return;
    float4 a = *(const float4*)(x + i), b = *(const float4*)(x + i + 4);
    ushort4 u0 = {f2b(a.x), f2b(a.y), f2b(a.z), f2b(a.w)};
    ushort4 u1 = {f2b(b.x), f2b(b.y), f2b(b.z), f2b(b.w)};
    *(ushort4*)(y + i) = u0; *(ushort4*)(y + i + 4) = u1;
}

// ---------------- softmax fp32 rows (W = NIT*256) ----------------
template<int NIT>
__global__ __launch_bounds__(256)
void softmax_rows(float* __restrict__ X, int W)
{
    long long row = blockIdx.x;
    float* x = X + row * W;
    float r[NIT];
    float m = -1e30f;
    #pragma unroll
    for (int i = 0; i < NIT; i++) { r[i] = x[threadIdx.x + i * 256]; m = fmaxf(m, r[i]); }
    m = blk_max(m);
    float s = 0.f;
    #pragma unroll
    for (int i = 0; i < NIT; i++) { r[i] = __expf(r[i] - m); s += r[i]; }
    s = blk_sum(s);
    float inv = 1.f / s;
    #pragma unroll
    for (int i = 0; i < NIT; i++) x[threadIdx.x + i * 256] = r[i] * inv;
}

// ---------------- LN + front-pad -> bf16 ----------------
__global__ __launch_bounds__(256)
void ln_pad(const float* __restrict__ H, const float* __restrict__ g,
            const float* __restrict__ b, ushort* __restrict__ X)
{
    int row = blockIdx.x, t = threadIdx.x;
    ushort* o = X + (long long)row * DIM;
    if (row < PAD) {
        #pragma unroll
        for (int i = 0; i < 4; i++) o[t + i * 256] = 0;
        return;
    }
    const float* x = H + (long long)(row - PAD) * DIM;
    float r[4]; float s = 0.f;
    #pragma unroll
    for (int i = 0; i < 4; i++) { r[i] = x[t + i * 256]; s += r[i]; }
    float mu = blk_sum(s) * (1.f / DIM);
    float v = 0.f;
    #pragma unroll
    for (int i = 0; i < 4; i++) { float d = r[i] - mu; v += d * d; }
    float var = blk_sum(v) * (1.f / DIM);
    float rs = rsqrtf(var + 1e-5f);
    #pragma unroll
    for (int i = 0; i < 4; i++) { int c = t + i * 256; o[c] = f2b((r[i] - mu) * rs * g[c] + b[c]); }
}

// ---------------- landmarks ----------------
__global__ __launch_bounds__(128)
void landmarks(const ushort* __restrict__ QKVb, ushort* __restrict__ QL, ushort* __restrict__ KL)
{
    int L = blockIdx.x, h = blockIdx.y, d = threadIdx.x;
    float sq = 0.f, sk = 0.f;
    #pragma unroll
    for (int j = 0; j < LSUB; j++) {
        const ushort* p = QKVb + (long long)(L * LSUB + j) * 3072 + h * DHEAD + d;
        sq += b2f(p[0]);
        sk += b2f(p[1024]);
    }
    QL[(long long)(h * LMK + L) * DHEAD + d] = f2b(sq * (1.f / LSUB));
    KL[(long long)(h * LMK + L) * DHEAD + d] = f2b(sk * (1.f / LSUB));
}

// ---------------- V transpose -> bf16 VT[h][d][i] ----------------
__global__ void vtrans(const ushort* __restrict__ Q, ushort* __restrict__ VT)
{
    __shared__ ushort tile[32][33];
    int h = blockIdx.z, i0 = blockIdx.x * 32, d0 = blockIdx.y * 32;
    int tx = threadIdx.x, ty = threadIdx.y;
    for (int yy = ty; yy < 32; yy += 8)
        tile[yy][tx] = Q[(long long)(i0 + yy) * 3072 + 2048 + h * 128 + d0 + tx];
    __syncthreads();
    for (int yy = ty; yy < 32; yy += 8)
        VT[((long long)h * 128 + d0 + yy) * 6144 + i0 + tx] = tile[tx][yy];
}

// ---------------- a2 column sums ----------------
__global__ __launch_bounds__(256)
void a2_sums2(const float* __restrict__ A2, float* __restrict__ cols)
{
    int h = blockIdx.x, slice = blockIdx.y, t = threadIdx.x;
    const float* a = A2 + (long long)h * LMK * LMK + (long long)slice * 64 * LMK;
    float s0 = 0.f, s1 = 0.f;
    #pragma unroll 4
    for (int i = 0; i < 64; i++) {
        s0 += a[(long long)i * LMK + t];
        s1 += a[(long long)i * LMK + t + 256];
    }
    atomicAdd(&cols[h * LMK + t], s0);
    atomicAdd(&cols[h * LMK + t + 256], s1);
}
__global__ __launch_bounds__(256)
void a2_scal2(const float* __restrict__ cols, float* __restrict__ scal)
{
    float mc = -1e30f;
    for (int i = threadIdx.x; i < HEADS * LMK; i += 256) mc = fmaxf(mc, cols[i]);
    mc = blk_max(mc);
    if (threadIdx.x == 0) scal[0] = 1.f / mc;
}

// ---------------- z0/X prep ----------------
__global__ void z0_t(const float* __restrict__ A2, ushort* __restrict__ Xb,
                     ushort* __restrict__ Z0b, ushort* __restrict__ Z0T,
                     const float* __restrict__ scal)
{
    __shared__ float tile[32][33];
    int h = blockIdx.z;
    const float* a = A2 + (long long)h * LMK * LMK;
    float s = scal[0];
    int x0 = blockIdx.x * 32, y0 = blockIdx.y * 32;
    int tx = threadIdx.x, ty = threadIdx.y;
    long long hb = (long long)h * LMK * LMK;
    for (int yy = ty; yy < 32; yy += 8) {
        float v = a[(long long)(y0 + yy) * LMK + x0 + tx];
        tile[yy][tx] = v;
        Xb [hb + (long long)(y0 + yy) * LMK + x0 + tx] = f2b(v);
        Z0T[hb + (long long)(y0 + yy) * LMK + x0 + tx] = f2b(s * v);
    }
    __syncthreads();
    for (int yy = ty; yy < 32; yy += 8)
        Z0b[hb + (long long)(x0 + yy) * LMK + y0 + tx] = f2b(s * tile[tx][yy]);
}

// ---------------- MoE ----------------
__global__ __launch_bounds__(256)
void moe_combine(const float* __restrict__ X, const float* __restrict__ wg,
                 const ushort* __restrict__ EO, const float* __restrict__ eb,
                 float* __restrict__ H)
{
    int i = blockIdx.x, t = threadIdx.x;
    const float* x = X + (long long)i * INDIM;
    float g0 = 0.f, g1 = 0.f, g2 = 0.f;
    for (int f = t; f < INDIM; f += 256) {
        float xv = x[f];
        const float* w = wg + f * 3;
        g0 += xv * w[0]; g1 += xv * w[1]; g2 += xv * w[2];
    }
    g0 = blk_sum(g0); g1 = blk_sum(g1); g2 = blk_sum(g2);
    float m = fmaxf(g0, fmaxf(g1, g2));
    float e0 = __expf(g0 - m), e1 = __expf(g1 - m), e2 = __expf(g2 - m);
    float inv = 1.f / (e0 + e1 + e2);
    e0 *= inv; e1 *= inv; e2 *= inv;
    const ushort* eo = EO + (long long)i * 3072;
    for (int o = t; o < DIM; o += 256) {
        float v0 = fmaxf(b2f(eo[o])        + eb[o],        0.f);
        float v1 = fmaxf(b2f(eo[1024 + o]) + eb[1024 + o], 0.f);
        float v2 = fmaxf(b2f(eo[2048 + o]) + eb[2048 + o], 0.f);
        float r = e0 * v0 + e1 * v1 + e2 * v2;
        H[(long long)(1 + i) * DIM + o] = r;
        if (i < 84) H[(long long)(6001 + i) * DIM + o] = r;
    }
}

__global__ void cls_copy(const float* __restrict__ c, float* __restrict__ H)
{
    for (int i = threadIdx.x; i < DIM; i += 256) H[i] = c[i];
}

// ---------------- res conv: Ob = bf16(O + depthwise33(V)) (coalesced) ----------------
__global__ __launch_bounds__(256)
void resconv(const ushort* __restrict__ QKVb, const float* __restrict__ rw,
             const float* __restrict__ O, ushort* __restrict__ Ob)
{
    long long idx = (long long)blockIdx.x * 256 + threadIdx.x;
    int c = (int)(idx & 1023);
    long long i = idx >> 10;
    int h = c >> 7;
    float acc = O[idx];
    #pragma unroll
    for (int t = 0; t < 33; t++) {
        long long r = i + t - 16;
        if (r >= 0 && r < NPL) acc += rw[h * 33 + t] * b2f(QKVb[r * 3072 + 2048 + c]);
    }
    Ob[idx] = f2b(acc);
}

// ---------------- PPEG ----------------
__global__ void h2f(const float* __restrict__ H, float* __restrict__ F)
{
    __shared__ float tile[32][33];
    int p0 = blockIdx.x * 32, c0 = blockIdx.y * 32;
    int tx = threadIdx.x, ty = threadIdx.y;
    for (int yy = ty; yy < 32; yy += 8) {
        int p = p0 + yy;
        if (p < HW * HW) tile[yy][tx] = H[(long long)(1 + p) * DIM + c0 + tx];
    }
    __syncthreads();
    for (int yy = ty; yy < 32; yy += 8) {
        int p = p0 + tx, c = c0 + yy;
        if (p < HW * HW) F[(long long)c * (HW * HW) + p] = tile[tx][yy];
    }
}
__global__ void f2h(const float* __restrict__ F2, float* __restrict__ H)
{
    __shared__ float tile[32][33];
    int c0 = blockIdx.x * 32, p0 = blockIdx.y * 32;
    int tx = threadIdx.x, ty = threadIdx.y;
    for (int yy = ty; yy < 32; yy += 8) {
        int p = p0 + tx;
        if (p < HW * HW) tile[yy][tx] = F2[(long long)(c0 + yy) * (HW * HW) + p];
    }
    __syncthreads();
    for (int yy = ty; yy < 32; yy += 8) {
        int p = p0 + yy;
        if (p < HW * HW) H[(long long)(1 + p) * DIM + c0 + tx] = tile[tx][yy];
    }
}
__global__ __launch_bounds__(256)
void ppeg_conv2(const float* __restrict__ F,
                const float* __restrict__ w7, const float* __restrict__ b7,
                const float* __restrict__ w5, const float* __restrict__ b5,
                const float* __restrict__ w3, const float* __restrict__ b3,
                float* __restrict__ F2)
{
    int c = blockIdx.x, t = threadIdx.x;
    __shared__ float plane[HW * HW];
    __shared__ float wm[49];
    for (int p = t; p < HW * HW; p += 256) plane[p] = F[(long long)c * (HW * HW) + p];
    if (t < 49) {
        int ky = t / 7 - 3, kx = t % 7 - 3;
        float w = w7[(long long)c * 49 + t];
        if (ky >= -2 && ky <= 2 && kx >= -2 && kx <= 2) w += w5[(long long)c * 25 + (ky + 2) * 5 + (kx + 2)];
        if (ky >= -1 && ky <= 1 && kx >= -1 && kx <= 1) w += w3[(long long)c * 9 + (ky + 1) * 3 + (kx + 1)];
        if (t == 24) w += 1.0f;
        wm[t] = w;
    }
    __syncthreads();
    float bsum = b7[c] + b5[c] + b3[c];
    for (int p = t; p < HW * HW; p += 256) {
        int y = p / HW, x = p - y * HW;
        float acc = bsum;
        if (y >= 3 && y < HW - 3 && x >= 3 && x < HW - 3) {
            const float* base = &plane[p];
            #pragma unroll
            for (int ky = -3; ky <= 3; ky++)
                #pragma unroll
                for (int kx = -3; kx <= 3; kx++)
                    acc += wm[(ky + 3) * 7 + kx + 3] * base[ky * HW + kx];
        } else {
            for (int ky = -3; ky <= 3; ky++) {
                int yy = y + ky; if ((unsigned)yy >= (unsigned)HW) continue;
                for (int kx = -3; kx <= 3; kx++) {
                    int xx = x + kx; if ((unsigned)xx >= (unsigned)HW) continue;
                    acc += wm[(ky + 3) * 7 + kx + 3] * plane[yy * HW + xx];
                }
            }
        }
        F2[(long long)c * (HW * HW) + p] = acc;
    }
}

// ---------------- final head ----------------
__global__ __launch_bounds__(256)
void head_k(const float* __restrict__ H, const float* __restrict__ g, const float* __restrict__ b,
            const float* __restrict__ fw, const float* __restrict__ fb, float* __restrict__ out)
{
    int t = threadIdx.x;
    float r[4]; float s = 0.f;
    #pragma unroll
    for (int i = 0; i < 4; i++) { r[i] = H[t + i * 256]; s += r[i]; }
    float mu = blk_sum(s) * (1.f / DIM);
    float v = 0.f;
    #pragma unroll
    for (int i = 0; i < 4; i++) { float d = r[i] - mu; v += d * d; }
    float var = blk_sum(v) * (1.f / DIM);
    float rs = rsqrtf(var + 1e-5f);
    float d0 = 0.f, d1 = 0.f;
    #pragma unroll
    for (int i = 0; i < 4; i++) {
        int c = t + i * 256;
        float hv = (r[i] - mu) * rs * g[c] + b[c];
        d0 += hv * fw[c];
        d1 += hv * fw[DIM + c];
    }
    d0 = blk_sum(d0); d1 = blk_sum(d1);
    if (t == 0) {
        float l0 = d0 + fb[0], l1 = d1 + fb[1];
        float m = fmaxf(l0, l1);
        float e0 = __expf(l0 - m), e1 = __expf(l1 - m);
        float inv = 1.f / (e0 + e1);
        out[0] = l0; out[1] = l1;
        out[2] = e0 * inv; out[3] = e1 * inv;
        out[4] = (l1 > l0) ? 1.0f : 0.0f;
    }
}

// ---------------- host ----------------
extern "C" void kernel_launch(void* const* d_in, const int* in_sizes, int n_in,
                              void* d_out, int out_size, void* d_ws, size_t ws_size,
                              hipStream_t stream)
{
    const float* data     = (const float*)d_in[0];
    const float* w_gate   = (const float*)d_in[1];
    const float* expert_w = (const float*)d_in[2];
    const float* expert_b = (const float*)d_in[3];
    const float* cls_tok  = (const float*)d_in[4];
    const float* ln_g[2]  = {(const float*)d_in[5],  (const float*)d_in[11]};
    const float* ln_b[2]  = {(const float*)d_in[6],  (const float*)d_in[12]};
    const float* qkv_w[2] = {(const float*)d_in[7],  (const float*)d_in[13]};
    const float* out_w[2] = {(const float*)d_in[8],  (const float*)d_in[14]};
    const float* out_b[2] = {(const float*)d_in[9],  (const float*)d_in[15]};
    const float* res_w[2] = {(const float*)d_in[10], (const float*)d_in[16]};
    const float* pw7 = (const float*)d_in[17]; const float* pb7 = (const float*)d_in[18];
    const float* pw5 = (const float*)d_in[19]; const float* pb5 = (const float*)d_in[20];
    const float* pw3 = (const float*)d_in[21]; const float* pb3 = (const float*)d_in[22];
    const float* nf_g = (const float*)d_in[23]; const float* nf_b = (const float*)d_in[24];
    const float* fc2w = (const float*)d_in[25]; const float* fc2b = (const float*)d_in[26];

    float*  ws    = (float*)d_ws;
    float*  H     = ws + OFF_H;
    ushort* LNXb  = (ushort*)(ws + OFF_LNXO);
    float*  O     = ws + OFF_LNXO;             // alias: O written after LNXb dead
    ushort* QKVb  = (ushort*)(ws + OFF_QKVB);
    ushort* EOb   = (ushort*)(ws + OFF_QKVB);
    float*  PBV   = ws + OFF_PBV;
    float*  PM    = ws + OFF_PM;
    float*  PL    = ws + OFF_PL;
    ushort* Ob    = (ushort*)(ws + OFF_OB);
    ushort* VT    = (ushort*)(ws + OFF_VT);
    ushort* QL    = (ushort*)(ws + OFF_QL);
    ushort* KL    = (ushort*)(ws + OFF_KL);
    float*  A2F   = ws + OFF_A2F;
    ushort* BVTb  = (ushort*)(ws + OFF_BVTB);
    ushort* Xb    = (ushort*)(ws + OFF_XB);
    ushort* XZB   = (ushort*)(ws + OFF_XZB);
    ushort* XZT7  = (ushort*)(ws + OFF_XZT7);
    ushort* PT15  = (ushort*)(ws + OFF_PT15);
    ushort* QT13  = (ushort*)(ws + OFF_QT13);
    ushort* ZB[2] = {(ushort*)(ws + OFF_ZB0), (ushort*)(ws + OFF_ZB1)};
    ushort* ZT[2] = {(ushort*)(ws + OFF_ZT0), (ushort*)(ws + OFF_ZT1)};
    ushort* ZBT   = (ushort*)(ws + OFF_ZBT);
    ushort* QWB   = (ushort*)(ws + OFF_QWB);
    ushort* OWB   = (ushort*)(ws + OFF_OWB);
    ushort* DATAB = (ushort*)(ws + OFF_DATAB);
    ushort* EWB   = (ushort*)(ws + OFF_EWB);
    float*  COLS  = ws + OFF_COLS;
    float*  SCAL  = ws + OFF_SCAL;

    const long long HSB = (long long)LMK * DHEAD;   // 65536
    const long long A2S = (long long)LMK * LMK;     // 262144

    // ---- MoE ----
    cvt_bf16<<<4500, 256, 0, stream>>>(data, DATAB, (long long)NTOK * INDIM);
    cvt_bf16<<<2304, 256, 0, stream>>>(expert_w, EWB, 3072LL * INDIM);
    mg<2><<<dim3(24,47,1),256,0,stream>>>(DATAB,INDIM,0, EWB,INDIM,0, EOb,3072,0,
        nullptr,0,0, NTOK,INDIM, nullptr, 1.f,0.f,0.f);
    moe_combine<<<NTOK,256,0,stream>>>(data, w_gate, EOb, expert_b, H);
    cls_copy<<<1,256,0,stream>>>(cls_tok, H);

    for (int stage = 0; stage < 2; stage++) {
        cvt_bf16<<<1536, 256, 0, stream>>>(qkv_w[stage], QWB, 3072LL * DIM);
        cvt_bf16<<<512, 256, 0, stream>>>(out_w[stage], OWB, (long long)DIM * DIM);
        ln_pad<<<NPL,256,0,stream>>>(H, ln_g[stage], ln_b[stage], LNXb);
        mg<1><<<dim3(24,48,1),256,0,stream>>>(LNXb,DIM,0, QWB,DIM,0, QKVb,3072,0,
            nullptr,0,0, NPL,DIM, nullptr, 1.f,0.f,0.f);
        landmarks<<<dim3(LMK,HEADS),128,0,stream>>>(QKVb, QL, KL);
        vtrans<<<dim3(192,4,8),dim3(32,8),0,stream>>>(QKVb, VT);
        // a2 = softmax(ql @ kl^T) f32  (64x128 tiles -> 256 blocks)
        mg64<0><<<dim3(4,8,8),256,0,stream>>>(QL,DHEAD,HSB, KL,DHEAD,HSB, A2F,LMK,A2S,
            nullptr,0,0, DHEAD, 1.f,0.f,0.f);
        softmax_rows<2><<<HEADS*LMK,256,0,stream>>>(A2F, LMK);
        hipMemsetAsync(COLS, 0, HEADS * LMK * sizeof(float), stream);
        a2_sums2<<<dim3(HEADS,8),256,0,stream>>>(A2F, COLS);
        a2_scal2<<<1,256,0,stream>>>(COLS, SCAL);
        z0_t<<<dim3(16,16,8),dim3(32,8),0,stream>>>(A2F, Xb, ZB[0], ZT[0], SCAL);
        // Newton-Schulz: 6 iterations, 64x128-tile GEMMs (256 blocks = all CUs)
        int cur = 0;
        for (int it = 0; it < 6; it++) {
            mg64<4><<<dim3(4,8,8),256,0,stream>>>(Xb,LMK,A2S, ZT[cur],LMK,A2S, XZB,LMK,A2S,
                XZT7,LMK,A2S, LMK, 1.f, 7.f, -1.f);
            mg64<5><<<dim3(4,8,8),256,0,stream>>>(XZB,LMK,A2S, XZT7,LMK,A2S, nullptr,0,0,
                PT15,LMK,A2S, LMK, 1.f, 15.f, -1.f);
            mg64<5><<<dim3(4,8,8),256,0,stream>>>(XZB,LMK,A2S, PT15,LMK,A2S, nullptr,0,0,
                QT13,LMK,A2S, LMK, 1.f, 13.f, -1.f);
            if (it < 5)
                mg64<4><<<dim3(4,8,8),256,0,stream>>>(ZB[cur],LMK,A2S, QT13,LMK,A2S, ZB[1-cur],LMK,A2S,
                    ZT[1-cur],LMK,A2S, LMK, 0.25f, 0.f, 1.f);
            else
                mg64<2><<<dim3(4,8,8),256,0,stream>>>(ZB[cur],LMK,A2S, QT13,LMK,A2S, ZB[1-cur],LMK,A2S,
                    nullptr,0,0, LMK, 0.25f, 0.f, 1.f);
            cur = 1 - cur;
        }
        ushort* Z6 = ZB[cur];
        // flash a3: partial bv over 16 kv-chunks of 384
        flash<1,2><<<dim3(4,NSPLIT,8),256,0,stream>>>(QL,DHEAD,HSB, QKVb+1024,3072,128,
            VT,NPL,(long long)DHEAD*NPL, PBV, PM, PL, 6, 384);
        bv_combine<<<dim3(16,8),256,0,stream>>>(PBV, PM, PL, BVTb);
        // ZBT[d][l'] = sum_l bvT[d][l] z6[l'][l]  (64 blocks)
        mg64<2><<<dim3(4,2,8),256,0,stream>>>(BVTb,LMK,HSB, Z6,LMK,A2S, ZBT,LMK,HSB,
            nullptr,0,0, LMK, 1.f,0.f,0.f);
        // flash a1: O = softmax(q @ kl^T) @ zb  (64-row q tiles, 768 blocks)
        flash<0,1><<<dim3(96,1,8),256,0,stream>>>(QKVb,3072,128, KL,DHEAD,HSB,
            ZBT,LMK,HSB, O, nullptr, nullptr, 8, 0);
        // Ob = bf16(O + res conv of v)
        resconv<<<(NPL*DIM)/256,256,0,stream>>>(QKVb, res_w[stage], O, Ob);
        // H += Ob @ out_w^T + out_b
        mg<3><<<dim3(8,48,1),256,0,stream>>>(Ob + (long long)PAD*DIM,DIM,0, OWB,DIM,0, H,DIM,0,
            nullptr,0,0, NH,DIM, out_b[stage], 1.f,0.f,0.f);
        if (stage == 0) {
            float* F  = ws + OFF_QKVB;
            float* F2 = F + 6230016LL;
            h2f<<<dim3(191,32),dim3(32,8),0,stream>>>(H, F);
            ppeg_conv2<<<DIM,256,0,stream>>>(F, pw7, pb7, pw5, pb5, pw3, pb3, F2);
            f2h<<<dim3(32,191),dim3(32,8),0,stream>>>(F2, H);
        }
    }

    head_k<<<1,256,0,stream>>>(H, nf_g, nf_b, fc2w, fc2b, (float*)d_out);
}

// Round 11
// 1564.060 us; speedup vs baseline: 1.6713x; 1.0622x over previous
//
#include <hip/hip_runtime.h>
#include <hip/hip_bf16.h>

// ---------------- constants ----------------
#define NTOK   6000
#define INDIM  1536
#define DIM    1024
#define NPL    6144
#define PAD    59
#define NH     6085
#define HEADS  8
#define DHEAD  128
#define LMK    512
#define LSUB   12
#define HW     78
#define QSCALE 0.08838834764831845f
#define NSPLIT 16

// ---------------- ws layout (float-slot offsets) ----------------
#define OFF_H     0LL          // 6144*1024 f32
#define OFF_LNXO  6291456LL    // LNXb bf16 / O f32 alias
#define OFF_QKVB  12582912LL   // 6144*3072 bf16; EO bf16 + PPEG planes alias
#define OFF_PBV   22020096LL   // 8h*512*16c*128 f32 = 8388608
#define OFF_PM    30408704LL   // 65536
#define OFF_PL    30474240LL   // 65536
#define OFF_OB    30539776LL   // 6144*1024 bf16 = 3145728 slots (ends 33685504)
#define OFF_VT    34603008LL   // 8*128*6144 bf16
#define OFF_QL    37748736LL
#define OFF_KL    38010880LL
#define OFF_A2F   38273024LL   // 8*512*512 f32
#define OFF_BVTB  40370176LL   // 8*128*512 bf16
#define OFF_XB    42467328LL   // bf16 8*512*512 each below
#define OFF_XZB   43515904LL
#define OFF_XZT7  44564480LL
#define OFF_PT15  45613056LL
#define OFF_QT13  46661632LL
#define OFF_ZB0   47710208LL
#define OFF_ZT0   48758784LL
#define OFF_ZB1   49807360LL
#define OFF_ZT1   50855936LL
#define OFF_ZBT   52428800LL   // 8*128*512 bf16
#define OFF_QWB   52690944LL   // 3072*1024 bf16
#define OFF_OWB   54263808LL   // 1024*1024 bf16
#define OFF_COLS  54788096LL
#define OFF_SCAL  54796288LL
// transient aliases (dead before overlapping buffers are written)
#define OFF_DATAB 31457280LL   // 6000*1536 bf16 (pre-stage only; overlaps OB/VT span)
#define OFF_EWB   36065280LL   // 3072*1536 bf16 (pre-stage only)

typedef __attribute__((ext_vector_type(8))) short s16x8;
typedef __attribute__((ext_vector_type(4))) float f32x4;

// ---------------- bf16 helpers ----------------
__device__ __forceinline__ ushort f2b(float f) {
    union { float f; unsigned u; } v; v.f = f;
    return (ushort)((v.u + 0x7FFF + ((v.u >> 16) & 1)) >> 16);
}
__device__ __forceinline__ float b2f(ushort h) {
    union { unsigned u; float f; } v; v.u = ((unsigned)h) << 16; return v.f;
}

// async global->LDS, 16 bytes per lane; lds ptr must be wave-uniform
__device__ __forceinline__ void gld16(const void* g, void* l) {
    __builtin_amdgcn_global_load_lds((const __attribute__((address_space(1))) void*)g,
                                     (__attribute__((address_space(3))) void*)l, 16, 0, 0);
}

// ---------------- reductions (blockDim.x == 256) ----------------
__device__ __forceinline__ float blk_sum(float v) {
    __shared__ float sb[4];
    #pragma unroll
    for (int o = 32; o > 0; o >>= 1) v += __shfl_down(v, o);
    int lane = threadIdx.x & 63, w = threadIdx.x >> 6;
    __syncthreads();
    if (lane == 0) sb[w] = v;
    __syncthreads();
    return sb[0] + sb[1] + sb[2] + sb[3];
}
__device__ __forceinline__ float blk_max(float v) {
    __shared__ float sb[4];
    #pragma unroll
    for (int o = 32; o > 0; o >>= 1) v = fmaxf(v, __shfl_down(v, o));
    int lane = threadIdx.x & 63, w = threadIdx.x >> 6;
    __syncthreads();
    if (lane == 0) sb[w] = v;
    __syncthreads();
    return fmaxf(fmaxf(sb[0], sb[1]), fmaxf(sb[2], sb[3]));
}

// ================= MFMA GEMM (bf16 x bf16), C = alpha * A @ B^T, 128x128 tile =================
// BK=64 (2 MFMA sub-steps per barrier pair). Requires K % 64 == 0.
// EPI: 0 f32 | 1 bf16 qkv-scale | 2 bf16 | 3 f32 += v+bias
//      4 bf16 C + bf16 T[c][r]=tdelta*(r==c)+tsign*v | 5 T only
template<int EPI>
__global__ __launch_bounds__(256)
void mg(const ushort* __restrict__ A, int lda, long long sA,
        const ushort* __restrict__ B, int ldb, long long sB,
        void* __restrict__ Cp, int ldc, long long sC,
        void* __restrict__ Tp, int ldt, long long sT,
        int M, int K, const float* __restrict__ bias,
        float alpha, float tdelta, float tsign)
{
    __shared__ ushort As[8192];   // 2 subtiles [128][32]
    __shared__ ushort Bs[8192];
    const int t = threadIdx.x;
    const int z = blockIdx.z;
    const ushort* Ab = A + (long long)z * sA;
    const ushort* Bb = B + (long long)z * sB;
    const int row0 = blockIdx.y * 128, col0 = blockIdx.x * 128;
    const int w = t >> 6, lane = t & 63;
    const int l4 = lane >> 2, ls = (lane & 3) * 8;
    const int q0 = w, q1 = 4 + w;
    int ar0 = row0 + q0 * 16 + l4; if (ar0 >= M) ar0 = M - 1;
    int ar1 = row0 + q1 * 16 + l4; if (ar1 >= M) ar1 = M - 1;
    const int br0 = col0 + q0 * 16 + l4;
    const int br1 = col0 + q1 * 16 + l4;
    const ushort* ap0 = Ab + (long long)ar0 * lda + ls;
    const ushort* ap1 = Ab + (long long)ar1 * lda + ls;
    const ushort* bp0 = Bb + (long long)br0 * ldb + ls;
    const ushort* bp1 = Bb + (long long)br1 * ldb + ls;
    ushort* asl0 = &As[q0 * 512];
    ushort* asl1 = &As[q1 * 512];
    ushort* bsl0 = &Bs[q0 * 512];
    ushort* bsl1 = &Bs[q1 * 512];

    const int wr = (w >> 1) * 64, wc = (w & 1) * 64;
    const int fr = lane & 15, fo = (lane >> 4) * 8;

    f32x4 acc[4][4];
    #pragma unroll
    for (int a = 0; a < 4; a++)
        #pragma unroll
        for (int b = 0; b < 4; b++)
            acc[a][b] = (f32x4){0.f, 0.f, 0.f, 0.f};

    for (int kt = 0; kt < K; kt += 64) {
        gld16(ap0 + kt, asl0);
        gld16(ap1 + kt, asl1);
        gld16(bp0 + kt, bsl0);
        gld16(bp1 + kt, bsl1);
        gld16(ap0 + kt + 32, asl0 + 4096);
        gld16(ap1 + kt + 32, asl1 + 4096);
        gld16(bp0 + kt + 32, bsl0 + 4096);
        gld16(bp1 + kt + 32, bsl1 + 4096);
        __syncthreads();
        #pragma unroll
        for (int half = 0; half < 2; half++) {
            s16x8 af[4], bf[4];
            #pragma unroll
            for (int a = 0; a < 4; a++) af[a] = *(const s16x8*)&As[half * 4096 + (wr + a * 16 + fr) * 32 + fo];
            #pragma unroll
            for (int b = 0; b < 4; b++) bf[b] = *(const s16x8*)&Bs[half * 4096 + (wc + b * 16 + fr) * 32 + fo];
            #pragma unroll
            for (int a = 0; a < 4; a++)
                #pragma unroll
                for (int b = 0; b < 4; b++)
                    acc[a][b] = __builtin_amdgcn_mfma_f32_16x16x32_bf16(af[a], bf[b], acc[a][b], 0, 0, 0);
        }
        __syncthreads();
    }

    const int er0 = row0 + wr + ((lane >> 4) << 2);
    const int ec0 = col0 + wc + fr;
    #pragma unroll
    for (int a = 0; a < 4; a++) {
        #pragma unroll
        for (int j = 0; j < 4; j++) {
            int r = er0 + a * 16 + j;
            if (r >= M) continue;
            #pragma unroll
            for (int b = 0; b < 4; b++) {
                int c = ec0 + b * 16;
                float v = alpha * acc[a][b][j];
                long long ci = z * sC + (long long)r * ldc + c;
                if constexpr (EPI == 0) ((float*)Cp)[ci] = v;
                else if constexpr (EPI == 1) ((ushort*)Cp)[ci] = f2b(c < 1024 ? v * QSCALE : v);
                else if constexpr (EPI == 2) ((ushort*)Cp)[ci] = f2b(v);
                else if constexpr (EPI == 3) ((float*)Cp)[ci] += v + bias[c];
                else {
                    ushort tv = f2b((r == c ? tdelta : 0.f) + tsign * v);
                    long long ti = z * sT + (long long)c * ldt + r;
                    if constexpr (EPI == 4) { ((ushort*)Cp)[ci] = f2b(v); ((ushort*)Tp)[ti] = tv; }
                    else { ((ushort*)Tp)[ti] = tv; }  // 5
                }
            }
        }
    }
}

// ================= MFMA GEMM 64x128 tile — for small batched GEMMs =================
// C = alpha * A @ B^T. Requires M%64==0, N%128==0, K%64==0. Grid (N/128, M/64, Z). BK=64.
// EPI: 0 f32 | 2 bf16 | 4 bf16 C + bf16 T[c][r]=tdelta*(r==c)+tsign*v | 5 T only
template<int EPI>
__global__ __launch_bounds__(256)
void mg64(const ushort* __restrict__ A, int lda, long long sA,
          const ushort* __restrict__ B, int ldb, long long sB,
          void* __restrict__ Cp, int ldc, long long sC,
          void* __restrict__ Tp, int ldt, long long sT,
          int K, float alpha, float tdelta, float tsign)
{
    __shared__ ushort As[4096];   // 2 subtiles [64][32]
    __shared__ ushort Bs[8192];   // 2 subtiles [128][32]
    const int t = threadIdx.x;
    const int z = blockIdx.z;
    const ushort* Ab = A + (long long)z * sA;
    const ushort* Bb = B + (long long)z * sB;
    const int row0 = blockIdx.y * 64, col0 = blockIdx.x * 128;
    const int w = t >> 6, lane = t & 63;
    const int l4 = lane >> 2, ls = (lane & 3) * 8;
    const ushort* ap = Ab + (long long)(row0 + w * 16 + l4) * lda + ls;
    ushort* asl = &As[w * 16 * 32];
    const ushort* bp0 = Bb + (long long)(col0 + w * 16 + l4) * ldb + ls;
    const ushort* bp1 = Bb + (long long)(col0 + 64 + w * 16 + l4) * ldb + ls;
    ushort* bsl0 = &Bs[w * 16 * 32];
    ushort* bsl1 = &Bs[(64 + w * 16) * 32];

    const int fr = lane & 15, fo = (lane >> 4) * 8;

    f32x4 acc[4][2];
    #pragma unroll
    for (int a = 0; a < 4; a++)
        #pragma unroll
        for (int b = 0; b < 2; b++)
            acc[a][b] = (f32x4){0.f, 0.f, 0.f, 0.f};

    for (int kt = 0; kt < K; kt += 64) {
        gld16(ap + kt, asl);
        gld16(bp0 + kt, bsl0);
        gld16(bp1 + kt, bsl1);
        gld16(ap + kt + 32, asl + 2048);
        gld16(bp0 + kt + 32, bsl0 + 4096);
        gld16(bp1 + kt + 32, bsl1 + 4096);
        __syncthreads();
        #pragma unroll
        for (int half = 0; half < 2; half++) {
            s16x8 af[4], bf[2];
            #pragma unroll
            for (int a = 0; a < 4; a++) af[a] = *(const s16x8*)&As[half * 2048 + (a * 16 + fr) * 32 + fo];
            #pragma unroll
            for (int b = 0; b < 2; b++) bf[b] = *(const s16x8*)&Bs[half * 4096 + (w * 32 + b * 16 + fr) * 32 + fo];
            #pragma unroll
            for (int a = 0; a < 4; a++)
                #pragma unroll
                for (int b = 0; b < 2; b++)
                    acc[a][b] = __builtin_amdgcn_mfma_f32_16x16x32_bf16(af[a], bf[b], acc[a][b], 0, 0, 0);
        }
        __syncthreads();
    }

    const int er0 = row0 + ((lane >> 4) << 2);
    const int ec0 = col0 + w * 32 + fr;
    #pragma unroll
    for (int a = 0; a < 4; a++) {
        #pragma unroll
        for (int j = 0; j < 4; j++) {
            int r = er0 + a * 16 + j;
            #pragma unroll
            for (int b = 0; b < 2; b++) {
                int c = ec0 + b * 16;
                float v = alpha * acc[a][b][j];
                long long ci = z * sC + (long long)r * ldc + c;
                if constexpr (EPI == 0) ((float*)Cp)[ci] = v;
                else if constexpr (EPI == 2) ((ushort*)Cp)[ci] = f2b(v);
                else {
                    ushort tv = f2b((r == c ? tdelta : 0.f) + tsign * v);
                    long long ti = z * sT + (long long)c * ldt + r;
                    if constexpr (EPI == 4) { ((ushort*)Cp)[ci] = f2b(v); ((ushort*)Tp)[ti] = tv; }
                    else { ((ushort*)Tp)[ti] = tv; }  // 5
                }
            }
        }
    }
}

// ================= fused flash attention =================
// Q in registers; q tile = NFI*64 rows (wave owns NFI*16 rows); KV chunks of 64.
// Online softmax with defer-max (RESCALE_THRESHOLD=8) and setprio around MFMA clusters.
// MODE 0: final f32 output to Op (cols h*128..); MODE 1: partial (acc,m,l) per kv-split.
template<int MODE, int NFI>
__global__ __launch_bounds__(256)
void flash(const ushort* __restrict__ Qp, int ldq, long long sQh,
           const ushort* __restrict__ Kp, int ldk, long long sKh,
           const ushort* __restrict__ Vp, int ldv, long long sVh,
           float* __restrict__ Op, float* __restrict__ Pm, float* __restrict__ Pl,
           int nkv, int kvspan)
{
    __shared__ ushort Zs[8192];    // 2 subtiles [128][32] (Vt chunk)
    __shared__ ushort KPs[8192];   // 4 subtiles [64][32] (K chunk); aliased by P [NFI*64][64] swizzled
    ushort* Ps = KPs;
    const int t = threadIdx.x;
    const int h = blockIdx.z;
    const int q0 = blockIdx.x * (NFI * 64);
    const int kvbase = blockIdx.y * kvspan;
    const ushort* Qb = Qp + (long long)h * sQh;
    const ushort* Kb = Kp + (long long)h * sKh;
    const ushort* Vb = Vp + (long long)h * sVh;
    const int w = t >> 6, lane = t & 63;
    const int sr = lane >> 2, sc2 = (lane & 3) * 8;
    const int fr = lane & 15, fo = (lane >> 4) * 8;
    const int jr = (lane >> 4) * 4;
    const int wbase = w * (NFI * 16);

    // Q fragments directly to registers (reused across all kv chunks)
    s16x8 qr[NFI][4];
    #pragma unroll
    for (int fi = 0; fi < NFI; fi++)
        #pragma unroll
        for (int ks = 0; ks < 4; ks++)
            qr[fi][ks] = *(const s16x8*)&Qb[(long long)(q0 + wbase + fi * 16 + fr) * ldq + ks * 32 + fo];

    f32x4 oa[NFI][8];
    float mold[NFI][4], lrun[NFI][4];
    #pragma unroll
    for (int fi = 0; fi < NFI; fi++) {
        #pragma unroll
        for (int fj = 0; fj < 8; fj++) oa[fi][fj] = (f32x4){0.f,0.f,0.f,0.f};
        #pragma unroll
        for (int j = 0; j < 4; j++) { mold[fi][j] = -1e30f; lrun[fi][j] = 0.f; }
    }

    for (int c = 0; c < nkv; c++) {
        int kvp = kvbase + c * 64;
        #pragma unroll
        for (int s = 0; s < 4; s++)
            gld16(Kb + (long long)(kvp + w * 16 + sr) * ldk + s * 32 + sc2,
                  &KPs[s * 2048 + (w * 16) * 32]);
        #pragma unroll
        for (int s = 0; s < 2; s++)
            #pragma unroll
            for (int r0 = 0; r0 < 128; r0 += 64)
                gld16(Vb + (long long)(r0 + w * 16 + sr) * ldv + kvp + s * 32 + sc2,
                      &Zs[s * 4096 + (r0 + w * 16) * 32]);
        __syncthreads();

        f32x4 acc[NFI][4];
        #pragma unroll
        for (int fi = 0; fi < NFI; fi++)
            #pragma unroll
            for (int fj = 0; fj < 4; fj++) acc[fi][fj] = (f32x4){0.f,0.f,0.f,0.f};
        __builtin_amdgcn_s_setprio(1);
        #pragma unroll
        for (int ks = 0; ks < 4; ks++) {
            s16x8 kb[4];
            #pragma unroll
            for (int fj = 0; fj < 4; fj++)
                kb[fj] = *(const s16x8*)&KPs[ks * 2048 + (fj * 16 + fr) * 32 + fo];
            #pragma unroll
            for (int fi = 0; fi < NFI; fi++)
                #pragma unroll
                for (int fj = 0; fj < 4; fj++)
                    acc[fi][fj] = __builtin_amdgcn_mfma_f32_16x16x32_bf16(qr[fi][ks], kb[fj], acc[fi][fj], 0, 0, 0);
        }
        __builtin_amdgcn_s_setprio(0);

        // online softmax with defer-max (threshold 8)
        float mx[NFI][4];
        bool need = false;
        #pragma unroll
        for (int fi = 0; fi < NFI; fi++) {
            #pragma unroll
            for (int j = 0; j < 4; j++) {
                float m0 = acc[fi][0][j];
                #pragma unroll
                for (int fj = 1; fj < 4; fj++) m0 = fmaxf(m0, acc[fi][fj][j]);
                m0 = fmaxf(m0, __shfl_xor(m0, 1));
                m0 = fmaxf(m0, __shfl_xor(m0, 2));
                m0 = fmaxf(m0, __shfl_xor(m0, 4));
                m0 = fmaxf(m0, __shfl_xor(m0, 8));
                mx[fi][j] = m0;
                need = need || (m0 - mold[fi][j] > 8.f);
            }
        }
        if (__any(need)) {
            #pragma unroll
            for (int fi = 0; fi < NFI; fi++)
                #pragma unroll
                for (int j = 0; j < 4; j++) {
                    float mn = fmaxf(mold[fi][j], mx[fi][j]);
                    float scl = __expf(mold[fi][j] - mn);
                    mold[fi][j] = mn;
                    lrun[fi][j] *= scl;
                    #pragma unroll
                    for (int fj = 0; fj < 8; fj++) oa[fi][fj][j] *= scl;
                }
        }
        float rs[NFI][4];
        #pragma unroll
        for (int fi = 0; fi < NFI; fi++) {
            #pragma unroll
            for (int j = 0; j < 4; j++) {
                float r = 0.f;
                #pragma unroll
                for (int fj = 0; fj < 4; fj++) {
                    float p = __expf(acc[fi][fj][j] - mold[fi][j]);
                    acc[fi][fj][j] = p;
                    r += p;
                }
                r += __shfl_xor(r, 1);
                r += __shfl_xor(r, 2);
                r += __shfl_xor(r, 4);
                r += __shfl_xor(r, 8);
                rs[fi][j] = r;
            }
        }
        __syncthreads();   // all waves done reading KPs
        #pragma unroll
        for (int fi = 0; fi < NFI; fi++)
            #pragma unroll
            for (int j = 0; j < 4; j++) {
                int row = wbase + fi * 16 + jr + j;
                lrun[fi][j] += rs[fi][j];
                #pragma unroll
                for (int fj = 0; fj < 4; fj++) {
                    int idx = (row * 64 + fj * 16 + fr) ^ ((row & 7) << 3);
                    Ps[idx] = f2b(acc[fi][fj][j]);
                }
            }
        __syncthreads();   // P visible

        __builtin_amdgcn_s_setprio(1);
        #pragma unroll
        for (int ks2 = 0; ks2 < 2; ks2++) {
            s16x8 pa[NFI], zb[8];
            #pragma unroll
            for (int fi = 0; fi < NFI; fi++) {
                int row = wbase + fi * 16 + fr;
                int idx = (row * 64 + ks2 * 32 + fo) ^ ((row & 7) << 3);
                pa[fi] = *(const s16x8*)&Ps[idx];
            }
            #pragma unroll
            for (int fj = 0; fj < 8; fj++)
                zb[fj] = *(const s16x8*)&Zs[ks2 * 4096 + (fj * 16 + fr) * 32 + fo];
            #pragma unroll
            for (int fi = 0; fi < NFI; fi++)
                #pragma unroll
                for (int fj = 0; fj < 8; fj++)
                    oa[fi][fj] = __builtin_amdgcn_mfma_f32_16x16x32_bf16(pa[fi], zb[fj], oa[fi][fj], 0, 0, 0);
        }
        __builtin_amdgcn_s_setprio(0);
        __syncthreads();
    }

    // epilogue
    #pragma unroll
    for (int fi = 0; fi < NFI; fi++)
        #pragma unroll
        for (int j = 0; j < 4; j++) {
            int row = wbase + fi * 16 + jr + j;
            if constexpr (MODE == 0) {
                float inv = 1.f / lrun[fi][j];
                #pragma unroll
                for (int fj = 0; fj < 8; fj++)
                    Op[(long long)(q0 + row) * DIM + h * 128 + fj * 16 + fr] = oa[fi][fj][j] * inv;
            } else {
                long long rb = (((long long)h * 512 + q0 + row) * NSPLIT + blockIdx.y) * 128;
                #pragma unroll
                for (int fj = 0; fj < 8; fj++)
                    Op[rb + fj * 16 + fr] = oa[fi][fj][j];
                if (fr == 0) {
                    long long si = ((long long)h * 512 + q0 + row) * NSPLIT + blockIdx.y;
                    Pm[si] = mold[fi][j];
                    Pl[si] = lrun[fi][j];
                }
            }
        }
}

// combine kv-split partials -> bvT bf16 [h][d][l]
__global__ __launch_bounds__(256)
void bv_combine(const float* __restrict__ PBV, const float* __restrict__ Pm,
                const float* __restrict__ Pl, ushort* __restrict__ BVTb)
{
    __shared__ float T[32][129];
    __shared__ float wc8[32][NSPLIT], invL[32];
    int t = threadIdx.x;
    int h = blockIdx.y, l0 = blockIdx.x * 32;
    if (t < 32) {
        long long base = ((long long)h * 512 + l0 + t) * NSPLIT;
        float m = -1e30f;
        float mv[NSPLIT], lv[NSPLIT];
        #pragma unroll
        for (int c = 0; c < NSPLIT; c++) { mv[c] = Pm[base + c]; lv[c] = Pl[base + c]; m = fmaxf(m, mv[c]); }
        float L = 0.f;
        #pragma unroll
        for (int c = 0; c < NSPLIT; c++) { float wv = __expf(mv[c] - m); wc8[t][c] = wv; L += wv * lv[c]; }
        invL[t] = 1.f / L;
    }
    __syncthreads();
    int l = t >> 3, dg = t & 7;
    long long rbase = ((long long)h * 512 + l0 + l) * NSPLIT * 128;
    #pragma unroll
    for (int dd = 0; dd < 16; dd++) {
        int d = dg * 16 + dd;
        float s = 0.f;
        #pragma unroll
        for (int c = 0; c < NSPLIT; c++) s += wc8[l][c] * PBV[rbase + c * 128 + d];
        T[l][d] = s * invL[l];
    }
    __syncthreads();
    int d = t >> 1, half = t & 1;
    #pragma unroll
    for (int lc = 0; lc < 16; lc++) {
        int l2 = half * 16 + lc;
        BVTb[(long long)h * 65536 + (long long)d * 512 + l0 + l2] = f2b(T[l2][d]);
    }
}

// ---------------- f32 -> bf16 convert ----------------
__global__ __launch_bounds__(256)
void cvt_bf16(const float* __restrict__ x, ushort* __restrict__ y, long long n)
{
    long long i = ((long long)blockIdx.x * 256 + threadIdx.x) * 8;
    if (i >= n) return;
    float4 a = *(const float4*)(x + i), b = *(const float4*)(x + i + 4);
    ushort4 u0 = {f2b(a.x), f2b(a.y), f2b(a.z), f2b(a.w)};
    ushort4 u1 = {f2b(b.x), f2b(b.y), f2b(b.z), f2b(b.w)};
    *(ushort4*)(y + i) = u0; *(ushort4*)(y + i + 4) = u1;
}

// ---------------- softmax fp32 rows (W = NIT*256) ----------------
template<int NIT>
__global__ __launch_bounds__(256)
void softmax_rows(float* __restrict__ X, int W)
{
    long long row = blockIdx.x;
    float* x = X + row * W;
    float r[NIT];
    float m = -1e30f;
    #pragma unroll
    for (int i = 0; i < NIT; i++) { r[i] = x[threadIdx.x + i * 256]; m = fmaxf(m, r[i]); }
    m = blk_max(m);
    float s = 0.f;
    #pragma unroll
    for (int i = 0; i < NIT; i++) { r[i] = __expf(r[i] - m); s += r[i]; }
    s = blk_sum(s);
    float inv = 1.f / s;
    #pragma unroll
    for (int i = 0; i < NIT; i++) x[threadIdx.x + i * 256] = r[i] * inv;
}

// ---------------- LN + front-pad -> bf16 ----------------
__global__ __launch_bounds__(256)
void ln_pad(const float* __restrict__ H, const float* __restrict__ g,
            const float* __restrict__ b, ushort* __restrict__ X)
{
    int row = blockIdx.x, t = threadIdx.x;
    ushort* o = X + (long long)row * DIM;
    if (row < PAD) {
        #pragma unroll
        for (int i = 0; i < 4; i++) o[t + i * 256] = 0;
        return;
    }
    const float* x = H + (long long)(row - PAD) * DIM;
    float r[4]; float s = 0.f;
    #pragma unroll
    for (int i = 0; i < 4; i++) { r[i] = x[t + i * 256]; s += r[i]; }
    float mu = blk_sum(s) * (1.f / DIM);
    float v = 0.f;
    #pragma unroll
    for (int i = 0; i < 4; i++) { float d = r[i] - mu; v += d * d; }
    float var = blk_sum(v) * (1.f / DIM);
    float rs = rsqrtf(var + 1e-5f);
    #pragma unroll
    for (int i = 0; i < 4; i++) { int c = t + i * 256; o[c] = f2b((r[i] - mu) * rs * g[c] + b[c]); }
}

// ---------------- landmarks ----------------
__global__ __launch_bounds__(128)
void landmarks(const ushort* __restrict__ QKVb, ushort* __restrict__ QL, ushort* __restrict__ KL)
{
    int L = blockIdx.x, h = blockIdx.y, d = threadIdx.x;
    float sq = 0.f, sk = 0.f;
    #pragma unroll
    for (int j = 0; j < LSUB; j++) {
        const ushort* p = QKVb + (long long)(L * LSUB + j) * 3072 + h * DHEAD + d;
        sq += b2f(p[0]);
        sk += b2f(p[1024]);
    }
    QL[(long long)(h * LMK + L) * DHEAD + d] = f2b(sq * (1.f / LSUB));
    KL[(long long)(h * LMK + L) * DHEAD + d] = f2b(sk * (1.f / LSUB));
}

// ---------------- V transpose -> bf16 VT[h][d][i] ----------------
__global__ void vtrans(const ushort* __restrict__ Q, ushort* __restrict__ VT)
{
    __shared__ ushort tile[32][33];
    int h = blockIdx.z, i0 = blockIdx.x * 32, d0 = blockIdx.y * 32;
    int tx = threadIdx.x, ty = threadIdx.y;
    for (int yy = ty; yy < 32; yy += 8)
        tile[yy][tx] = Q[(long long)(i0 + yy) * 3072 + 2048 + h * 128 + d0 + tx];
    __syncthreads();
    for (int yy = ty; yy < 32; yy += 8)
        VT[((long long)h * 128 + d0 + yy) * 6144 + i0 + tx] = tile[tx][yy];
}

// ---------------- a2 column sums ----------------
__global__ __launch_bounds__(256)
void a2_sums2(const float* __restrict__ A2, float* __restrict__ cols)
{
    int h = blockIdx.x, slice = blockIdx.y, t = threadIdx.x;
    const float* a = A2 + (long long)h * LMK * LMK + (long long)slice * 64 * LMK;
    float s0 = 0.f, s1 = 0.f;
    #pragma unroll 4
    for (int i = 0; i < 64; i++) {
        s0 += a[(long long)i * LMK + t];
        s1 += a[(long long)i * LMK + t + 256];
    }
    atomicAdd(&cols[h * LMK + t], s0);
    atomicAdd(&cols[h * LMK + t + 256], s1);
}
__global__ __launch_bounds__(256)
void a2_scal2(const float* __restrict__ cols, float* __restrict__ scal)
{
    float mc = -1e30f;
    for (int i = threadIdx.x; i < HEADS * LMK; i += 256) mc = fmaxf(mc, cols[i]);
    mc = blk_max(mc);
    if (threadIdx.x == 0) scal[0] = 1.f / mc;
}

// ---------------- z0/X prep ----------------
__global__ void z0_t(const float* __restrict__ A2, ushort* __restrict__ Xb,
                     ushort* __restrict__ Z0b, ushort* __restrict__ Z0T,
                     const float* __restrict__ scal)
{
    __shared__ float tile[32][33];
    int h = blockIdx.z;
    const float* a = A2 + (long long)h * LMK * LMK;
    float s = scal[0];
    int x0 = blockIdx.x * 32, y0 = blockIdx.y * 32;
    int tx = threadIdx.x, ty = threadIdx.y;
    long long hb = (long long)h * LMK * LMK;
    for (int yy = ty; yy < 32; yy += 8) {
        float v = a[(long long)(y0 + yy) * LMK + x0 + tx];
        tile[yy][tx] = v;
        Xb [hb + (long long)(y0 + yy) * LMK + x0 + tx] = f2b(v);
        Z0T[hb + (long long)(y0 + yy) * LMK + x0 + tx] = f2b(s * v);
    }
    __syncthreads();
    for (int yy = ty; yy < 32; yy += 8)
        Z0b[hb + (long long)(x0 + yy) * LMK + y0 + tx] = f2b(s * tile[tx][yy]);
}

// ---------------- MoE ----------------
__global__ __launch_bounds__(256)
void moe_combine(const float* __restrict__ X, const float* __restrict__ wg,
                 const ushort* __restrict__ EO, const float* __restrict__ eb,
                 float* __restrict__ H)
{
    int i = blockIdx.x, t = threadIdx.x;
    const float* x = X + (long long)i * INDIM;
    float g0 = 0.f, g1 = 0.f, g2 = 0.f;
    for (int f = t; f < INDIM; f += 256) {
        float xv = x[f];
        const float* w = wg + f * 3;
        g0 += xv * w[0]; g1 += xv * w[1]; g2 += xv * w[2];
    }
    g0 = blk_sum(g0); g1 = blk_sum(g1); g2 = blk_sum(g2);
    float m = fmaxf(g0, fmaxf(g1, g2));
    float e0 = __expf(g0 - m), e1 = __expf(g1 - m), e2 = __expf(g2 - m);
    float inv = 1.f / (e0 + e1 + e2);
    e0 *= inv; e1 *= inv; e2 *= inv;
    const ushort* eo = EO + (long long)i * 3072;
    for (int o = t; o < DIM; o += 256) {
        float v0 = fmaxf(b2f(eo[o])        + eb[o],        0.f);
        float v1 = fmaxf(b2f(eo[1024 + o]) + eb[1024 + o], 0.f);
        float v2 = fmaxf(b2f(eo[2048 + o]) + eb[2048 + o], 0.f);
        float r = e0 * v0 + e1 * v1 + e2 * v2;
        H[(long long)(1 + i) * DIM + o] = r;
        if (i < 84) H[(long long)(6001 + i) * DIM + o] = r;
    }
}

__global__ void cls_copy(const float* __restrict__ c, float* __restrict__ H)
{
    for (int i = threadIdx.x; i < DIM; i += 256) H[i] = c[i];
}

// ---------------- res conv: Ob = bf16(O + depthwise33(V)) (coalesced) ----------------
__global__ __launch_bounds__(256)
void resconv(const ushort* __restrict__ QKVb, const float* __restrict__ rw,
             const float* __restrict__ O, ushort* __restrict__ Ob)
{
    long long idx = (long long)blockIdx.x * 256 + threadIdx.x;
    int c = (int)(idx & 1023);
    long long i = idx >> 10;
    int h = c >> 7;
    float acc = O[idx];
    #pragma unroll
    for (int t = 0; t < 33; t++) {
        long long r = i + t - 16;
        if (r >= 0 && r < NPL) acc += rw[h * 33 + t] * b2f(QKVb[r * 3072 + 2048 + c]);
    }
    Ob[idx] = f2b(acc);
}

// ---------------- PPEG ----------------
__global__ void h2f(const float* __restrict__ H, float* __restrict__ F)
{
    __shared__ float tile[32][33];
    int p0 = blockIdx.x * 32, c0 = blockIdx.y * 32;
    int tx = threadIdx.x, ty = threadIdx.y;
    for (int yy = ty; yy < 32; yy += 8) {
        int p = p0 + yy;
        if (p < HW * HW) tile[yy][tx] = H[(long long)(1 + p) * DIM + c0 + tx];
    }
    __syncthreads();
    for (int yy = ty; yy < 32; yy += 8) {
        int p = p0 + tx, c = c0 + yy;
        if (p < HW * HW) F[(long long)c * (HW * HW) + p] = tile[tx][yy];
    }
}
__global__ void f2h(const float* __restrict__ F2, float* __restrict__ H)
{
    __shared__ float tile[32][33];
    int c0 = blockIdx.x * 32, p0 = blockIdx.y * 32;
    int tx = threadIdx.x, ty = threadIdx.y;
    for (int yy = ty; yy < 32; yy += 8) {
        int p = p0 + tx;
        if (p < HW * HW) tile[yy][tx] = F2[(long long)(c0 + yy) * (HW * HW) + p];
    }
    __syncthreads();
    for (int yy = ty; yy < 32; yy += 8) {
        int p = p0 + yy;
        if (p < HW * HW) H[(long long)(1 + p) * DIM + c0 + tx] = tile[tx][yy];
    }
}
__global__ __launch_bounds__(256)
void ppeg_conv2(const float* __restrict__ F,
                const float* __restrict__ w7, const float* __restrict__ b7,
                const float* __restrict__ w5, const float* __restrict__ b5,
                const float* __restrict__ w3, const float* __restrict__ b3,
                float* __restrict__ F2)
{
    int c = blockIdx.x, t = threadIdx.x;
    __shared__ float plane[HW * HW];
    __shared__ float wm[49];
    for (int p = t; p < HW * HW; p += 256) plane[p] = F[(long long)c * (HW * HW) + p];
    if (t < 49) {
        int ky = t / 7 - 3, kx = t % 7 - 3;
        float w = w7[(long long)c * 49 + t];
        if (ky >= -2 && ky <= 2 && kx >= -2 && kx <= 2) w += w5[(long long)c * 25 + (ky + 2) * 5 + (kx + 2)];
        if (ky >= -1 && ky <= 1 && kx >= -1 && kx <= 1) w += w3[(long long)c * 9 + (ky + 1) * 3 + (kx + 1)];
        if (t == 24) w += 1.0f;
        wm[t] = w;
    }
    __syncthreads();
    float bsum = b7[c] + b5[c] + b3[c];
    for (int p = t; p < HW * HW; p += 256) {
        int y = p / HW, x = p - y * HW;
        float acc = bsum;
        if (y >= 3 && y < HW - 3 && x >= 3 && x < HW - 3) {
            const float* base = &plane[p];
            #pragma unroll
            for (int ky = -3; ky <= 3; ky++)
                #pragma unroll
                for (int kx = -3; kx <= 3; kx++)
                    acc += wm[(ky + 3) * 7 + kx + 3] * base[ky * HW + kx];
        } else {
            for (int ky = -3; ky <= 3; ky++) {
                int yy = y + ky; if ((unsigned)yy >= (unsigned)HW) continue;
                for (int kx = -3; kx <= 3; kx++) {
                    int xx = x + kx; if ((unsigned)xx >= (unsigned)HW) continue;
                    acc += wm[(ky + 3) * 7 + kx + 3] * plane[yy * HW + xx];
                }
            }
        }
        F2[(long long)c * (HW * HW) + p] = acc;
    }
}

// ---------------- final head ----------------
__global__ __launch_bounds__(256)
void head_k(const float* __restrict__ H, const float* __restrict__ g, const float* __restrict__ b,
            const float* __restrict__ fw, const float* __restrict__ fb, float* __restrict__ out)
{
    int t = threadIdx.x;
    float r[4]; float s = 0.f;
    #pragma unroll
    for (int i = 0; i < 4; i++) { r[i] = H[t + i * 256]; s += r[i]; }
    float mu = blk_sum(s) * (1.f / DIM);
    float v = 0.f;
    #pragma unroll
    for (int i = 0; i < 4; i++) { float d = r[i] - mu; v += d * d; }
    float var = blk_sum(v) * (1.f / DIM);
    float rs = rsqrtf(var + 1e-5f);
    float d0 = 0.f, d1 = 0.f;
    #pragma unroll
    for (int i = 0; i < 4; i++) {
        int c = t + i * 256;
        float hv = (r[i] - mu) * rs * g[c] + b[c];
        d0 += hv * fw[c];
        d1 += hv * fw[DIM + c];
    }
    d0 = blk_sum(d0); d1 = blk_sum(d1);
    if (t == 0) {
        float l0 = d0 + fb[0], l1 = d1 + fb[1];
        float m = fmaxf(l0, l1);
        float e0 = __expf(l0 - m), e1 = __expf(l1 - m);
        float inv = 1.f / (e0 + e1);
        out[0] = l0; out[1] = l1;
        out[2] = e0 * inv; out[3] = e1 * inv;
        out[4] = (l1 > l0) ? 1.0f : 0.0f;
    }
}

// ---------------- host ----------------
extern "C" void kernel_launch(void* const* d_in, const int* in_sizes, int n_in,
                              void* d_out, int out_size, void* d_ws, size_t ws_size,
                              hipStream_t stream)
{
    const float* data     = (const float*)d_in[0];
    const float* w_gate   = (const float*)d_in[1];
    const float* expert_w = (const float*)d_in[2];
    const float* expert_b = (const float*)d_in[3];
    const float* cls_tok  = (const float*)d_in[4];
    const float* ln_g[2]  = {(const float*)d_in[5],  (const float*)d_in[11]};
    const float* ln_b[2]  = {(const float*)d_in[6],  (const float*)d_in[12]};
    const float* qkv_w[2] = {(const float*)d_in[7],  (const float*)d_in[13]};
    const float* out_w[2] = {(const float*)d_in[8],  (const float*)d_in[14]};
    const float* out_b[2] = {(const float*)d_in[9],  (const float*)d_in[15]};
    const float* res_w[2] = {(const float*)d_in[10], (const float*)d_in[16]};
    const float* pw7 = (const float*)d_in[17]; const float* pb7 = (const float*)d_in[18];
    const float* pw5 = (const float*)d_in[19]; const float* pb5 = (const float*)d_in[20];
    const float* pw3 = (const float*)d_in[21]; const float* pb3 = (const float*)d_in[22];
    const float* nf_g = (const float*)d_in[23]; const float* nf_b = (const float*)d_in[24];
    const float* fc2w = (const float*)d_in[25]; const float* fc2b = (const float*)d_in[26];

    float*  ws    = (float*)d_ws;
    float*  H     = ws + OFF_H;
    ushort* LNXb  = (ushort*)(ws + OFF_LNXO);
    float*  O     = ws + OFF_LNXO;             // alias: O written after LNXb dead
    ushort* QKVb  = (ushort*)(ws + OFF_QKVB);
    ushort* EOb   = (ushort*)(ws + OFF_QKVB);
    float*  PBV   = ws + OFF_PBV;
    float*  PM    = ws + OFF_PM;
    float*  PL    = ws + OFF_PL;
    ushort* Ob    = (ushort*)(ws + OFF_OB);
    ushort* VT    = (ushort*)(ws + OFF_VT);
    ushort* QL    = (ushort*)(ws + OFF_QL);
    ushort* KL    = (ushort*)(ws + OFF_KL);
    float*  A2F   = ws + OFF_A2F;
    ushort* BVTb  = (ushort*)(ws + OFF_BVTB);
    ushort* Xb    = (ushort*)(ws + OFF_XB);
    ushort* XZB   = (ushort*)(ws + OFF_XZB);
    ushort* XZT7  = (ushort*)(ws + OFF_XZT7);
    ushort* PT15  = (ushort*)(ws + OFF_PT15);
    ushort* QT13  = (ushort*)(ws + OFF_QT13);
    ushort* ZB[2] = {(ushort*)(ws + OFF_ZB0), (ushort*)(ws + OFF_ZB1)};
    ushort* ZT[2] = {(ushort*)(ws + OFF_ZT0), (ushort*)(ws + OFF_ZT1)};
    ushort* ZBT   = (ushort*)(ws + OFF_ZBT);
    ushort* QWB   = (ushort*)(ws + OFF_QWB);
    ushort* OWB   = (ushort*)(ws + OFF_OWB);
    ushort* DATAB = (ushort*)(ws + OFF_DATAB);
    ushort* EWB   = (ushort*)(ws + OFF_EWB);
    float*  COLS  = ws + OFF_COLS;
    float*  SCAL  = ws + OFF_SCAL;

    const long long HSB = (long long)LMK * DHEAD;   // 65536
    const long long A2S = (long long)LMK * LMK;     // 262144

    // ---- MoE ----
    cvt_bf16<<<4500, 256, 0, stream>>>(data, DATAB, (long long)NTOK * INDIM);
    cvt_bf16<<<2304, 256, 0, stream>>>(expert_w, EWB, 3072LL * INDIM);
    mg<2><<<dim3(24,47,1),256,0,stream>>>(DATAB,INDIM,0, EWB,INDIM,0, EOb,3072,0,
        nullptr,0,0, NTOK,INDIM, nullptr, 1.f,0.f,0.f);
    moe_combine<<<NTOK,256,0,stream>>>(data, w_gate, EOb, expert_b, H);
    cls_copy<<<1,256,0,stream>>>(cls_tok, H);

    for (int stage = 0; stage < 2; stage++) {
        cvt_bf16<<<1536, 256, 0, stream>>>(qkv_w[stage], QWB, 3072LL * DIM);
        cvt_bf16<<<512, 256, 0, stream>>>(out_w[stage], OWB, (long long)DIM * DIM);
        ln_pad<<<NPL,256,0,stream>>>(H, ln_g[stage], ln_b[stage], LNXb);
        mg<1><<<dim3(24,48,1),256,0,stream>>>(LNXb,DIM,0, QWB,DIM,0, QKVb,3072,0,
            nullptr,0,0, NPL,DIM, nullptr, 1.f,0.f,0.f);
        landmarks<<<dim3(LMK,HEADS),128,0,stream>>>(QKVb, QL, KL);
        vtrans<<<dim3(192,4,8),dim3(32,8),0,stream>>>(QKVb, VT);
        // a2 = softmax(ql @ kl^T) f32  (64x128 tiles -> 256 blocks)
        mg64<0><<<dim3(4,8,8),256,0,stream>>>(QL,DHEAD,HSB, KL,DHEAD,HSB, A2F,LMK,A2S,
            nullptr,0,0, DHEAD, 1.f,0.f,0.f);
        softmax_rows<2><<<HEADS*LMK,256,0,stream>>>(A2F, LMK);
        hipMemsetAsync(COLS, 0, HEADS * LMK * sizeof(float), stream);
        a2_sums2<<<dim3(HEADS,8),256,0,stream>>>(A2F, COLS);
        a2_scal2<<<1,256,0,stream>>>(COLS, SCAL);
        z0_t<<<dim3(16,16,8),dim3(32,8),0,stream>>>(A2F, Xb, ZB[0], ZT[0], SCAL);
        // Newton-Schulz: 6 iterations, 64x128-tile GEMMs (256 blocks = all CUs)
        int cur = 0;
        for (int it = 0; it < 6; it++) {
            mg64<4><<<dim3(4,8,8),256,0,stream>>>(Xb,LMK,A2S, ZT[cur],LMK,A2S, XZB,LMK,A2S,
                XZT7,LMK,A2S, LMK, 1.f, 7.f, -1.f);
            mg64<5><<<dim3(4,8,8),256,0,stream>>>(XZB,LMK,A2S, XZT7,LMK,A2S, nullptr,0,0,
                PT15,LMK,A2S, LMK, 1.f, 15.f, -1.f);
            mg64<5><<<dim3(4,8,8),256,0,stream>>>(XZB,LMK,A2S, PT15,LMK,A2S, nullptr,0,0,
                QT13,LMK,A2S, LMK, 1.f, 13.f, -1.f);
            if (it < 5)
                mg64<4><<<dim3(4,8,8),256,0,stream>>>(ZB[cur],LMK,A2S, QT13,LMK,A2S, ZB[1-cur],LMK,A2S,
                    ZT[1-cur],LMK,A2S, LMK, 0.25f, 0.f, 1.f);
            else
                mg64<2><<<dim3(4,8,8),256,0,stream>>>(ZB[cur],LMK,A2S, QT13,LMK,A2S, ZB[1-cur],LMK,A2S,
                    nullptr,0,0, LMK, 0.25f, 0.f, 1.f);
            cur = 1 - cur;
        }
        ushort* Z6 = ZB[cur];
        // flash a3: partial bv over 16 kv-chunks of 384
        flash<1,2><<<dim3(4,NSPLIT,8),256,0,stream>>>(QL,DHEAD,HSB, QKVb+1024,3072,128,
            VT,NPL,(long long)DHEAD*NPL, PBV, PM, PL, 6, 384);
        bv_combine<<<dim3(16,8),256,0,stream>>>(PBV, PM, PL, BVTb);
        // ZBT[d][l'] = sum_l bvT[d][l] z6[l'][l]  (64 blocks)
        mg64<2><<<dim3(4,2,8),256,0,stream>>>(BVTb,LMK,HSB, Z6,LMK,A2S, ZBT,LMK,HSB,
            nullptr,0,0, LMK, 1.f,0.f,0.f);
        // flash a1: O = softmax(q @ kl^T) @ zb  (64-row q tiles, 768 blocks)
        flash<0,1><<<dim3(96,1,8),256,0,stream>>>(QKVb,3072,128, KL,DHEAD,HSB,
            ZBT,LMK,HSB, O, nullptr, nullptr, 8, 0);
        // Ob = bf16(O + res conv of v)
        resconv<<<(NPL*DIM)/256,256,0,stream>>>(QKVb, res_w[stage], O, Ob);
        // H += Ob @ out_w^T + out_b
        mg<3><<<dim3(8,48,1),256,0,stream>>>(Ob + (long long)PAD*DIM,DIM,0, OWB,DIM,0, H,DIM,0,
            nullptr,0,0, NH,DIM, out_b[stage], 1.f,0.f,0.f);
        if (stage == 0) {
            float* F  = ws + OFF_QKVB;
            float* F2 = F + 6230016LL;
            h2f<<<dim3(191,32),dim3(32,8),0,stream>>>(H, F);
            ppeg_conv2<<<DIM,256,0,stream>>>(F, pw7, pb7, pw5, pb5, pw3, pb3, F2);
            f2h<<<dim3(32,191),dim3(32,8),0,stream>>>(F2, H);
        }
    }

    head_k<<<1,256,0,stream>>>(H, nf_g, nf_b, fc2w, fc2b, (float*)d_out);
}

// Round 12
// 1461.235 us; speedup vs baseline: 1.7889x; 1.0704x over previous
//
#include <hip/hip_runtime.h>
#include <hip/hip_bf16.h>

// ---------------- constants ----------------
#define NTOK   6000
#define INDIM  1536
#define DIM    1024
#define NPL    6144
#define PAD    59
#define NH     6085
#define HEADS  8
#define DHEAD  128
#define LMK    512
#define LSUB   12
#define HW     78
#define QSCALE 0.08838834764831845f
#define NSPLIT 16

// ---------------- ws layout (float-slot offsets) ----------------
#define OFF_H     0LL          // 6144*1024 f32
#define OFF_LNXO  6291456LL    // LNXb bf16 / O f32 alias
#define OFF_QKVB  12582912LL   // 6144*3072 bf16; EO bf16 + PPEG planes alias
#define OFF_PBV   22020096LL   // 8h*512*16c*128 f32 = 8388608
#define OFF_PM    30408704LL   // 65536
#define OFF_PL    30474240LL   // 65536
#define OFF_OB    30539776LL   // 6144*1024 bf16 = 3145728 slots (ends 33685504)
#define OFF_VT    34603008LL   // 8*128*6144 bf16
#define OFF_QL    37748736LL
#define OFF_KL    38010880LL
#define OFF_A2F   38273024LL   // 8*512*512 f32
#define OFF_BVTB  40370176LL   // 8*128*512 bf16
#define OFF_XB    42467328LL   // bf16 8*512*512 each below
#define OFF_XZB   43515904LL
#define OFF_XZT7  44564480LL
#define OFF_PT15  45613056LL
#define OFF_QT13  46661632LL
#define OFF_ZB0   47710208LL
#define OFF_ZT0   48758784LL
#define OFF_ZB1   49807360LL
#define OFF_ZT1   50855936LL
#define OFF_ZBT   52428800LL   // 8*128*512 bf16
#define OFF_QWB   52690944LL   // 3072*1024 bf16
#define OFF_OWB   54263808LL   // 1024*1024 bf16
#define OFF_COLS  54788096LL
#define OFF_SCAL  54796288LL
// transient aliases (dead before overlapping buffers are written)
#define OFF_DATAB 31457280LL   // 6000*1536 bf16 (pre-stage only; overlaps OB/VT span)
#define OFF_EWB   36065280LL   // 3072*1536 bf16 (pre-stage only)

typedef __attribute__((ext_vector_type(8))) short s16x8;
typedef __attribute__((ext_vector_type(4))) float f32x4;

// ---------------- bf16 helpers ----------------
__device__ __forceinline__ ushort f2b(float f) {
    union { float f; unsigned u; } v; v.f = f;
    return (ushort)((v.u + 0x7FFF + ((v.u >> 16) & 1)) >> 16);
}
__device__ __forceinline__ float b2f(ushort h) {
    union { unsigned u; float f; } v; v.u = ((unsigned)h) << 16; return v.f;
}

// async global->LDS, 16 bytes per lane; lds ptr must be wave-uniform
__device__ __forceinline__ void gld16(const void* g, void* l) {
    __builtin_amdgcn_global_load_lds((const __attribute__((address_space(1))) void*)g,
                                     (__attribute__((address_space(3))) void*)l, 16, 0, 0);
}

// ---------------- reductions (blockDim.x == 256) ----------------
__device__ __forceinline__ float blk_sum(float v) {
    __shared__ float sb[4];
    #pragma unroll
    for (int o = 32; o > 0; o >>= 1) v += __shfl_down(v, o);
    int lane = threadIdx.x & 63, w = threadIdx.x >> 6;
    __syncthreads();
    if (lane == 0) sb[w] = v;
    __syncthreads();
    return sb[0] + sb[1] + sb[2] + sb[3];
}
__device__ __forceinline__ float blk_max(float v) {
    __shared__ float sb[4];
    #pragma unroll
    for (int o = 32; o > 0; o >>= 1) v = fmaxf(v, __shfl_down(v, o));
    int lane = threadIdx.x & 63, w = threadIdx.x >> 6;
    __syncthreads();
    if (lane == 0) sb[w] = v;
    __syncthreads();
    return fmaxf(fmaxf(sb[0], sb[1]), fmaxf(sb[2], sb[3]));
}

// ================= MFMA GEMM (bf16 x bf16), C = alpha * A @ B^T, 128x128 tile =================
// BK=64 (2 MFMA sub-steps per barrier pair). Requires K % 64 == 0.
// EPI: 0 f32 | 1 bf16 qkv-scale | 2 bf16 | 3 f32 += v+bias
//      4 bf16 C + bf16 T[c][r]=tdelta*(r==c)+tsign*v | 5 T only
template<int EPI>
__global__ __launch_bounds__(256)
void mg(const ushort* __restrict__ A, int lda, long long sA,
        const ushort* __restrict__ B, int ldb, long long sB,
        void* __restrict__ Cp, int ldc, long long sC,
        void* __restrict__ Tp, int ldt, long long sT,
        int M, int K, const float* __restrict__ bias,
        float alpha, float tdelta, float tsign)
{
    __shared__ ushort As[8192];   // 2 subtiles [128][32]
    __shared__ ushort Bs[8192];
    const int t = threadIdx.x;
    const int z = blockIdx.z;
    const ushort* Ab = A + (long long)z * sA;
    const ushort* Bb = B + (long long)z * sB;
    const int row0 = blockIdx.y * 128, col0 = blockIdx.x * 128;
    const int w = t >> 6, lane = t & 63;
    const int l4 = lane >> 2, ls = (lane & 3) * 8;
    const int q0 = w, q1 = 4 + w;
    int ar0 = row0 + q0 * 16 + l4; if (ar0 >= M) ar0 = M - 1;
    int ar1 = row0 + q1 * 16 + l4; if (ar1 >= M) ar1 = M - 1;
    const int br0 = col0 + q0 * 16 + l4;
    const int br1 = col0 + q1 * 16 + l4;
    const ushort* ap0 = Ab + (long long)ar0 * lda + ls;
    const ushort* ap1 = Ab + (long long)ar1 * lda + ls;
    const ushort* bp0 = Bb + (long long)br0 * ldb + ls;
    const ushort* bp1 = Bb + (long long)br1 * ldb + ls;
    ushort* asl0 = &As[q0 * 512];
    ushort* asl1 = &As[q1 * 512];
    ushort* bsl0 = &Bs[q0 * 512];
    ushort* bsl1 = &Bs[q1 * 512];

    const int wr = (w >> 1) * 64, wc = (w & 1) * 64;
    const int fr = lane & 15, fo = (lane >> 4) * 8;

    f32x4 acc[4][4];
    #pragma unroll
    for (int a = 0; a < 4; a++)
        #pragma unroll
        for (int b = 0; b < 4; b++)
            acc[a][b] = (f32x4){0.f, 0.f, 0.f, 0.f};

    for (int kt = 0; kt < K; kt += 64) {
        gld16(ap0 + kt, asl0);
        gld16(ap1 + kt, asl1);
        gld16(bp0 + kt, bsl0);
        gld16(bp1 + kt, bsl1);
        gld16(ap0 + kt + 32, asl0 + 4096);
        gld16(ap1 + kt + 32, asl1 + 4096);
        gld16(bp0 + kt + 32, bsl0 + 4096);
        gld16(bp1 + kt + 32, bsl1 + 4096);
        __syncthreads();
        #pragma unroll
        for (int half = 0; half < 2; half++) {
            s16x8 af[4], bf[4];
            #pragma unroll
            for (int a = 0; a < 4; a++) af[a] = *(const s16x8*)&As[half * 4096 + (wr + a * 16 + fr) * 32 + fo];
            #pragma unroll
            for (int b = 0; b < 4; b++) bf[b] = *(const s16x8*)&Bs[half * 4096 + (wc + b * 16 + fr) * 32 + fo];
            #pragma unroll
            for (int a = 0; a < 4; a++)
                #pragma unroll
                for (int b = 0; b < 4; b++)
                    acc[a][b] = __builtin_amdgcn_mfma_f32_16x16x32_bf16(af[a], bf[b], acc[a][b], 0, 0, 0);
        }
        __syncthreads();
    }

    const int er0 = row0 + wr + ((lane >> 4) << 2);
    const int ec0 = col0 + wc + fr;
    #pragma unroll
    for (int a = 0; a < 4; a++) {
        #pragma unroll
        for (int j = 0; j < 4; j++) {
            int r = er0 + a * 16 + j;
            if (r >= M) continue;
            #pragma unroll
            for (int b = 0; b < 4; b++) {
                int c = ec0 + b * 16;
                float v = alpha * acc[a][b][j];
                long long ci = z * sC + (long long)r * ldc + c;
                if constexpr (EPI == 0) ((float*)Cp)[ci] = v;
                else if constexpr (EPI == 1) ((ushort*)Cp)[ci] = f2b(c < 1024 ? v * QSCALE : v);
                else if constexpr (EPI == 2) ((ushort*)Cp)[ci] = f2b(v);
                else if constexpr (EPI == 3) ((float*)Cp)[ci] += v + bias[c];
                else {
                    ushort tv = f2b((r == c ? tdelta : 0.f) + tsign * v);
                    long long ti = z * sT + (long long)c * ldt + r;
                    if constexpr (EPI == 4) { ((ushort*)Cp)[ci] = f2b(v); ((ushort*)Tp)[ti] = tv; }
                    else { ((ushort*)Tp)[ti] = tv; }  // 5
                }
            }
        }
    }
}

// ================= MFMA GEMM 64x128 tile — for small batched GEMMs =================
// C = alpha * A @ B^T. Requires M%64==0, N%128==0, K%64==0. Grid (N/128, M/64, Z). BK=64.
// EPI: 0 f32 | 2 bf16 | 4 bf16 C + bf16 T[c][r]=tdelta*(r==c)+tsign*v | 5 T only
template<int EPI>
__global__ __launch_bounds__(256)
void mg64(const ushort* __restrict__ A, int lda, long long sA,
          const ushort* __restrict__ B, int ldb, long long sB,
          void* __restrict__ Cp, int ldc, long long sC,
          void* __restrict__ Tp, int ldt, long long sT,
          int K, float alpha, float tdelta, float tsign)
{
    __shared__ ushort As[4096];   // 2 subtiles [64][32]
    __shared__ ushort Bs[8192];   // 2 subtiles [128][32]
    const int t = threadIdx.x;
    const int z = blockIdx.z;
    const ushort* Ab = A + (long long)z * sA;
    const ushort* Bb = B + (long long)z * sB;
    const int row0 = blockIdx.y * 64, col0 = blockIdx.x * 128;
    const int w = t >> 6, lane = t & 63;
    const int l4 = lane >> 2, ls = (lane & 3) * 8;
    const ushort* ap = Ab + (long long)(row0 + w * 16 + l4) * lda + ls;
    ushort* asl = &As[w * 16 * 32];
    const ushort* bp0 = Bb + (long long)(col0 + w * 16 + l4) * ldb + ls;
    const ushort* bp1 = Bb + (long long)(col0 + 64 + w * 16 + l4) * ldb + ls;
    ushort* bsl0 = &Bs[w * 16 * 32];
    ushort* bsl1 = &Bs[(64 + w * 16) * 32];

    const int fr = lane & 15, fo = (lane >> 4) * 8;

    f32x4 acc[4][2];
    #pragma unroll
    for (int a = 0; a < 4; a++)
        #pragma unroll
        for (int b = 0; b < 2; b++)
            acc[a][b] = (f32x4){0.f, 0.f, 0.f, 0.f};

    for (int kt = 0; kt < K; kt += 64) {
        gld16(ap + kt, asl);
        gld16(bp0 + kt, bsl0);
        gld16(bp1 + kt, bsl1);
        gld16(ap + kt + 32, asl + 2048);
        gld16(bp0 + kt + 32, bsl0 + 4096);
        gld16(bp1 + kt + 32, bsl1 + 4096);
        __syncthreads();
        #pragma unroll
        for (int half = 0; half < 2; half++) {
            s16x8 af[4], bf[2];
            #pragma unroll
            for (int a = 0; a < 4; a++) af[a] = *(const s16x8*)&As[half * 2048 + (a * 16 + fr) * 32 + fo];
            #pragma unroll
            for (int b = 0; b < 2; b++) bf[b] = *(const s16x8*)&Bs[half * 4096 + (w * 32 + b * 16 + fr) * 32 + fo];
            #pragma unroll
            for (int a = 0; a < 4; a++)
                #pragma unroll
                for (int b = 0; b < 2; b++)
                    acc[a][b] = __builtin_amdgcn_mfma_f32_16x16x32_bf16(af[a], bf[b], acc[a][b], 0, 0, 0);
        }
        __syncthreads();
    }

    const int er0 = row0 + ((lane >> 4) << 2);
    const int ec0 = col0 + w * 32 + fr;
    #pragma unroll
    for (int a = 0; a < 4; a++) {
        #pragma unroll
        for (int j = 0; j < 4; j++) {
            int r = er0 + a * 16 + j;
            #pragma unroll
            for (int b = 0; b < 2; b++) {
                int c = ec0 + b * 16;
                float v = alpha * acc[a][b][j];
                long long ci = z * sC + (long long)r * ldc + c;
                if constexpr (EPI == 0) ((float*)Cp)[ci] = v;
                else if constexpr (EPI == 2) ((ushort*)Cp)[ci] = f2b(v);
                else {
                    ushort tv = f2b((r == c ? tdelta : 0.f) + tsign * v);
                    long long ti = z * sT + (long long)c * ldt + r;
                    if constexpr (EPI == 4) { ((ushort*)Cp)[ci] = f2b(v); ((ushort*)Tp)[ti] = tv; }
                    else { ((ushort*)Tp)[ti] = tv; }  // 5
                }
            }
        }
    }
}

// ================= fused flash attention =================
// Q in registers; q tile = NFI*64 rows (wave owns NFI*16 rows); KV chunks of 64.
// Online softmax with defer-max (RESCALE_THRESHOLD=8) and setprio around MFMA clusters.
// MODE 0: final f32 output to Op (cols h*128..); MODE 1: partial (acc,m,l) per kv-split.
template<int MODE, int NFI>
__global__ __launch_bounds__(256)
void flash(const ushort* __restrict__ Qp, int ldq, long long sQh,
           const ushort* __restrict__ Kp, int ldk, long long sKh,
           const ushort* __restrict__ Vp, int ldv, long long sVh,
           float* __restrict__ Op, float* __restrict__ Pm, float* __restrict__ Pl,
           int nkv, int kvspan)
{
    __shared__ ushort Zs[8192];    // 2 subtiles [128][32] (Vt chunk)
    __shared__ ushort KPs[8192];   // 4 subtiles [64][32] (K chunk); aliased by P [NFI*64][64] swizzled
    ushort* Ps = KPs;
    const int t = threadIdx.x;
    const int h = blockIdx.z;
    const int q0 = blockIdx.x * (NFI * 64);
    const int kvbase = blockIdx.y * kvspan;
    const ushort* Qb = Qp + (long long)h * sQh;
    const ushort* Kb = Kp + (long long)h * sKh;
    const ushort* Vb = Vp + (long long)h * sVh;
    const int w = t >> 6, lane = t & 63;
    const int sr = lane >> 2, sc2 = (lane & 3) * 8;
    const int fr = lane & 15, fo = (lane >> 4) * 8;
    const int jr = (lane >> 4) * 4;
    const int wbase = w * (NFI * 16);

    // Q fragments directly to registers (reused across all kv chunks)
    s16x8 qr[NFI][4];
    #pragma unroll
    for (int fi = 0; fi < NFI; fi++)
        #pragma unroll
        for (int ks = 0; ks < 4; ks++)
            qr[fi][ks] = *(const s16x8*)&Qb[(long long)(q0 + wbase + fi * 16 + fr) * ldq + ks * 32 + fo];

    f32x4 oa[NFI][8];
    float mold[NFI][4], lrun[NFI][4];
    #pragma unroll
    for (int fi = 0; fi < NFI; fi++) {
        #pragma unroll
        for (int fj = 0; fj < 8; fj++) oa[fi][fj] = (f32x4){0.f,0.f,0.f,0.f};
        #pragma unroll
        for (int j = 0; j < 4; j++) { mold[fi][j] = -1e30f; lrun[fi][j] = 0.f; }
    }

    for (int c = 0; c < nkv; c++) {
        int kvp = kvbase + c * 64;
        #pragma unroll
        for (int s = 0; s < 4; s++)
            gld16(Kb + (long long)(kvp + w * 16 + sr) * ldk + s * 32 + sc2,
                  &KPs[s * 2048 + (w * 16) * 32]);
        #pragma unroll
        for (int s = 0; s < 2; s++)
            #pragma unroll
            for (int r0 = 0; r0 < 128; r0 += 64)
                gld16(Vb + (long long)(r0 + w * 16 + sr) * ldv + kvp + s * 32 + sc2,
                      &Zs[s * 4096 + (r0 + w * 16) * 32]);
        __syncthreads();

        f32x4 acc[NFI][4];
        #pragma unroll
        for (int fi = 0; fi < NFI; fi++)
            #pragma unroll
            for (int fj = 0; fj < 4; fj++) acc[fi][fj] = (f32x4){0.f,0.f,0.f,0.f};
        __builtin_amdgcn_s_setprio(1);
        #pragma unroll
        for (int ks = 0; ks < 4; ks++) {
            s16x8 kb[4];
            #pragma unroll
            for (int fj = 0; fj < 4; fj++)
                kb[fj] = *(const s16x8*)&KPs[ks * 2048 + (fj * 16 + fr) * 32 + fo];
            #pragma unroll
            for (int fi = 0; fi < NFI; fi++)
                #pragma unroll
                for (int fj = 0; fj < 4; fj++)
                    acc[fi][fj] = __builtin_amdgcn_mfma_f32_16x16x32_bf16(qr[fi][ks], kb[fj], acc[fi][fj], 0, 0, 0);
        }
        __builtin_amdgcn_s_setprio(0);

        // online softmax with defer-max (threshold 8)
        float mx[NFI][4];
        bool need = false;
        #pragma unroll
        for (int fi = 0; fi < NFI; fi++) {
            #pragma unroll
            for (int j = 0; j < 4; j++) {
                float m0 = acc[fi][0][j];
                #pragma unroll
                for (int fj = 1; fj < 4; fj++) m0 = fmaxf(m0, acc[fi][fj][j]);
                m0 = fmaxf(m0, __shfl_xor(m0, 1));
                m0 = fmaxf(m0, __shfl_xor(m0, 2));
                m0 = fmaxf(m0, __shfl_xor(m0, 4));
                m0 = fmaxf(m0, __shfl_xor(m0, 8));
                mx[fi][j] = m0;
                need = need || (m0 - mold[fi][j] > 8.f);
            }
        }
        if (__any(need)) {
            #pragma unroll
            for (int fi = 0; fi < NFI; fi++)
                #pragma unroll
                for (int j = 0; j < 4; j++) {
                    float mn = fmaxf(mold[fi][j], mx[fi][j]);
                    float scl = __expf(mold[fi][j] - mn);
                    mold[fi][j] = mn;
                    lrun[fi][j] *= scl;
                    #pragma unroll
                    for (int fj = 0; fj < 8; fj++) oa[fi][fj][j] *= scl;
                }
        }
        float rs[NFI][4];
        #pragma unroll
        for (int fi = 0; fi < NFI; fi++) {
            #pragma unroll
            for (int j = 0; j < 4; j++) {
                float r = 0.f;
                #pragma unroll
                for (int fj = 0; fj < 4; fj++) {
                    float p = __expf(acc[fi][fj][j] - mold[fi][j]);
                    acc[fi][fj][j] = p;
                    r += p;
                }
                r += __shfl_xor(r, 1);
                r += __shfl_xor(r, 2);
                r += __shfl_xor(r, 4);
                r += __shfl_xor(r, 8);
                rs[fi][j] = r;
            }
        }
        __syncthreads();   // all waves done reading KPs
        #pragma unroll
        for (int fi = 0; fi < NFI; fi++)
            #pragma unroll
            for (int j = 0; j < 4; j++) {
                int row = wbase + fi * 16 + jr + j;
                lrun[fi][j] += rs[fi][j];
                #pragma unroll
                for (int fj = 0; fj < 4; fj++) {
                    int idx = (row * 64 + fj * 16 + fr) ^ ((row & 7) << 3);
                    Ps[idx] = f2b(acc[fi][fj][j]);
                }
            }
        __syncthreads();   // P visible

        __builtin_amdgcn_s_setprio(1);
        #pragma unroll
        for (int ks2 = 0; ks2 < 2; ks2++) {
            s16x8 pa[NFI], zb[8];
            #pragma unroll
            for (int fi = 0; fi < NFI; fi++) {
                int row = wbase + fi * 16 + fr;
                int idx = (row * 64 + ks2 * 32 + fo) ^ ((row & 7) << 3);
                pa[fi] = *(const s16x8*)&Ps[idx];
            }
            #pragma unroll
            for (int fj = 0; fj < 8; fj++)
                zb[fj] = *(const s16x8*)&Zs[ks2 * 4096 + (fj * 16 + fr) * 32 + fo];
            #pragma unroll
            for (int fi = 0; fi < NFI; fi++)
                #pragma unroll
                for (int fj = 0; fj < 8; fj++)
                    oa[fi][fj] = __builtin_amdgcn_mfma_f32_16x16x32_bf16(pa[fi], zb[fj], oa[fi][fj], 0, 0, 0);
        }
        __builtin_amdgcn_s_setprio(0);
        __syncthreads();
    }

    // epilogue
    #pragma unroll
    for (int fi = 0; fi < NFI; fi++)
        #pragma unroll
        for (int j = 0; j < 4; j++) {
            int row = wbase + fi * 16 + jr + j;
            if constexpr (MODE == 0) {
                float inv = 1.f / lrun[fi][j];
                #pragma unroll
                for (int fj = 0; fj < 8; fj++)
                    Op[(long long)(q0 + row) * DIM + h * 128 + fj * 16 + fr] = oa[fi][fj][j] * inv;
            } else {
                long long rb = (((long long)h * 512 + q0 + row) * NSPLIT + blockIdx.y) * 128;
                #pragma unroll
                for (int fj = 0; fj < 8; fj++)
                    Op[rb + fj * 16 + fr] = oa[fi][fj][j];
                if (fr == 0) {
                    long long si = ((long long)h * 512 + q0 + row) * NSPLIT + blockIdx.y;
                    Pm[si] = mold[fi][j];
                    Pl[si] = lrun[fi][j];
                }
            }
        }
}

// combine kv-split partials -> bvT bf16 [h][d][l]
__global__ __launch_bounds__(256)
void bv_combine(const float* __restrict__ PBV, const float* __restrict__ Pm,
                const float* __restrict__ Pl, ushort* __restrict__ BVTb)
{
    __shared__ float T[32][129];
    __shared__ float wc8[32][NSPLIT], invL[32];
    int t = threadIdx.x;
    int h = blockIdx.y, l0 = blockIdx.x * 32;
    if (t < 32) {
        long long base = ((long long)h * 512 + l0 + t) * NSPLIT;
        float m = -1e30f;
        float mv[NSPLIT], lv[NSPLIT];
        #pragma unroll
        for (int c = 0; c < NSPLIT; c++) { mv[c] = Pm[base + c]; lv[c] = Pl[base + c]; m = fmaxf(m, mv[c]); }
        float L = 0.f;
        #pragma unroll
        for (int c = 0; c < NSPLIT; c++) { float wv = __expf(mv[c] - m); wc8[t][c] = wv; L += wv * lv[c]; }
        invL[t] = 1.f / L;
    }
    __syncthreads();
    int l = t >> 3, dg = t & 7;
    long long rbase = ((long long)h * 512 + l0 + l) * NSPLIT * 128;
    #pragma unroll
    for (int dd = 0; dd < 16; dd++) {
        int d = dg * 16 + dd;
        float s = 0.f;
        #pragma unroll
        for (int c = 0; c < NSPLIT; c++) s += wc8[l][c] * PBV[rbase + c * 128 + d];
        T[l][d] = s * invL[l];
    }
    __syncthreads();
    int d = t >> 1, half = t & 1;
    #pragma unroll
    for (int lc = 0; lc < 16; lc++) {
        int l2 = half * 16 + lc;
        BVTb[(long long)h * 65536 + (long long)d * 512 + l0 + l2] = f2b(T[l2][d]);
    }
}

// ---------------- f32 -> bf16 convert ----------------
__global__ __launch_bounds__(256)
void cvt_bf16(const float* __restrict__ x, ushort* __restrict__ y, long long n)
{
    long long i = ((long long)blockIdx.x * 256 + threadIdx.x) * 8;
    if (i >= n) return;
    float4 a = *(const float4*)(x + i), b = *(const float4*)(x + i + 4);
    ushort4 u0 = {f2b(a.x), f2b(a.y), f2b(a.z), f2b(a.w)};
    ushort4 u1 = {f2b(b.x), f2b(b.y), f2b(b.z), f2b(b.w)};
    *(ushort4*)(y + i) = u0; *(ushort4*)(y + i + 4) = u1;
}

// ---------------- softmax fp32 rows (W = NIT*256) ----------------
template<int NIT>
__global__ __launch_bounds__(256)
void softmax_rows(float* __restrict__ X, int W)
{
    long long row = blockIdx.x;
    float* x = X + row * W;
    float r[NIT];
    float m = -1e30f;
    #pragma unroll
    for (int i = 0; i < NIT; i++) { r[i] = x[threadIdx.x + i * 256]; m = fmaxf(m, r[i]); }
    m = blk_max(m);
    float s = 0.f;
    #pragma unroll
    for (int i = 0; i < NIT; i++) { r[i] = __expf(r[i] - m); s += r[i]; }
    s = blk_sum(s);
    float inv = 1.f / s;
    #pragma unroll
    for (int i = 0; i < NIT; i++) x[threadIdx.x + i * 256] = r[i] * inv;
}

// ---------------- LN + front-pad -> bf16 ----------------
__global__ __launch_bounds__(256)
void ln_pad(const float* __restrict__ H, const float* __restrict__ g,
            const float* __restrict__ b, ushort* __restrict__ X)
{
    int row = blockIdx.x, t = threadIdx.x;
    ushort* o = X + (long long)row * DIM;
    if (row < PAD) {
        #pragma unroll
        for (int i = 0; i < 4; i++) o[t + i * 256] = 0;
        return;
    }
    const float* x = H + (long long)(row - PAD) * DIM;
    float r[4]; float s = 0.f;
    #pragma unroll
    for (int i = 0; i < 4; i++) { r[i] = x[t + i * 256]; s += r[i]; }
    float mu = blk_sum(s) * (1.f / DIM);
    float v = 0.f;
    #pragma unroll
    for (int i = 0; i < 4; i++) { float d = r[i] - mu; v += d * d; }
    float var = blk_sum(v) * (1.f / DIM);
    float rs = rsqrtf(var + 1e-5f);
    #pragma unroll
    for (int i = 0; i < 4; i++) { int c = t + i * 256; o[c] = f2b((r[i] - mu) * rs * g[c] + b[c]); }
}

// ---------------- landmarks ----------------
__global__ __launch_bounds__(128)
void landmarks(const ushort* __restrict__ QKVb, ushort* __restrict__ QL, ushort* __restrict__ KL)
{
    int L = blockIdx.x, h = blockIdx.y, d = threadIdx.x;
    float sq = 0.f, sk = 0.f;
    #pragma unroll
    for (int j = 0; j < LSUB; j++) {
        const ushort* p = QKVb + (long long)(L * LSUB + j) * 3072 + h * DHEAD + d;
        sq += b2f(p[0]);
        sk += b2f(p[1024]);
    }
    QL[(long long)(h * LMK + L) * DHEAD + d] = f2b(sq * (1.f / LSUB));
    KL[(long long)(h * LMK + L) * DHEAD + d] = f2b(sk * (1.f / LSUB));
}

// ---------------- V transpose -> bf16 VT[h][d][i] ----------------
__global__ void vtrans(const ushort* __restrict__ Q, ushort* __restrict__ VT)
{
    __shared__ ushort tile[32][33];
    int h = blockIdx.z, i0 = blockIdx.x * 32, d0 = blockIdx.y * 32;
    int tx = threadIdx.x, ty = threadIdx.y;
    for (int yy = ty; yy < 32; yy += 8)
        tile[yy][tx] = Q[(long long)(i0 + yy) * 3072 + 2048 + h * 128 + d0 + tx];
    __syncthreads();
    for (int yy = ty; yy < 32; yy += 8)
        VT[((long long)h * 128 + d0 + yy) * 6144 + i0 + tx] = tile[tx][yy];
}

// ---------------- a2 column sums ----------------
__global__ __launch_bounds__(256)
void a2_sums2(const float* __restrict__ A2, float* __restrict__ cols)
{
    int h = blockIdx.x, slice = blockIdx.y, t = threadIdx.x;
    const float* a = A2 + (long long)h * LMK * LMK + (long long)slice * 64 * LMK;
    float s0 = 0.f, s1 = 0.f;
    #pragma unroll 4
    for (int i = 0; i < 64; i++) {
        s0 += a[(long long)i * LMK + t];
        s1 += a[(long long)i * LMK + t + 256];
    }
    atomicAdd(&cols[h * LMK + t], s0);
    atomicAdd(&cols[h * LMK + t + 256], s1);
}
__global__ __launch_bounds__(256)
void a2_scal2(const float* __restrict__ cols, float* __restrict__ scal)
{
    float mc = -1e30f;
    for (int i = threadIdx.x; i < HEADS * LMK; i += 256) mc = fmaxf(mc, cols[i]);
    mc = blk_max(mc);
    if (threadIdx.x == 0) scal[0] = 1.f / mc;
}

// ---------------- z0/X prep ----------------
__global__ void z0_t(const float* __restrict__ A2, ushort* __restrict__ Xb,
                     ushort* __restrict__ Z0b, ushort* __restrict__ Z0T,
                     const float* __restrict__ scal)
{
    __shared__ float tile[32][33];
    int h = blockIdx.z;
    const float* a = A2 + (long long)h * LMK * LMK;
    float s = scal[0];
    int x0 = blockIdx.x * 32, y0 = blockIdx.y * 32;
    int tx = threadIdx.x, ty = threadIdx.y;
    long long hb = (long long)h * LMK * LMK;
    for (int yy = ty; yy < 32; yy += 8) {
        float v = a[(long long)(y0 + yy) * LMK + x0 + tx];
        tile[yy][tx] = v;
        Xb [hb + (long long)(y0 + yy) * LMK + x0 + tx] = f2b(v);
        Z0T[hb + (long long)(y0 + yy) * LMK + x0 + tx] = f2b(s * v);
    }
    __syncthreads();
    for (int yy = ty; yy < 32; yy += 8)
        Z0b[hb + (long long)(x0 + yy) * LMK + y0 + tx] = f2b(s * tile[tx][yy]);
}

// ---------------- MoE ----------------
__global__ __launch_bounds__(256)
void moe_combine(const float* __restrict__ X, const float* __restrict__ wg,
                 const ushort* __restrict__ EO, const float* __restrict__ eb,
                 float* __restrict__ H)
{
    int i = blockIdx.x, t = threadIdx.x;
    const float* x = X + (long long)i * INDIM;
    float g0 = 0.f, g1 = 0.f, g2 = 0.f;
    for (int f = t; f < INDIM; f += 256) {
        float xv = x[f];
        const float* w = wg + f * 3;
        g0 += xv * w[0]; g1 += xv * w[1]; g2 += xv * w[2];
    }
    g0 = blk_sum(g0); g1 = blk_sum(g1); g2 = blk_sum(g2);
    float m = fmaxf(g0, fmaxf(g1, g2));
    float e0 = __expf(g0 - m), e1 = __expf(g1 - m), e2 = __expf(g2 - m);
    float inv = 1.f / (e0 + e1 + e2);
    e0 *= inv; e1 *= inv; e2 *= inv;
    const ushort* eo = EO + (long long)i * 3072;
    for (int o = t; o < DIM; o += 256) {
        float v0 = fmaxf(b2f(eo[o])        + eb[o],        0.f);
        float v1 = fmaxf(b2f(eo[1024 + o]) + eb[1024 + o], 0.f);
        float v2 = fmaxf(b2f(eo[2048 + o]) + eb[2048 + o], 0.f);
        float r = e0 * v0 + e1 * v1 + e2 * v2;
        H[(long long)(1 + i) * DIM + o] = r;
        if (i < 84) H[(long long)(6001 + i) * DIM + o] = r;
    }
}

__global__ void cls_copy(const float* __restrict__ c, float* __restrict__ H)
{
    for (int i = threadIdx.x; i < DIM; i += 256) H[i] = c[i];
}

// ---------------- res conv (vectorized, 8 channels/thread): Ob = bf16(O + dw33(V)) ----------------
__global__ __launch_bounds__(256)
void resconv(const ushort* __restrict__ QKVb, const float* __restrict__ rw,
             const float* __restrict__ O, ushort* __restrict__ Ob)
{
    long long idx = (long long)blockIdx.x * 256 + threadIdx.x;   // over NPL * 128
    int cg = (int)(idx & 127);
    long long i = idx >> 7;
    int c0 = cg * 8;
    int h = c0 >> 7;
    float acc[8];
    const float* op = O + i * DIM + c0;
    float4 o0 = *(const float4*)op, o1 = *(const float4*)(op + 4);
    acc[0] = o0.x; acc[1] = o0.y; acc[2] = o0.z; acc[3] = o0.w;
    acc[4] = o1.x; acc[5] = o1.y; acc[6] = o1.z; acc[7] = o1.w;
    const ushort* vb = QKVb + 2048 + c0;
    const float* rwh = rw + h * 33;
    #pragma unroll
    for (int t = 0; t < 33; t++) {
        long long r = i + t - 16;
        if ((unsigned long long)r < (unsigned long long)NPL) {
            float wv = rwh[t];
            const ushort* p = vb + r * 3072;
            ushort4 v0 = *(const ushort4*)p, v1 = *(const ushort4*)(p + 4);
            acc[0] += wv * b2f(v0.x); acc[1] += wv * b2f(v0.y);
            acc[2] += wv * b2f(v0.z); acc[3] += wv * b2f(v0.w);
            acc[4] += wv * b2f(v1.x); acc[5] += wv * b2f(v1.y);
            acc[6] += wv * b2f(v1.z); acc[7] += wv * b2f(v1.w);
        }
    }
    ushort4 u0 = {f2b(acc[0]), f2b(acc[1]), f2b(acc[2]), f2b(acc[3])};
    ushort4 u1 = {f2b(acc[4]), f2b(acc[5]), f2b(acc[6]), f2b(acc[7])};
    ushort* ob = Ob + i * DIM + c0;
    *(ushort4*)ob = u0;
    *(ushort4*)(ob + 4) = u1;
}

// ---------------- PPEG ----------------
__global__ void h2f(const float* __restrict__ H, float* __restrict__ F)
{
    __shared__ float tile[32][33];
    int p0 = blockIdx.x * 32, c0 = blockIdx.y * 32;
    int tx = threadIdx.x, ty = threadIdx.y;
    for (int yy = ty; yy < 32; yy += 8) {
        int p = p0 + yy;
        if (p < HW * HW) tile[yy][tx] = H[(long long)(1 + p) * DIM + c0 + tx];
    }
    __syncthreads();
    for (int yy = ty; yy < 32; yy += 8) {
        int p = p0 + tx, c = c0 + yy;
        if (p < HW * HW) F[(long long)c * (HW * HW) + p] = tile[tx][yy];
    }
}
__global__ void f2h(const float* __restrict__ F2, float* __restrict__ H)
{
    __shared__ float tile[32][33];
    int c0 = blockIdx.x * 32, p0 = blockIdx.y * 32;
    int tx = threadIdx.x, ty = threadIdx.y;
    for (int yy = ty; yy < 32; yy += 8) {
        int p = p0 + tx;
        if (p < HW * HW) tile[yy][tx] = F2[(long long)(c0 + yy) * (HW * HW) + p];
    }
    __syncthreads();
    for (int yy = ty; yy < 32; yy += 8) {
        int p = p0 + yy;
        if (p < HW * HW) H[(long long)(1 + p) * DIM + c0 + tx] = tile[tx][yy];
    }
}
__global__ __launch_bounds__(256)
void ppeg_conv2(const float* __restrict__ F,
                const float* __restrict__ w7, const float* __restrict__ b7,
                const float* __restrict__ w5, const float* __restrict__ b5,
                const float* __restrict__ w3, const float* __restrict__ b3,
                float* __restrict__ F2)
{
    int c = blockIdx.x, t = threadIdx.x;
    __shared__ float plane[HW * HW];
    __shared__ float wm[49];
    for (int p = t; p < HW * HW; p += 256) plane[p] = F[(long long)c * (HW * HW) + p];
    if (t < 49) {
        int ky = t / 7 - 3, kx = t % 7 - 3;
        float w = w7[(long long)c * 49 + t];
        if (ky >= -2 && ky <= 2 && kx >= -2 && kx <= 2) w += w5[(long long)c * 25 + (ky + 2) * 5 + (kx + 2)];
        if (ky >= -1 && ky <= 1 && kx >= -1 && kx <= 1) w += w3[(long long)c * 9 + (ky + 1) * 3 + (kx + 1)];
        if (t == 24) w += 1.0f;
        wm[t] = w;
    }
    __syncthreads();
    float bsum = b7[c] + b5[c] + b3[c];
    for (int p = t; p < HW * HW; p += 256) {
        int y = p / HW, x = p - y * HW;
        float acc = bsum;
        if (y >= 3 && y < HW - 3 && x >= 3 && x < HW - 3) {
            const float* base = &plane[p];
            #pragma unroll
            for (int ky = -3; ky <= 3; ky++)
                #pragma unroll
                for (int kx = -3; kx <= 3; kx++)
                    acc += wm[(ky + 3) * 7 + kx + 3] * base[ky * HW + kx];
        } else {
            for (int ky = -3; ky <= 3; ky++) {
                int yy = y + ky; if ((unsigned)yy >= (unsigned)HW) continue;
                for (int kx = -3; kx <= 3; kx++) {
                    int xx = x + kx; if ((unsigned)xx >= (unsigned)HW) continue;
                    acc += wm[(ky + 3) * 7 + kx + 3] * plane[yy * HW + xx];
                }
            }
        }
        F2[(long long)c * (HW * HW) + p] = acc;
    }
}

// ---------------- final head ----------------
__global__ __launch_bounds__(256)
void head_k(const float* __restrict__ H, const float* __restrict__ g, const float* __restrict__ b,
            const float* __restrict__ fw, const float* __restrict__ fb, float* __restrict__ out)
{
    int t = threadIdx.x;
    float r[4]; float s = 0.f;
    #pragma unroll
    for (int i = 0; i < 4; i++) { r[i] = H[t + i * 256]; s += r[i]; }
    float mu = blk_sum(s) * (1.f / DIM);
    float v = 0.f;
    #pragma unroll
    for (int i = 0; i < 4; i++) { float d = r[i] - mu; v += d * d; }
    float var = blk_sum(v) * (1.f / DIM);
    float rs = rsqrtf(var + 1e-5f);
    float d0 = 0.f, d1 = 0.f;
    #pragma unroll
    for (int i = 0; i < 4; i++) {
        int c = t + i * 256;
        float hv = (r[i] - mu) * rs * g[c] + b[c];
        d0 += hv * fw[c];
        d1 += hv * fw[DIM + c];
    }
    d0 = blk_sum(d0); d1 = blk_sum(d1);
    if (t == 0) {
        float l0 = d0 + fb[0], l1 = d1 + fb[1];
        float m = fmaxf(l0, l1);
        float e0 = __expf(l0 - m), e1 = __expf(l1 - m);
        float inv = 1.f / (e0 + e1);
        out[0] = l0; out[1] = l1;
        out[2] = e0 * inv; out[3] = e1 * inv;
        out[4] = (l1 > l0) ? 1.0f : 0.0f;
    }
}

// ---------------- host ----------------
extern "C" void kernel_launch(void* const* d_in, const int* in_sizes, int n_in,
                              void* d_out, int out_size, void* d_ws, size_t ws_size,
                              hipStream_t stream)
{
    const float* data     = (const float*)d_in[0];
    const float* w_gate   = (const float*)d_in[1];
    const float* expert_w = (const float*)d_in[2];
    const float* expert_b = (const float*)d_in[3];
    const float* cls_tok  = (const float*)d_in[4];
    const float* ln_g[2]  = {(const float*)d_in[5],  (const float*)d_in[11]};
    const float* ln_b[2]  = {(const float*)d_in[6],  (const float*)d_in[12]};
    const float* qkv_w[2] = {(const float*)d_in[7],  (const float*)d_in[13]};
    const float* out_w[2] = {(const float*)d_in[8],  (const float*)d_in[14]};
    const float* out_b[2] = {(const float*)d_in[9],  (const float*)d_in[15]};
    const float* res_w[2] = {(const float*)d_in[10], (const float*)d_in[16]};
    const float* pw7 = (const float*)d_in[17]; const float* pb7 = (const float*)d_in[18];
    const float* pw5 = (const float*)d_in[19]; const float* pb5 = (const float*)d_in[20];
    const float* pw3 = (const float*)d_in[21]; const float* pb3 = (const float*)d_in[22];
    const float* nf_g = (const float*)d_in[23]; const float* nf_b = (const float*)d_in[24];
    const float* fc2w = (const float*)d_in[25]; const float* fc2b = (const float*)d_in[26];

    float*  ws    = (float*)d_ws;
    float*  H     = ws + OFF_H;
    ushort* LNXb  = (ushort*)(ws + OFF_LNXO);
    float*  O     = ws + OFF_LNXO;             // alias: O written after LNXb dead
    ushort* QKVb  = (ushort*)(ws + OFF_QKVB);
    ushort* EOb   = (ushort*)(ws + OFF_QKVB);
    float*  PBV   = ws + OFF_PBV;
    float*  PM    = ws + OFF_PM;
    float*  PL    = ws + OFF_PL;
    ushort* Ob    = (ushort*)(ws + OFF_OB);
    ushort* VT    = (ushort*)(ws + OFF_VT);
    ushort* QL    = (ushort*)(ws + OFF_QL);
    ushort* KL    = (ushort*)(ws + OFF_KL);
    float*  A2F   = ws + OFF_A2F;
    ushort* BVTb  = (ushort*)(ws + OFF_BVTB);
    ushort* Xb    = (ushort*)(ws + OFF_XB);
    ushort* XZB   = (ushort*)(ws + OFF_XZB);
    ushort* XZT7  = (ushort*)(ws + OFF_XZT7);
    ushort* PT15  = (ushort*)(ws + OFF_PT15);
    ushort* QT13  = (ushort*)(ws + OFF_QT13);
    ushort* ZB[2] = {(ushort*)(ws + OFF_ZB0), (ushort*)(ws + OFF_ZB1)};
    ushort* ZT[2] = {(ushort*)(ws + OFF_ZT0), (ushort*)(ws + OFF_ZT1)};
    ushort* ZBT   = (ushort*)(ws + OFF_ZBT);
    ushort* QWB   = (ushort*)(ws + OFF_QWB);
    ushort* OWB   = (ushort*)(ws + OFF_OWB);
    ushort* DATAB = (ushort*)(ws + OFF_DATAB);
    ushort* EWB   = (ushort*)(ws + OFF_EWB);
    float*  COLS  = ws + OFF_COLS;
    float*  SCAL  = ws + OFF_SCAL;

    const long long HSB = (long long)LMK * DHEAD;   // 65536
    const long long A2S = (long long)LMK * LMK;     // 262144

    // ---- MoE ----
    cvt_bf16<<<4500, 256, 0, stream>>>(data, DATAB, (long long)NTOK * INDIM);
    cvt_bf16<<<2304, 256, 0, stream>>>(expert_w, EWB, 3072LL * INDIM);
    mg<2><<<dim3(24,47,1),256,0,stream>>>(DATAB,INDIM,0, EWB,INDIM,0, EOb,3072,0,
        nullptr,0,0, NTOK,INDIM, nullptr, 1.f,0.f,0.f);
    moe_combine<<<NTOK,256,0,stream>>>(data, w_gate, EOb, expert_b, H);
    cls_copy<<<1,256,0,stream>>>(cls_tok, H);

    for (int stage = 0; stage < 2; stage++) {
        cvt_bf16<<<1536, 256, 0, stream>>>(qkv_w[stage], QWB, 3072LL * DIM);
        cvt_bf16<<<512, 256, 0, stream>>>(out_w[stage], OWB, (long long)DIM * DIM);
        ln_pad<<<NPL,256,0,stream>>>(H, ln_g[stage], ln_b[stage], LNXb);
        mg<1><<<dim3(24,48,1),256,0,stream>>>(LNXb,DIM,0, QWB,DIM,0, QKVb,3072,0,
            nullptr,0,0, NPL,DIM, nullptr, 1.f,0.f,0.f);
        landmarks<<<dim3(LMK,HEADS),128,0,stream>>>(QKVb, QL, KL);
        vtrans<<<dim3(192,4,8),dim3(32,8),0,stream>>>(QKVb, VT);
        // a2 = softmax(ql @ kl^T) f32  (64x128 tiles -> 256 blocks)
        mg64<0><<<dim3(4,8,8),256,0,stream>>>(QL,DHEAD,HSB, KL,DHEAD,HSB, A2F,LMK,A2S,
            nullptr,0,0, DHEAD, 1.f,0.f,0.f);
        softmax_rows<2><<<HEADS*LMK,256,0,stream>>>(A2F, LMK);
        hipMemsetAsync(COLS, 0, HEADS * LMK * sizeof(float), stream);
        a2_sums2<<<dim3(HEADS,8),256,0,stream>>>(A2F, COLS);
        a2_scal2<<<1,256,0,stream>>>(COLS, SCAL);
        z0_t<<<dim3(16,16,8),dim3(32,8),0,stream>>>(A2F, Xb, ZB[0], ZT[0], SCAL);
        // Newton-Schulz: 6 iterations, 64x128-tile GEMMs (256 blocks = all CUs)
        int cur = 0;
        for (int it = 0; it < 6; it++) {
            mg64<4><<<dim3(4,8,8),256,0,stream>>>(Xb,LMK,A2S, ZT[cur],LMK,A2S, XZB,LMK,A2S,
                XZT7,LMK,A2S, LMK, 1.f, 7.f, -1.f);
            mg64<5><<<dim3(4,8,8),256,0,stream>>>(XZB,LMK,A2S, XZT7,LMK,A2S, nullptr,0,0,
                PT15,LMK,A2S, LMK, 1.f, 15.f, -1.f);
            mg64<5><<<dim3(4,8,8),256,0,stream>>>(XZB,LMK,A2S, PT15,LMK,A2S, nullptr,0,0,
                QT13,LMK,A2S, LMK, 1.f, 13.f, -1.f);
            if (it < 5)
                mg64<4><<<dim3(4,8,8),256,0,stream>>>(ZB[cur],LMK,A2S, QT13,LMK,A2S, ZB[1-cur],LMK,A2S,
                    ZT[1-cur],LMK,A2S, LMK, 0.25f, 0.f, 1.f);
            else
                mg64<2><<<dim3(4,8,8),256,0,stream>>>(ZB[cur],LMK,A2S, QT13,LMK,A2S, ZB[1-cur],LMK,A2S,
                    nullptr,0,0, LMK, 0.25f, 0.f, 1.f);
            cur = 1 - cur;
        }
        ushort* Z6 = ZB[cur];
        // flash a3: partial bv over 16 kv-chunks of 384
        flash<1,2><<<dim3(4,NSPLIT,8),256,0,stream>>>(QL,DHEAD,HSB, QKVb+1024,3072,128,
            VT,NPL,(long long)DHEAD*NPL, PBV, PM, PL, 6, 384);
        bv_combine<<<dim3(16,8),256,0,stream>>>(PBV, PM, PL, BVTb);
        // ZBT[d][l'] = sum_l bvT[d][l] z6[l'][l]  (64 blocks)
        mg64<2><<<dim3(4,2,8),256,0,stream>>>(BVTb,LMK,HSB, Z6,LMK,A2S, ZBT,LMK,HSB,
            nullptr,0,0, LMK, 1.f,0.f,0.f);
        // flash a1: O = softmax(q @ kl^T) @ zb  (64-row q tiles, 768 blocks)
        flash<0,1><<<dim3(96,1,8),256,0,stream>>>(QKVb,3072,128, KL,DHEAD,HSB,
            ZBT,LMK,HSB, O, nullptr, nullptr, 8, 0);
        // Ob = bf16(O + res conv of v)  (vectorized: 8 channels/thread)
        resconv<<<(NPL*128)/256,256,0,stream>>>(QKVb, res_w[stage], O, Ob);
        // H += Ob @ out_w^T + out_b
        mg<3><<<dim3(8,48,1),256,0,stream>>>(Ob + (long long)PAD*DIM,DIM,0, OWB,DIM,0, H,DIM,0,
            nullptr,0,0, NH,DIM, out_b[stage], 1.f,0.f,0.f);
        if (stage == 0) {
            float* F  = ws + OFF_QKVB;
            float* F2 = F + 6230016LL;
            h2f<<<dim3(191,32),dim3(32,8),0,stream>>>(H, F);
            ppeg_conv2<<<DIM,256,0,stream>>>(F, pw7, pb7, pw5, pb5, pw3, pb3, F2);
            f2h<<<dim3(32,191),dim3(32,8),0,stream>>>(F2, H);
        }
    }

    head_k<<<1,256,0,stream>>>(H, nf_g, nf_b, fc2w, fc2b, (float*)d_out);
}

// Round 13
// 1441.145 us; speedup vs baseline: 1.8138x; 1.0139x over previous
//
#include <hip/hip_runtime.h>
#include <hip/hip_bf16.h>

// ---------------- constants ----------------
#define NTOK   6000
#define INDIM  1536
#define DIM    1024
#define NPL    6144
#define PAD    59
#define NH     6085
#define HEADS  8
#define DHEAD  128
#define LMK    512
#define LSUB   12
#define HW     78
#define QSCALE 0.08838834764831845f
#define NSPLIT 16

// ---------------- ws layout (float-slot offsets) ----------------
#define OFF_H     0LL          // 6144*1024 f32
#define OFF_LNXO  6291456LL    // LNXb bf16
#define OFF_QKVB  12582912LL   // 6144*3072 bf16; EO bf16 + PPEG planes alias
#define OFF_PBV   22020096LL   // 8h*512*16c*128 f32 = 8388608
#define OFF_PM    30408704LL   // 65536
#define OFF_PL    30474240LL   // 65536
#define OFF_OB    30539776LL   // 6144*1024 bf16 = 3145728 slots (ends 33685504)
#define OFF_VT    34603008LL   // 8*128*6144 bf16
#define OFF_QL    37748736LL
#define OFF_KL    38010880LL
#define OFF_A2F   38273024LL   // 8*512*512 f32
#define OFF_BVTB  40370176LL   // 8*128*512 bf16
#define OFF_XB    42467328LL   // bf16 8*512*512 each below
#define OFF_XZB   43515904LL
#define OFF_XZT7  44564480LL
#define OFF_PT15  45613056LL
#define OFF_QT13  46661632LL
#define OFF_ZB0   47710208LL
#define OFF_ZT0   48758784LL
#define OFF_ZB1   49807360LL
#define OFF_ZT1   50855936LL
#define OFF_ZBT   52428800LL   // 8*128*512 bf16
#define OFF_QWB   52690944LL   // 3072*1024 bf16
#define OFF_OWB   54263808LL   // 1024*1024 bf16
#define OFF_COLS  54788096LL
#define OFF_SCAL  54796288LL
// transient aliases (dead before overlapping buffers are written)
#define OFF_DATAB 31457280LL   // 6000*1536 bf16 (pre-stage only; overlaps OB/VT span)
#define OFF_EWB   36065280LL   // 3072*1536 bf16 (pre-stage only)

typedef __attribute__((ext_vector_type(8))) short s16x8;
typedef __attribute__((ext_vector_type(4))) float f32x4;

// ---------------- bf16 helpers ----------------
__device__ __forceinline__ ushort f2b(float f) {
    union { float f; unsigned u; } v; v.f = f;
    return (ushort)((v.u + 0x7FFF + ((v.u >> 16) & 1)) >> 16);
}
__device__ __forceinline__ float b2f(ushort h) {
    union { unsigned u; float f; } v; v.u = ((unsigned)h) << 16; return v.f;
}

// async global->LDS, 16 bytes per lane; lds ptr must be wave-uniform
__device__ __forceinline__ void gld16(const void* g, void* l) {
    __builtin_amdgcn_global_load_lds((const __attribute__((address_space(1))) void*)g,
                                     (__attribute__((address_space(3))) void*)l, 16, 0, 0);
}

// ---------------- reductions (blockDim.x == 256) ----------------
__device__ __forceinline__ float blk_sum(float v) {
    __shared__ float sb[4];
    #pragma unroll
    for (int o = 32; o > 0; o >>= 1) v += __shfl_down(v, o);
    int lane = threadIdx.x & 63, w = threadIdx.x >> 6;
    __syncthreads();
    if (lane == 0) sb[w] = v;
    __syncthreads();
    return sb[0] + sb[1] + sb[2] + sb[3];
}
__device__ __forceinline__ float blk_max(float v) {
    __shared__ float sb[4];
    #pragma unroll
    for (int o = 32; o > 0; o >>= 1) v = fmaxf(v, __shfl_down(v, o));
    int lane = threadIdx.x & 63, w = threadIdx.x >> 6;
    __syncthreads();
    if (lane == 0) sb[w] = v;
    __syncthreads();
    return fmaxf(fmaxf(sb[0], sb[1]), fmaxf(sb[2], sb[3]));
}

// ================= MFMA GEMM (bf16 x bf16), C = alpha * A @ B^T, 128x128 tile =================
// BK=64 (2 MFMA sub-steps per barrier pair). Requires K % 64 == 0.
// EPI: 0 f32 | 1 bf16 qkv-scale | 2 bf16 | 3 f32 += v+bias
//      4 bf16 C + bf16 T[c][r]=tdelta*(r==c)+tsign*v | 5 T only
template<int EPI>
__global__ __launch_bounds__(256)
void mg(const ushort* __restrict__ A, int lda, long long sA,
        const ushort* __restrict__ B, int ldb, long long sB,
        void* __restrict__ Cp, int ldc, long long sC,
        void* __restrict__ Tp, int ldt, long long sT,
        int M, int K, const float* __restrict__ bias,
        float alpha, float tdelta, float tsign)
{
    __shared__ ushort As[8192];   // 2 subtiles [128][32]
    __shared__ ushort Bs[8192];
    const int t = threadIdx.x;
    const int z = blockIdx.z;
    const ushort* Ab = A + (long long)z * sA;
    const ushort* Bb = B + (long long)z * sB;
    const int row0 = blockIdx.y * 128, col0 = blockIdx.x * 128;
    const int w = t >> 6, lane = t & 63;
    const int l4 = lane >> 2, ls = (lane & 3) * 8;
    const int q0 = w, q1 = 4 + w;
    int ar0 = row0 + q0 * 16 + l4; if (ar0 >= M) ar0 = M - 1;
    int ar1 = row0 + q1 * 16 + l4; if (ar1 >= M) ar1 = M - 1;
    const int br0 = col0 + q0 * 16 + l4;
    const int br1 = col0 + q1 * 16 + l4;
    const ushort* ap0 = Ab + (long long)ar0 * lda + ls;
    const ushort* ap1 = Ab + (long long)ar1 * lda + ls;
    const ushort* bp0 = Bb + (long long)br0 * ldb + ls;
    const ushort* bp1 = Bb + (long long)br1 * ldb + ls;
    ushort* asl0 = &As[q0 * 512];
    ushort* asl1 = &As[q1 * 512];
    ushort* bsl0 = &Bs[q0 * 512];
    ushort* bsl1 = &Bs[q1 * 512];

    const int wr = (w >> 1) * 64, wc = (w & 1) * 64;
    const int fr = lane & 15, fo = (lane >> 4) * 8;

    f32x4 acc[4][4];
    #pragma unroll
    for (int a = 0; a < 4; a++)
        #pragma unroll
        for (int b = 0; b < 4; b++)
            acc[a][b] = (f32x4){0.f, 0.f, 0.f, 0.f};

    for (int kt = 0; kt < K; kt += 64) {
        gld16(ap0 + kt, asl0);
        gld16(ap1 + kt, asl1);
        gld16(bp0 + kt, bsl0);
        gld16(bp1 + kt, bsl1);
        gld16(ap0 + kt + 32, asl0 + 4096);
        gld16(ap1 + kt + 32, asl1 + 4096);
        gld16(bp0 + kt + 32, bsl0 + 4096);
        gld16(bp1 + kt + 32, bsl1 + 4096);
        __syncthreads();
        #pragma unroll
        for (int half = 0; half < 2; half++) {
            s16x8 af[4], bf[4];
            #pragma unroll
            for (int a = 0; a < 4; a++) af[a] = *(const s16x8*)&As[half * 4096 + (wr + a * 16 + fr) * 32 + fo];
            #pragma unroll
            for (int b = 0; b < 4; b++) bf[b] = *(const s16x8*)&Bs[half * 4096 + (wc + b * 16 + fr) * 32 + fo];
            #pragma unroll
            for (int a = 0; a < 4; a++)
                #pragma unroll
                for (int b = 0; b < 4; b++)
                    acc[a][b] = __builtin_amdgcn_mfma_f32_16x16x32_bf16(af[a], bf[b], acc[a][b], 0, 0, 0);
        }
        __syncthreads();
    }

    const int er0 = row0 + wr + ((lane >> 4) << 2);
    const int ec0 = col0 + wc + fr;
    #pragma unroll
    for (int a = 0; a < 4; a++) {
        #pragma unroll
        for (int j = 0; j < 4; j++) {
            int r = er0 + a * 16 + j;
            if (r >= M) continue;
            #pragma unroll
            for (int b = 0; b < 4; b++) {
                int c = ec0 + b * 16;
                float v = alpha * acc[a][b][j];
                long long ci = z * sC + (long long)r * ldc + c;
                if constexpr (EPI == 0) ((float*)Cp)[ci] = v;
                else if constexpr (EPI == 1) ((ushort*)Cp)[ci] = f2b(c < 1024 ? v * QSCALE : v);
                else if constexpr (EPI == 2) ((ushort*)Cp)[ci] = f2b(v);
                else if constexpr (EPI == 3) ((float*)Cp)[ci] += v + bias[c];
                else {
                    ushort tv = f2b((r == c ? tdelta : 0.f) + tsign * v);
                    long long ti = z * sT + (long long)c * ldt + r;
                    if constexpr (EPI == 4) { ((ushort*)Cp)[ci] = f2b(v); ((ushort*)Tp)[ti] = tv; }
                    else { ((ushort*)Tp)[ti] = tv; }  // 5
                }
            }
        }
    }
}

// ================= MFMA GEMM 64x128 tile — for small batched GEMMs =================
// C = alpha * A @ B^T. Requires M%64==0, N%128==0, K%64==0. Grid (N/128, M/64, Z). BK=64.
// EPI: 0 f32 | 2 bf16 | 4 bf16 C + bf16 T[c][r]=tdelta*(r==c)+tsign*v | 5 T only
template<int EPI>
__global__ __launch_bounds__(256)
void mg64(const ushort* __restrict__ A, int lda, long long sA,
          const ushort* __restrict__ B, int ldb, long long sB,
          void* __restrict__ Cp, int ldc, long long sC,
          void* __restrict__ Tp, int ldt, long long sT,
          int K, float alpha, float tdelta, float tsign)
{
    __shared__ ushort As[4096];   // 2 subtiles [64][32]
    __shared__ ushort Bs[8192];   // 2 subtiles [128][32]
    const int t = threadIdx.x;
    const int z = blockIdx.z;
    const ushort* Ab = A + (long long)z * sA;
    const ushort* Bb = B + (long long)z * sB;
    const int row0 = blockIdx.y * 64, col0 = blockIdx.x * 128;
    const int w = t >> 6, lane = t & 63;
    const int l4 = lane >> 2, ls = (lane & 3) * 8;
    const ushort* ap = Ab + (long long)(row0 + w * 16 + l4) * lda + ls;
    ushort* asl = &As[w * 16 * 32];
    const ushort* bp0 = Bb + (long long)(col0 + w * 16 + l4) * ldb + ls;
    const ushort* bp1 = Bb + (long long)(col0 + 64 + w * 16 + l4) * ldb + ls;
    ushort* bsl0 = &Bs[w * 16 * 32];
    ushort* bsl1 = &Bs[(64 + w * 16) * 32];

    const int fr = lane & 15, fo = (lane >> 4) * 8;

    f32x4 acc[4][2];
    #pragma unroll
    for (int a = 0; a < 4; a++)
        #pragma unroll
        for (int b = 0; b < 2; b++)
            acc[a][b] = (f32x4){0.f, 0.f, 0.f, 0.f};

    for (int kt = 0; kt < K; kt += 64) {
        gld16(ap + kt, asl);
        gld16(bp0 + kt, bsl0);
        gld16(bp1 + kt, bsl1);
        gld16(ap + kt + 32, asl + 2048);
        gld16(bp0 + kt + 32, bsl0 + 4096);
        gld16(bp1 + kt + 32, bsl1 + 4096);
        __syncthreads();
        #pragma unroll
        for (int half = 0; half < 2; half++) {
            s16x8 af[4], bf[2];
            #pragma unroll
            for (int a = 0; a < 4; a++) af[a] = *(const s16x8*)&As[half * 2048 + (a * 16 + fr) * 32 + fo];
            #pragma unroll
            for (int b = 0; b < 2; b++) bf[b] = *(const s16x8*)&Bs[half * 4096 + (w * 32 + b * 16 + fr) * 32 + fo];
            #pragma unroll
            for (int a = 0; a < 4; a++)
                #pragma unroll
                for (int b = 0; b < 2; b++)
                    acc[a][b] = __builtin_amdgcn_mfma_f32_16x16x32_bf16(af[a], bf[b], acc[a][b], 0, 0, 0);
        }
        __syncthreads();
    }

    const int er0 = row0 + ((lane >> 4) << 2);
    const int ec0 = col0 + w * 32 + fr;
    #pragma unroll
    for (int a = 0; a < 4; a++) {
        #pragma unroll
        for (int j = 0; j < 4; j++) {
            int r = er0 + a * 16 + j;
            #pragma unroll
            for (int b = 0; b < 2; b++) {
                int c = ec0 + b * 16;
                float v = alpha * acc[a][b][j];
                long long ci = z * sC + (long long)r * ldc + c;
                if constexpr (EPI == 0) ((float*)Cp)[ci] = v;
                else if constexpr (EPI == 2) ((ushort*)Cp)[ci] = f2b(v);
                else {
                    ushort tv = f2b((r == c ? tdelta : 0.f) + tsign * v);
                    long long ti = z * sT + (long long)c * ldt + r;
                    if constexpr (EPI == 4) { ((ushort*)Cp)[ci] = f2b(v); ((ushort*)Tp)[ti] = tv; }
                    else { ((ushort*)Tp)[ti] = tv; }  // 5
                }
            }
        }
    }
}

// ================= fused flash attention =================
// Q in registers; q tile = NFI*64 rows (wave owns NFI*16 rows); KV chunks of 64.
// Online softmax with defer-max (RESCALE_THRESHOLD=8) and setprio around MFMA clusters.
// MODE 0: final normalized bf16 output to Obp (cols h*128..); MODE 1: partial (acc,m,l) per kv-split.
template<int MODE, int NFI>
__global__ __launch_bounds__(256)
void flash(const ushort* __restrict__ Qp, int ldq, long long sQh,
           const ushort* __restrict__ Kp, int ldk, long long sKh,
           const ushort* __restrict__ Vp, int ldv, long long sVh,
           float* __restrict__ Op, float* __restrict__ Pm, float* __restrict__ Pl,
           ushort* __restrict__ Obp, int nkv, int kvspan)
{
    __shared__ ushort Zs[8192];    // 2 subtiles [128][32] (Vt chunk)
    __shared__ ushort KPs[8192];   // 4 subtiles [64][32] (K chunk); aliased by P [NFI*64][64] swizzled
    ushort* Ps = KPs;
    const int t = threadIdx.x;
    const int h = blockIdx.z;
    const int q0 = blockIdx.x * (NFI * 64);
    const int kvbase = blockIdx.y * kvspan;
    const ushort* Qb = Qp + (long long)h * sQh;
    const ushort* Kb = Kp + (long long)h * sKh;
    const ushort* Vb = Vp + (long long)h * sVh;
    const int w = t >> 6, lane = t & 63;
    const int sr = lane >> 2, sc2 = (lane & 3) * 8;
    const int fr = lane & 15, fo = (lane >> 4) * 8;
    const int jr = (lane >> 4) * 4;
    const int wbase = w * (NFI * 16);

    // Q fragments directly to registers (reused across all kv chunks)
    s16x8 qr[NFI][4];
    #pragma unroll
    for (int fi = 0; fi < NFI; fi++)
        #pragma unroll
        for (int ks = 0; ks < 4; ks++)
            qr[fi][ks] = *(const s16x8*)&Qb[(long long)(q0 + wbase + fi * 16 + fr) * ldq + ks * 32 + fo];

    f32x4 oa[NFI][8];
    float mold[NFI][4], lrun[NFI][4];
    #pragma unroll
    for (int fi = 0; fi < NFI; fi++) {
        #pragma unroll
        for (int fj = 0; fj < 8; fj++) oa[fi][fj] = (f32x4){0.f,0.f,0.f,0.f};
        #pragma unroll
        for (int j = 0; j < 4; j++) { mold[fi][j] = -1e30f; lrun[fi][j] = 0.f; }
    }

    for (int c = 0; c < nkv; c++) {
        int kvp = kvbase + c * 64;
        #pragma unroll
        for (int s = 0; s < 4; s++)
            gld16(Kb + (long long)(kvp + w * 16 + sr) * ldk + s * 32 + sc2,
                  &KPs[s * 2048 + (w * 16) * 32]);
        #pragma unroll
        for (int s = 0; s < 2; s++)
            #pragma unroll
            for (int r0 = 0; r0 < 128; r0 += 64)
                gld16(Vb + (long long)(r0 + w * 16 + sr) * ldv + kvp + s * 32 + sc2,
                      &Zs[s * 4096 + (r0 + w * 16) * 32]);
        __syncthreads();

        f32x4 acc[NFI][4];
        #pragma unroll
        for (int fi = 0; fi < NFI; fi++)
            #pragma unroll
            for (int fj = 0; fj < 4; fj++) acc[fi][fj] = (f32x4){0.f,0.f,0.f,0.f};
        __builtin_amdgcn_s_setprio(1);
        #pragma unroll
        for (int ks = 0; ks < 4; ks++) {
            s16x8 kb[4];
            #pragma unroll
            for (int fj = 0; fj < 4; fj++)
                kb[fj] = *(const s16x8*)&KPs[ks * 2048 + (fj * 16 + fr) * 32 + fo];
            #pragma unroll
            for (int fi = 0; fi < NFI; fi++)
                #pragma unroll
                for (int fj = 0; fj < 4; fj++)
                    acc[fi][fj] = __builtin_amdgcn_mfma_f32_16x16x32_bf16(qr[fi][ks], kb[fj], acc[fi][fj], 0, 0, 0);
        }
        __builtin_amdgcn_s_setprio(0);

        // online softmax with defer-max (threshold 8)
        float mx[NFI][4];
        bool need = false;
        #pragma unroll
        for (int fi = 0; fi < NFI; fi++) {
            #pragma unroll
            for (int j = 0; j < 4; j++) {
                float m0 = acc[fi][0][j];
                #pragma unroll
                for (int fj = 1; fj < 4; fj++) m0 = fmaxf(m0, acc[fi][fj][j]);
                m0 = fmaxf(m0, __shfl_xor(m0, 1));
                m0 = fmaxf(m0, __shfl_xor(m0, 2));
                m0 = fmaxf(m0, __shfl_xor(m0, 4));
                m0 = fmaxf(m0, __shfl_xor(m0, 8));
                mx[fi][j] = m0;
                need = need || (m0 - mold[fi][j] > 8.f);
            }
        }
        if (__any(need)) {
            #pragma unroll
            for (int fi = 0; fi < NFI; fi++)
                #pragma unroll
                for (int j = 0; j < 4; j++) {
                    float mn = fmaxf(mold[fi][j], mx[fi][j]);
                    float scl = __expf(mold[fi][j] - mn);
                    mold[fi][j] = mn;
                    lrun[fi][j] *= scl;
                    #pragma unroll
                    for (int fj = 0; fj < 8; fj++) oa[fi][fj][j] *= scl;
                }
        }
        float rs[NFI][4];
        #pragma unroll
        for (int fi = 0; fi < NFI; fi++) {
            #pragma unroll
            for (int j = 0; j < 4; j++) {
                float r = 0.f;
                #pragma unroll
                for (int fj = 0; fj < 4; fj++) {
                    float p = __expf(acc[fi][fj][j] - mold[fi][j]);
                    acc[fi][fj][j] = p;
                    r += p;
                }
                r += __shfl_xor(r, 1);
                r += __shfl_xor(r, 2);
                r += __shfl_xor(r, 4);
                r += __shfl_xor(r, 8);
                rs[fi][j] = r;
            }
        }
        __syncthreads();   // all waves done reading KPs
        #pragma unroll
        for (int fi = 0; fi < NFI; fi++)
            #pragma unroll
            for (int j = 0; j < 4; j++) {
                int row = wbase + fi * 16 + jr + j;
                lrun[fi][j] += rs[fi][j];
                #pragma unroll
                for (int fj = 0; fj < 4; fj++) {
                    int idx = (row * 64 + fj * 16 + fr) ^ ((row & 7) << 3);
                    Ps[idx] = f2b(acc[fi][fj][j]);
                }
            }
        __syncthreads();   // P visible

        __builtin_amdgcn_s_setprio(1);
        #pragma unroll
        for (int ks2 = 0; ks2 < 2; ks2++) {
            s16x8 pa[NFI], zb[8];
            #pragma unroll
            for (int fi = 0; fi < NFI; fi++) {
                int row = wbase + fi * 16 + fr;
                int idx = (row * 64 + ks2 * 32 + fo) ^ ((row & 7) << 3);
                pa[fi] = *(const s16x8*)&Ps[idx];
            }
            #pragma unroll
            for (int fj = 0; fj < 8; fj++)
                zb[fj] = *(const s16x8*)&Zs[ks2 * 4096 + (fj * 16 + fr) * 32 + fo];
            #pragma unroll
            for (int fi = 0; fi < NFI; fi++)
                #pragma unroll
                for (int fj = 0; fj < 8; fj++)
                    oa[fi][fj] = __builtin_amdgcn_mfma_f32_16x16x32_bf16(pa[fi], zb[fj], oa[fi][fj], 0, 0, 0);
        }
        __builtin_amdgcn_s_setprio(0);
        __syncthreads();
    }

    // epilogue
    #pragma unroll
    for (int fi = 0; fi < NFI; fi++)
        #pragma unroll
        for (int j = 0; j < 4; j++) {
            int row = wbase + fi * 16 + jr + j;
            if constexpr (MODE == 0) {
                float inv = 1.f / lrun[fi][j];
                #pragma unroll
                for (int fj = 0; fj < 8; fj++)
                    Obp[(long long)(q0 + row) * DIM + h * 128 + fj * 16 + fr] = f2b(oa[fi][fj][j] * inv);
            } else {
                long long rb = (((long long)h * 512 + q0 + row) * NSPLIT + blockIdx.y) * 128;
                #pragma unroll
                for (int fj = 0; fj < 8; fj++)
                    Op[rb + fj * 16 + fr] = oa[fi][fj][j];
                if (fr == 0) {
                    long long si = ((long long)h * 512 + q0 + row) * NSPLIT + blockIdx.y;
                    Pm[si] = mold[fi][j];
                    Pl[si] = lrun[fi][j];
                }
            }
        }
}

// combine kv-split partials -> bvT bf16 [h][d][l]
__global__ __launch_bounds__(256)
void bv_combine(const float* __restrict__ PBV, const float* __restrict__ Pm,
                const float* __restrict__ Pl, ushort* __restrict__ BVTb)
{
    __shared__ float T[32][129];
    __shared__ float wc8[32][NSPLIT], invL[32];
    int t = threadIdx.x;
    int h = blockIdx.y, l0 = blockIdx.x * 32;
    if (t < 32) {
        long long base = ((long long)h * 512 + l0 + t) * NSPLIT;
        float m = -1e30f;
        float mv[NSPLIT], lv[NSPLIT];
        #pragma unroll
        for (int c = 0; c < NSPLIT; c++) { mv[c] = Pm[base + c]; lv[c] = Pl[base + c]; m = fmaxf(m, mv[c]); }
        float L = 0.f;
        #pragma unroll
        for (int c = 0; c < NSPLIT; c++) { float wv = __expf(mv[c] - m); wc8[t][c] = wv; L += wv * lv[c]; }
        invL[t] = 1.f / L;
    }
    __syncthreads();
    int l = t >> 3, dg = t & 7;
    long long rbase = ((long long)h * 512 + l0 + l) * NSPLIT * 128;
    #pragma unroll
    for (int dd = 0; dd < 16; dd++) {
        int d = dg * 16 + dd;
        float s = 0.f;
        #pragma unroll
        for (int c = 0; c < NSPLIT; c++) s += wc8[l][c] * PBV[rbase + c * 128 + d];
        T[l][d] = s * invL[l];
    }
    __syncthreads();
    int d = t >> 1, half = t & 1;
    #pragma unroll
    for (int lc = 0; lc < 16; lc++) {
        int l2 = half * 16 + lc;
        BVTb[(long long)h * 65536 + (long long)d * 512 + l0 + l2] = f2b(T[l2][d]);
    }
}

// ---------------- f32 -> bf16 convert ----------------
__global__ __launch_bounds__(256)
void cvt_bf16(const float* __restrict__ x, ushort* __restrict__ y, long long n)
{
    long long i = ((long long)blockIdx.x * 256 + threadIdx.x) * 8;
    if (i >= n) return;
    float4 a = *(const float4*)(x + i), b = *(const float4*)(x + i + 4);
    ushort4 u0 = {f2b(a.x), f2b(a.y), f2b(a.z), f2b(a.w)};
    ushort4 u1 = {f2b(b.x), f2b(b.y), f2b(b.z), f2b(b.w)};
    *(ushort4*)(y + i) = u0; *(ushort4*)(y + i + 4) = u1;
}

// fused 2-array convert (per-stage weights: qkv_w then out_w)
__global__ __launch_bounds__(256)
void cvt2_bf16(const float* __restrict__ x1, ushort* __restrict__ y1, long long n1,
               const float* __restrict__ x2, ushort* __restrict__ y2, long long n2)
{
    long long i = ((long long)blockIdx.x * 256 + threadIdx.x) * 8;
    const float* x; ushort* y; long long j;
    if (i < n1) { x = x1; y = y1; j = i; }
    else { j = i - n1; if (j >= n2) return; x = x2; y = y2; }
    float4 a = *(const float4*)(x + j), b = *(const float4*)(x + j + 4);
    ushort4 u0 = {f2b(a.x), f2b(a.y), f2b(a.z), f2b(a.w)};
    ushort4 u1 = {f2b(b.x), f2b(b.y), f2b(b.z), f2b(b.w)};
    *(ushort4*)(y + j) = u0; *(ushort4*)(y + j + 4) = u1;
}

// ---------------- softmax fp32 rows (W = NIT*256) ----------------
template<int NIT>
__global__ __launch_bounds__(256)
void softmax_rows(float* __restrict__ X, int W)
{
    long long row = blockIdx.x;
    float* x = X + row * W;
    float r[NIT];
    float m = -1e30f;
    #pragma unroll
    for (int i = 0; i < NIT; i++) { r[i] = x[threadIdx.x + i * 256]; m = fmaxf(m, r[i]); }
    m = blk_max(m);
    float s = 0.f;
    #pragma unroll
    for (int i = 0; i < NIT; i++) { r[i] = __expf(r[i] - m); s += r[i]; }
    s = blk_sum(s);
    float inv = 1.f / s;
    #pragma unroll
    for (int i = 0; i < NIT; i++) x[threadIdx.x + i * 256] = r[i] * inv;
}

// ---------------- LN + front-pad -> bf16 ----------------
__global__ __launch_bounds__(256)
void ln_pad(const float* __restrict__ H, const float* __restrict__ g,
            const float* __restrict__ b, ushort* __restrict__ X)
{
    int row = blockIdx.x, t = threadIdx.x;
    ushort* o = X + (long long)row * DIM;
    if (row < PAD) {
        #pragma unroll
        for (int i = 0; i < 4; i++) o[t + i * 256] = 0;
        return;
    }
    const float* x = H + (long long)(row - PAD) * DIM;
    float r[4]; float s = 0.f;
    #pragma unroll
    for (int i = 0; i < 4; i++) { r[i] = x[t + i * 256]; s += r[i]; }
    float mu = blk_sum(s) * (1.f / DIM);
    float v = 0.f;
    #pragma unroll
    for (int i = 0; i < 4; i++) { float d = r[i] - mu; v += d * d; }
    float var = blk_sum(v) * (1.f / DIM);
    float rs = rsqrtf(var + 1e-5f);
    #pragma unroll
    for (int i = 0; i < 4; i++) { int c = t + i * 256; o[c] = f2b((r[i] - mu) * rs * g[c] + b[c]); }
}

// ---------------- landmarks ----------------
__global__ __launch_bounds__(128)
void landmarks(const ushort* __restrict__ QKVb, ushort* __restrict__ QL, ushort* __restrict__ KL)
{
    int L = blockIdx.x, h = blockIdx.y, d = threadIdx.x;
    float sq = 0.f, sk = 0.f;
    #pragma unroll
    for (int j = 0; j < LSUB; j++) {
        const ushort* p = QKVb + (long long)(L * LSUB + j) * 3072 + h * DHEAD + d;
        sq += b2f(p[0]);
        sk += b2f(p[1024]);
    }
    QL[(long long)(h * LMK + L) * DHEAD + d] = f2b(sq * (1.f / LSUB));
    KL[(long long)(h * LMK + L) * DHEAD + d] = f2b(sk * (1.f / LSUB));
}

// ---------------- V transpose -> bf16 VT[h][d][i] ----------------
__global__ void vtrans(const ushort* __restrict__ Q, ushort* __restrict__ VT)
{
    __shared__ ushort tile[32][33];
    int h = blockIdx.z, i0 = blockIdx.x * 32, d0 = blockIdx.y * 32;
    int tx = threadIdx.x, ty = threadIdx.y;
    for (int yy = ty; yy < 32; yy += 8)
        tile[yy][tx] = Q[(long long)(i0 + yy) * 3072 + 2048 + h * 128 + d0 + tx];
    __syncthreads();
    for (int yy = ty; yy < 32; yy += 8)
        VT[((long long)h * 128 + d0 + yy) * 6144 + i0 + tx] = tile[tx][yy];
}

// ---------------- a2 column sums ----------------
__global__ __launch_bounds__(256)
void a2_sums2(const float* __restrict__ A2, float* __restrict__ cols)
{
    int h = blockIdx.x, slice = blockIdx.y, t = threadIdx.x;
    const float* a = A2 + (long long)h * LMK * LMK + (long long)slice * 64 * LMK;
    float s0 = 0.f, s1 = 0.f;
    #pragma unroll 4
    for (int i = 0; i < 64; i++) {
        s0 += a[(long long)i * LMK + t];
        s1 += a[(long long)i * LMK + t + 256];
    }
    atomicAdd(&cols[h * LMK + t], s0);
    atomicAdd(&cols[h * LMK + t + 256], s1);
}
__global__ __launch_bounds__(256)
void a2_scal2(const float* __restrict__ cols, float* __restrict__ scal)
{
    float mc = -1e30f;
    for (int i = threadIdx.x; i < HEADS * LMK; i += 256) mc = fmaxf(mc, cols[i]);
    mc = blk_max(mc);
    if (threadIdx.x == 0) scal[0] = 1.f / mc;
}

// ---------------- z0/X prep ----------------
__global__ void z0_t(const float* __restrict__ A2, ushort* __restrict__ Xb,
                     ushort* __restrict__ Z0b, ushort* __restrict__ Z0T,
                     const float* __restrict__ scal)
{
    __shared__ float tile[32][33];
    int h = blockIdx.z;
    const float* a = A2 + (long long)h * LMK * LMK;
    float s = scal[0];
    int x0 = blockIdx.x * 32, y0 = blockIdx.y * 32;
    int tx = threadIdx.x, ty = threadIdx.y;
    long long hb = (long long)h * LMK * LMK;
    for (int yy = ty; yy < 32; yy += 8) {
        float v = a[(long long)(y0 + yy) * LMK + x0 + tx];
        tile[yy][tx] = v;
        Xb [hb + (long long)(y0 + yy) * LMK + x0 + tx] = f2b(v);
        Z0T[hb + (long long)(y0 + yy) * LMK + x0 + tx] = f2b(s * v);
    }
    __syncthreads();
    for (int yy = ty; yy < 32; yy += 8)
        Z0b[hb + (long long)(x0 + yy) * LMK + y0 + tx] = f2b(s * tile[tx][yy]);
}

// ---------------- MoE ----------------
__global__ __launch_bounds__(256)
void moe_combine(const float* __restrict__ X, const float* __restrict__ wg,
                 const ushort* __restrict__ EO, const float* __restrict__ eb,
                 float* __restrict__ H)
{
    int i = blockIdx.x, t = threadIdx.x;
    const float* x = X + (long long)i * INDIM;
    float g0 = 0.f, g1 = 0.f, g2 = 0.f;
    for (int f = t; f < INDIM; f += 256) {
        float xv = x[f];
        const float* w = wg + f * 3;
        g0 += xv * w[0]; g1 += xv * w[1]; g2 += xv * w[2];
    }
    g0 = blk_sum(g0); g1 = blk_sum(g1); g2 = blk_sum(g2);
    float m = fmaxf(g0, fmaxf(g1, g2));
    float e0 = __expf(g0 - m), e1 = __expf(g1 - m), e2 = __expf(g2 - m);
    float inv = 1.f / (e0 + e1 + e2);
    e0 *= inv; e1 *= inv; e2 *= inv;
    const ushort* eo = EO + (long long)i * 3072;
    for (int o = t; o < DIM; o += 256) {
        float v0 = fmaxf(b2f(eo[o])        + eb[o],        0.f);
        float v1 = fmaxf(b2f(eo[1024 + o]) + eb[1024 + o], 0.f);
        float v2 = fmaxf(b2f(eo[2048 + o]) + eb[2048 + o], 0.f);
        float r = e0 * v0 + e1 * v1 + e2 * v2;
        H[(long long)(1 + i) * DIM + o] = r;
        if (i < 84) H[(long long)(6001 + i) * DIM + o] = r;
    }
}

__global__ void cls_copy(const float* __restrict__ c, float* __restrict__ H)
{
    for (int i = threadIdx.x; i < DIM; i += 256) H[i] = c[i];
}

// ---------------- res conv (in-place bf16, 8 channels/thread): Ob += dw33(V) ----------------
__global__ __launch_bounds__(256)
void resconv(const ushort* __restrict__ QKVb, const float* __restrict__ rw,
             ushort* __restrict__ Ob)
{
    long long idx = (long long)blockIdx.x * 256 + threadIdx.x;   // over NPL * 128
    int cg = (int)(idx & 127);
    long long i = idx >> 7;
    int c0 = cg * 8;
    int h = c0 >> 7;
    float acc[8];
    ushort* ob = Ob + i * DIM + c0;
    {
        ushort4 a0 = *(const ushort4*)ob, a1 = *(const ushort4*)(ob + 4);
        acc[0] = b2f(a0.x); acc[1] = b2f(a0.y); acc[2] = b2f(a0.z); acc[3] = b2f(a0.w);
        acc[4] = b2f(a1.x); acc[5] = b2f(a1.y); acc[6] = b2f(a1.z); acc[7] = b2f(a1.w);
    }
    const ushort* vb = QKVb + 2048 + c0;
    const float* rwh = rw + h * 33;
    #pragma unroll
    for (int t = 0; t < 33; t++) {
        long long r = i + t - 16;
        if ((unsigned long long)r < (unsigned long long)NPL) {
            float wv = rwh[t];
            const ushort* p = vb + r * 3072;
            ushort4 v0 = *(const ushort4*)p, v1 = *(const ushort4*)(p + 4);
            acc[0] += wv * b2f(v0.x); acc[1] += wv * b2f(v0.y);
            acc[2] += wv * b2f(v0.z); acc[3] += wv * b2f(v0.w);
            acc[4] += wv * b2f(v1.x); acc[5] += wv * b2f(v1.y);
            acc[6] += wv * b2f(v1.z); acc[7] += wv * b2f(v1.w);
        }
    }
    ushort4 u0 = {f2b(acc[0]), f2b(acc[1]), f2b(acc[2]), f2b(acc[3])};
    ushort4 u1 = {f2b(acc[4]), f2b(acc[5]), f2b(acc[6]), f2b(acc[7])};
    *(ushort4*)ob = u0;
    *(ushort4*)(ob + 4) = u1;
}

// ---------------- PPEG ----------------
__global__ void h2f(const float* __restrict__ H, float* __restrict__ F)
{
    __shared__ float tile[32][33];
    int p0 = blockIdx.x * 32, c0 = blockIdx.y * 32;
    int tx = threadIdx.x, ty = threadIdx.y;
    for (int yy = ty; yy < 32; yy += 8) {
        int p = p0 + yy;
        if (p < HW * HW) tile[yy][tx] = H[(long long)(1 + p) * DIM + c0 + tx];
    }
    __syncthreads();
    for (int yy = ty; yy < 32; yy += 8) {
        int p = p0 + tx, c = c0 + yy;
        if (p < HW * HW) F[(long long)c * (HW * HW) + p] = tile[tx][yy];
    }
}
__global__ void f2h(const float* __restrict__ F2, float* __restrict__ H)
{
    __shared__ float tile[32][33];
    int c0 = blockIdx.x * 32, p0 = blockIdx.y * 32;
    int tx = threadIdx.x, ty = threadIdx.y;
    for (int yy = ty; yy < 32; yy += 8) {
        int p = p0 + tx;
        if (p < HW * HW) tile[yy][tx] = F2[(long long)(c0 + yy) * (HW * HW) + p];
    }
    __syncthreads();
    for (int yy = ty; yy < 32; yy += 8) {
        int p = p0 + yy;
        if (p < HW * HW) H[(long long)(1 + p) * DIM + c0 + tx] = tile[tx][yy];
    }
}
__global__ __launch_bounds__(256)
void ppeg_conv2(const float* __restrict__ F,
                const float* __restrict__ w7, const float* __restrict__ b7,
                const float* __restrict__ w5, const float* __restrict__ b5,
                const float* __restrict__ w3, const float* __restrict__ b3,
                float* __restrict__ F2)
{
    int c = blockIdx.x, t = threadIdx.x;
    __shared__ float plane[HW * HW];
    __shared__ float wm[49];
    for (int p = t; p < HW * HW; p += 256) plane[p] = F[(long long)c * (HW * HW) + p];
    if (t < 49) {
        int ky = t / 7 - 3, kx = t % 7 - 3;
        float w = w7[(long long)c * 49 + t];
        if (ky >= -2 && ky <= 2 && kx >= -2 && kx <= 2) w += w5[(long long)c * 25 + (ky + 2) * 5 + (kx + 2)];
        if (ky >= -1 && ky <= 1 && kx >= -1 && kx <= 1) w += w3[(long long)c * 9 + (ky + 1) * 3 + (kx + 1)];
        if (t == 24) w += 1.0f;
        wm[t] = w;
    }
    __syncthreads();
    float bsum = b7[c] + b5[c] + b3[c];
    for (int p = t; p < HW * HW; p += 256) {
        int y = p / HW, x = p - y * HW;
        float acc = bsum;
        if (y >= 3 && y < HW - 3 && x >= 3 && x < HW - 3) {
            const float* base = &plane[p];
            #pragma unroll
            for (int ky = -3; ky <= 3; ky++)
                #pragma unroll
                for (int kx = -3; kx <= 3; kx++)
                    acc += wm[(ky + 3) * 7 + kx + 3] * base[ky * HW + kx];
        } else {
            for (int ky = -3; ky <= 3; ky++) {
                int yy = y + ky; if ((unsigned)yy >= (unsigned)HW) continue;
                for (int kx = -3; kx <= 3; kx++) {
                    int xx = x + kx; if ((unsigned)xx >= (unsigned)HW) continue;
                    acc += wm[(ky + 3) * 7 + kx + 3] * plane[yy * HW + xx];
                }
            }
        }
        F2[(long long)c * (HW * HW) + p] = acc;
    }
}

// ---------------- final head ----------------
__global__ __launch_bounds__(256)
void head_k(const float* __restrict__ H, const float* __restrict__ g, const float* __restrict__ b,
            const float* __restrict__ fw, const float* __restrict__ fb, float* __restrict__ out)
{
    int t = threadIdx.x;
    float r[4]; float s = 0.f;
    #pragma unroll
    for (int i = 0; i < 4; i++) { r[i] = H[t + i * 256]; s += r[i]; }
    float mu = blk_sum(s) * (1.f / DIM);
    float v = 0.f;
    #pragma unroll
    for (int i = 0; i < 4; i++) { float d = r[i] - mu; v += d * d; }
    float var = blk_sum(v) * (1.f / DIM);
    float rs = rsqrtf(var + 1e-5f);
    float d0 = 0.f, d1 = 0.f;
    #pragma unroll
    for (int i = 0; i < 4; i++) {
        int c = t + i * 256;
        float hv = (r[i] - mu) * rs * g[c] + b[c];
        d0 += hv * fw[c];
        d1 += hv * fw[DIM + c];
    }
    d0 = blk_sum(d0); d1 = blk_sum(d1);
    if (t == 0) {
        float l0 = d0 + fb[0], l1 = d1 + fb[1];
        float m = fmaxf(l0, l1);
        float e0 = __expf(l0 - m), e1 = __expf(l1 - m);
        float inv = 1.f / (e0 + e1);
        out[0] = l0; out[1] = l1;
        out[2] = e0 * inv; out[3] = e1 * inv;
        out[4] = (l1 > l0) ? 1.0f : 0.0f;
    }
}

// ---------------- host ----------------
extern "C" void kernel_launch(void* const* d_in, const int* in_sizes, int n_in,
                              void* d_out, int out_size, void* d_ws, size_t ws_size,
                              hipStream_t stream)
{
    const float* data     = (const float*)d_in[0];
    const float* w_gate   = (const float*)d_in[1];
    const float* expert_w = (const float*)d_in[2];
    const float* expert_b = (const float*)d_in[3];
    const float* cls_tok  = (const float*)d_in[4];
    const float* ln_g[2]  = {(const float*)d_in[5],  (const float*)d_in[11]};
    const float* ln_b[2]  = {(const float*)d_in[6],  (const float*)d_in[12]};
    const float* qkv_w[2] = {(const float*)d_in[7],  (const float*)d_in[13]};
    const float* out_w[2] = {(const float*)d_in[8],  (const float*)d_in[14]};
    const float* out_b[2] = {(const float*)d_in[9],  (const float*)d_in[15]};
    const float* res_w[2] = {(const float*)d_in[10], (const float*)d_in[16]};
    const float* pw7 = (const float*)d_in[17]; const float* pb7 = (const float*)d_in[18];
    const float* pw5 = (const float*)d_in[19]; const float* pb5 = (const float*)d_in[20];
    const float* pw3 = (const float*)d_in[21]; const float* pb3 = (const float*)d_in[22];
    const float* nf_g = (const float*)d_in[23]; const float* nf_b = (const float*)d_in[24];
    const float* fc2w = (const float*)d_in[25]; const float* fc2b = (const float*)d_in[26];

    float*  ws    = (float*)d_ws;
    float*  H     = ws + OFF_H;
    ushort* LNXb  = (ushort*)(ws + OFF_LNXO);
    ushort* QKVb  = (ushort*)(ws + OFF_QKVB);
    ushort* EOb   = (ushort*)(ws + OFF_QKVB);
    float*  PBV   = ws + OFF_PBV;
    float*  PM    = ws + OFF_PM;
    float*  PL    = ws + OFF_PL;
    ushort* Ob    = (ushort*)(ws + OFF_OB);
    ushort* VT    = (ushort*)(ws + OFF_VT);
    ushort* QL    = (ushort*)(ws + OFF_QL);
    ushort* KL    = (ushort*)(ws + OFF_KL);
    float*  A2F   = ws + OFF_A2F;
    ushort* BVTb  = (ushort*)(ws + OFF_BVTB);
    ushort* Xb    = (ushort*)(ws + OFF_XB);
    ushort* XZB   = (ushort*)(ws + OFF_XZB);
    ushort* XZT7  = (ushort*)(ws + OFF_XZT7);
    ushort* PT15  = (ushort*)(ws + OFF_PT15);
    ushort* QT13  = (ushort*)(ws + OFF_QT13);
    ushort* ZB[2] = {(ushort*)(ws + OFF_ZB0), (ushort*)(ws + OFF_ZB1)};
    ushort* ZT[2] = {(ushort*)(ws + OFF_ZT0), (ushort*)(ws + OFF_ZT1)};
    ushort* ZBT   = (ushort*)(ws + OFF_ZBT);
    ushort* QWB   = (ushort*)(ws + OFF_QWB);
    ushort* OWB   = (ushort*)(ws + OFF_OWB);
    ushort* DATAB = (ushort*)(ws + OFF_DATAB);
    ushort* EWB   = (ushort*)(ws + OFF_EWB);
    float*  COLS  = ws + OFF_COLS;
    float*  SCAL  = ws + OFF_SCAL;

    const long long HSB = (long long)LMK * DHEAD;   // 65536
    const long long A2S = (long long)LMK * LMK;     // 262144

    // ---- MoE ----
    cvt_bf16<<<4500, 256, 0, stream>>>(data, DATAB, (long long)NTOK * INDIM);
    cvt_bf16<<<2304, 256, 0, stream>>>(expert_w, EWB, 3072LL * INDIM);
    mg<2><<<dim3(24,47,1),256,0,stream>>>(DATAB,INDIM,0, EWB,INDIM,0, EOb,3072,0,
        nullptr,0,0, NTOK,INDIM, nullptr, 1.f,0.f,0.f);
    moe_combine<<<NTOK,256,0,stream>>>(data, w_gate, EOb, expert_b, H);
    cls_copy<<<1,256,0,stream>>>(cls_tok, H);

    for (int stage = 0; stage < 2; stage++) {
        cvt2_bf16<<<2048, 256, 0, stream>>>(qkv_w[stage], QWB, 3072LL * DIM,
                                            out_w[stage], OWB, (long long)DIM * DIM);
        ln_pad<<<NPL,256,0,stream>>>(H, ln_g[stage], ln_b[stage], LNXb);
        mg<1><<<dim3(24,48,1),256,0,stream>>>(LNXb,DIM,0, QWB,DIM,0, QKVb,3072,0,
            nullptr,0,0, NPL,DIM, nullptr, 1.f,0.f,0.f);
        landmarks<<<dim3(LMK,HEADS),128,0,stream>>>(QKVb, QL, KL);
        vtrans<<<dim3(192,4,8),dim3(32,8),0,stream>>>(QKVb, VT);
        // a2 = softmax(ql @ kl^T) f32  (64x128 tiles -> 256 blocks)
        mg64<0><<<dim3(4,8,8),256,0,stream>>>(QL,DHEAD,HSB, KL,DHEAD,HSB, A2F,LMK,A2S,
            nullptr,0,0, DHEAD, 1.f,0.f,0.f);
        softmax_rows<2><<<HEADS*LMK,256,0,stream>>>(A2F, LMK);
        hipMemsetAsync(COLS, 0, HEADS * LMK * sizeof(float), stream);
        a2_sums2<<<dim3(HEADS,8),256,0,stream>>>(A2F, COLS);
        a2_scal2<<<1,256,0,stream>>>(COLS, SCAL);
        z0_t<<<dim3(16,16,8),dim3(32,8),0,stream>>>(A2F, Xb, ZB[0], ZT[0], SCAL);
        // Newton-Schulz: 6 iterations, 64x128-tile GEMMs (256 blocks = all CUs)
        int cur = 0;
        for (int it = 0; it < 6; it++) {
            mg64<4><<<dim3(4,8,8),256,0,stream>>>(Xb,LMK,A2S, ZT[cur],LMK,A2S, XZB,LMK,A2S,
                XZT7,LMK,A2S, LMK, 1.f, 7.f, -1.f);
            mg64<5><<<dim3(4,8,8),256,0,stream>>>(XZB,LMK,A2S, XZT7,LMK,A2S, nullptr,0,0,
                PT15,LMK,A2S, LMK, 1.f, 15.f, -1.f);
            mg64<5><<<dim3(4,8,8),256,0,stream>>>(XZB,LMK,A2S, PT15,LMK,A2S, nullptr,0,0,
                QT13,LMK,A2S, LMK, 1.f, 13.f, -1.f);
            if (it < 5)
                mg64<4><<<dim3(4,8,8),256,0,stream>>>(ZB[cur],LMK,A2S, QT13,LMK,A2S, ZB[1-cur],LMK,A2S,
                    ZT[1-cur],LMK,A2S, LMK, 0.25f, 0.f, 1.f);
            else
                mg64<2><<<dim3(4,8,8),256,0,stream>>>(ZB[cur],LMK,A2S, QT13,LMK,A2S, ZB[1-cur],LMK,A2S,
                    nullptr,0,0, LMK, 0.25f, 0.f, 1.f);
            cur = 1 - cur;
        }
        ushort* Z6 = ZB[cur];
        // flash a3: partial bv over 16 kv-chunks of 384
        flash<1,2><<<dim3(4,NSPLIT,8),256,0,stream>>>(QL,DHEAD,HSB, QKVb+1024,3072,128,
            VT,NPL,(long long)DHEAD*NPL, PBV, PM, PL, nullptr, 6, 384);
        bv_combine<<<dim3(16,8),256,0,stream>>>(PBV, PM, PL, BVTb);
        // ZBT[d][l'] = sum_l bvT[d][l] z6[l'][l]  (64 blocks)
        mg64<2><<<dim3(4,2,8),256,0,stream>>>(BVTb,LMK,HSB, Z6,LMK,A2S, ZBT,LMK,HSB,
            nullptr,0,0, LMK, 1.f,0.f,0.f);
        // flash a1: Ob = bf16(softmax(q @ kl^T) @ zb)  (64-row q tiles, 768 blocks)
        flash<0,1><<<dim3(96,1,8),256,0,stream>>>(QKVb,3072,128, KL,DHEAD,HSB,
            ZBT,LMK,HSB, nullptr, nullptr, nullptr, Ob, 8, 0);
        // Ob += res conv of v  (in-place bf16, 8 channels/thread)
        resconv<<<(NPL*128)/256,256,0,stream>>>(QKVb, res_w[stage], Ob);
        // H += Ob @ out_w^T + out_b
        mg<3><<<dim3(8,48,1),256,0,stream>>>(Ob + (long long)PAD*DIM,DIM,0, OWB,DIM,0, H,DIM,0,
            nullptr,0,0, NH,DIM, out_b[stage], 1.f,0.f,0.f);
        if (stage == 0) {
            float* F  = ws + OFF_QKVB;
            float* F2 = F + 6230016LL;
            h2f<<<dim3(191,32),dim3(32,8),0,stream>>>(H, F);
            ppeg_conv2<<<DIM,256,0,stream>>>(F, pw7, pb7, pw5, pb5, pw3, pb3, F2);
            f2h<<<dim3(32,191),dim3(32,8),0,stream>>>(F2, H);
        }
    }

    head_k<<<1,256,0,stream>>>(H, nf_g, nf_b, fc2w, fc2b, (float*)d_out);
}